// Round 10
// baseline (1663.188 us; speedup 1.0000x reference)
//
#include <hip/hip_runtime.h>
#include <hip/hip_bf16.h>
#include <cstdint>
#include <cstddef>

// ---------------------------------------------------------------------------
// MMPrompt pipeline, round 10:
//  - RGCN inverted to aggregate-then-transform: per-(node,rel) segmented CSR,
//    k_agg6 gathers from cache-resident xb (23MB) into agg6, then K=2304
//    GEMMs (36 K-iters) accumulate into ent0. Replaces the hh short-K GEMMs
//    + 138MB-random-read gathers.
//  - final GEMM epilogue: transpose index math via col_base decomposition.
//  - everything else = round 8/9 proven lane.
// ---------------------------------------------------------------------------

namespace {

constexpr int NE   = 30000;
constexpr int NM   = 6000;
constexpr int Dm   = 384;
constexpr int Hm   = 768;
constexpr int EKG  = 200000;
constexpr int EC   = 200000;
constexpr int ES   = 80000;
constexpr int Bc   = 16;
constexpr int LE   = 48;
constexpr int NTOK = 4096;
constexpr int NO   = 18432;

constexpr size_t NBf = (size_t)NE * Dm;   // 11,520,000
constexpr size_t MBF = (size_t)NM * Dm;   // 2,304,000

// ---------------- d_out arena (f32-unit offsets) ----------------
// phase A
constexpr size_t P_XB    = 0;          // xb bf16 NE*384           ends 5,760,000
constexpr size_t P_WCT   = 5760000;    // wct2 bf16 2*384*2304     ends 6,644,736
constexpr size_t P_CNT   = 6644736;    // counts->rcp f32 12*NE    ends 7,004,736
constexpr size_t P_ENT0  = 7004736;    // f32 NE*384               ends 18,524,736
constexpr size_t P_HH    = 18524736;   // agg6 bf16 NE*2304        ends 53,084,736
constexpr size_t P_DIS   = 53084736;   // disc+dist+disi f32       ends 53,126,736
// phase B — xb dead after agg pass 2; ent0 f32 dead after k_cvt->ent0b
constexpr size_t P_E0B   = 0;          // ent0b bf16 NE*384  ends 2,880,000
constexpr size_t P_C1B   = 2880000;    // bf16 NE*384        ends 5,760,000
constexpr size_t P_C2B   = 5760000;    // bf16 NE*384        ends 8,640,000
constexpr size_t P_NFB   = 8640000;    // bf16 NM*384        ends 9,792,000
constexpr size_t P_T1B   = 9800000;    // bf16 NM*384        ends 10,952,000
constexpr size_t P_G1    = 11000000;   // f32 NM*384         ends 13,304,000
constexpr size_t P_ACC   = 41564736;   // f32 NE*384 (over dead agg6) ends 53,084,736
constexpr size_t P_ENTB  = 55600000;   // bf16 NE*384        ends 61,360,000
// phase C
constexpr size_t P_HIDB  = 0;          // bf16 NE*192
constexpr size_t P_ENT2B = 2880000;    // bf16 NE*384
constexpr size_t P_E768B = 8640000;    // bf16 NE*768   ends 20,160,000
constexpr size_t P_TOKB  = 20160000;   // bf16 4096*768
constexpr size_t P_THIDB = 21732864;   // bf16 4096*384
constexpr size_t P_TOK1B = 22519296;   // bf16 4096*768
constexpr size_t P_TOK2B = 24092160;   // bf16 4096*768
constexpr size_t P_QB    = 25665024;   // bf16 4096*768
constexpr size_t P_EEMB  = 27237888;   // bf16 768*Hm
constexpr size_t P_PR0   = 27532800;   // f32 4096*768
constexpr size_t P_PR0B  = 30678528;   // bf16 4096*768
constexpr size_t P_PHIDB = 32251392;   // bf16 4096*384 ends 33,037,824
// whole-launch small weights
constexpr size_t P_WT    = 74000000;   // ends < 75,497,472
constexpr size_t S_ROOT  = 0;
constexpr size_t S_EP1A  = 147456;
constexpr size_t S_EP1B  = 221184;
constexpr size_t S_EP2   = 294912;
constexpr size_t S_TP1A  = 589824;
constexpr size_t S_TP1B  = 884736;
constexpr size_t S_TP2   = 1179648;
constexpr size_t S_CAW   = 1769472;
constexpr size_t S_PP1A  = 2359296;
constexpr size_t S_PP1B  = 2654208;

// ---------------- d_ws layout ----------------
constexpr size_t WI       = 6291456 / 4;
constexpr size_t I_CNT    = WI + 0;        // 30000
constexpr size_t I_PART   = WI + 30000;    // 256
constexpr size_t I_KG_RP  = WI + 30256;    // 30000
constexpr size_t I_KG_SL  = WI + 60256;    // 200000
constexpr size_t I_C_RP   = WI + 260256;
constexpr size_t I_C_CUR  = WI + 290256;
constexpr size_t I_C_SL   = WI + 320256;   // 200000
constexpr size_t I_TS_RP  = WI + 520256;
constexpr size_t I_TS_CUR = WI + 526256;
constexpr size_t I_TS_SL  = WI + 532256;   // 80000
constexpr size_t I_IS_RP  = WI + 612256;
constexpr size_t I_IS_CUR = WI + 618256;
constexpr size_t I_IS_SL  = WI + 624256;   // 80000 -> WI+704,256
constexpr size_t I_BND12  = WI + 704256;   // NE*12 = 360000
constexpr size_t I_CUR12  = WI + 1064256;  // 360000 -> ends WI+1,424,256 (~11.99MB)
constexpr size_t WS_PP2T_BYTE = 6291456;   // overlays CSR after death
constexpr size_t WS_NEED      = 34603008;

inline int cdiv(long a, long b) { return (int)((a + b - 1) / b); }

} // namespace

typedef short short8v __attribute__((ext_vector_type(8)));
typedef float f32x4 __attribute__((ext_vector_type(4)));

__device__ __forceinline__ unsigned short f2bf(float f) {
  union { float f; uint32_t u; } v; v.f = f;
  uint32_t u = v.u;
  u += 0x7fffu + ((u >> 16) & 1u);
  return (unsigned short)(u >> 16);
}
__device__ __forceinline__ uint32_t pkbf(float a, float b) {
  __hip_bfloat162 h = __float22bfloat162_rn(float2{a, b});
  union { __hip_bfloat162 h; uint32_t u; } cv; cv.h = h;
  return cv.u;
}
__device__ __forceinline__ float bflo(uint32_t u) {
  union { uint32_t u; float f; } c; c.u = u << 16; return c.f;
}
__device__ __forceinline__ float bfhi(uint32_t u) {
  union { uint32_t u; float f; } c; c.u = u & 0xFFFF0000u; return c.f;
}

__device__ __forceinline__ void gl16(const void* g, void* l) {
  __builtin_amdgcn_global_load_lds(
      (const __attribute__((address_space(1))) void*)g,
      (__attribute__((address_space(3))) void*)l, 16, 0, 0);
}

// ---------------------------------------------------------------------------
// conversion / utility kernels
// ---------------------------------------------------------------------------

__global__ void k_cvt(const float* __restrict__ x, unsigned short* __restrict__ o, size_t n2) {
  size_t i = (size_t)blockIdx.x * 256 + threadIdx.x;
  if (i >= n2) return;
  float2 v = *(const float2*)(x + 2 * i);
  *(uint32_t*)(o + 2 * i) = pkbf(v.x, v.y);
}

// f32 W[K][N] -> bf16 Wt[N][K]
__global__ void k_cvt_t(const float* __restrict__ W, unsigned short* __restrict__ Wt,
                        int K, int N) {
  __shared__ float t[32][33];
  int tx = threadIdx.x & 31, ty = threadIdx.x >> 5;
  int n0 = blockIdx.x * 32, k0 = blockIdx.y * 32;
#pragma unroll
  for (int j = 0; j < 4; ++j)
    t[ty + 8 * j][tx] = W[(size_t)(k0 + ty + 8 * j) * N + n0 + tx];
  __syncthreads();
#pragma unroll
  for (int j = 0; j < 4; ++j) {
    int n = ty + 8 * j;
    Wt[(size_t)(n0 + n) * K + k0 + tx] = f2bf(t[tx][n]);
  }
}

// wct2[half][o][rr*384+i] = sum_b comp[half*6+rr][b] * bases[b][i][o]   (bf16)
__global__ void k_wcat2(const float* __restrict__ comp, const float* __restrict__ bases,
                        unsigned short* __restrict__ Wt) {
  int idx = blockIdx.x * 256 + threadIdx.x;
  if (idx >= 12 * Dm * Dm) return;
  int i = idx % Dm;
  int rr = (idx / Dm) % 6;
  int o = (idx / (Dm * 6)) % Dm;
  int half = idx / (Dm * 6 * Dm);
  int r = half * 6 + rr;
  float s = 0.f;
#pragma unroll
  for (int b = 0; b < 8; ++b)
    s += comp[r * 8 + b] * bases[(size_t)b * Dm * Dm + (size_t)i * Dm + o];
  Wt[(size_t)half * 884736 + (size_t)o * 2304 + rr * 384 + i] = f2bf(s);
}

// gather bf16 rows as u32 chunks
__global__ void k_gather_b(const int* __restrict__ idx, const uint32_t* __restrict__ x2,
                           uint32_t* __restrict__ out2, int rows, int D2) {
  size_t i = (size_t)blockIdx.x * 256 + threadIdx.x;
  if (i >= (size_t)rows * D2) return;
  int r = (int)(i / D2);
  int c = (int)(i - (size_t)r * D2);
  out2[i] = x2[(size_t)idx[r] * D2 + c];
}

// ent[mte[m]][d] += 0.25*g[m][d]
__global__ void k_scatter_movie(const int* __restrict__ mte, const float* __restrict__ g,
                                float* __restrict__ ent) {
  size_t i = (size_t)blockIdx.x * 256 + threadIdx.x;
  if (i >= MBF) return;
  int m = (int)(i / Dm);
  int d = (int)(i - (size_t)m * Dm);
  atomicAdd(&ent[(size_t)mte[m] * Dm + d], 0.25f * g[i]);
}

// ---------------------------------------------------------------------------
// CSR build
// ---------------------------------------------------------------------------

__global__ void k_hist(const int* __restrict__ dst, int* __restrict__ cnt, int E) {
  int e = blockIdx.x * 256 + threadIdx.x;
  if (e < E) atomicAdd(&cnt[dst[e]], 1);
}

__global__ void k_scan_blk(const int* __restrict__ in, int* __restrict__ out,
                           int* __restrict__ part, int n) {
  __shared__ int s[256];
  int t = threadIdx.x;
  int g = blockIdx.x * 256 + t;
  int v = (g < n) ? in[g] : 0;
  s[t] = v;
  __syncthreads();
  for (int off = 1; off < 256; off <<= 1) {
    int add = (t >= off) ? s[t - off] : 0;
    __syncthreads();
    s[t] += add;
    __syncthreads();
  }
  if (g < n) out[g] = s[t] - v;
  if (t == 255) part[blockIdx.x] = s[255];
}

__global__ void k_scan_top(int* __restrict__ part, int nb) {
  __shared__ int s[256];
  int t = threadIdx.x;
  int v = (t < nb) ? part[t] : 0;
  s[t] = v;
  __syncthreads();
  for (int off = 1; off < 256; off <<= 1) {
    int add = (t >= off) ? s[t - off] : 0;
    __syncthreads();
    s[t] += add;
    __syncthreads();
  }
  if (t < nb) part[t] = s[t] - v;
}

__global__ void k_scan_add(int* __restrict__ out, const int* __restrict__ part, int n) {
  int g = blockIdx.x * 256 + threadIdx.x;
  if (g < n) out[g] += part[blockIdx.x];
}

__global__ void k_fill(const int* __restrict__ src, const int* __restrict__ dst,
                       int* __restrict__ cur, int* __restrict__ slots, int E) {
  int e = blockIdx.x * 256 + threadIdx.x;
  if (e >= E) return;
  int d = dst[e];
  int pos = atomicAdd(&cur[d], 1);
  slots[pos] = src[e];
}

// per-(v,rel) segment starts: bnd12[v*12+r] = rp[v] + prefix(counts[.][v])
__global__ void k_seg(const float* __restrict__ cnt, const int* __restrict__ rp,
                      int* __restrict__ bnd12, int n) {
  int v = blockIdx.x * 256 + threadIdx.x;
  if (v >= n) return;
  int base = rp[v];
#pragma unroll
  for (int r = 0; r < 12; ++r) {
    bnd12[v * 12 + r] = base;
    base += (int)cnt[(size_t)r * NE + v];
  }
}

// fill into per-(v,rel) segments
__global__ void k_fill_kg(const int* __restrict__ src, const int* __restrict__ dst,
                          const int* __restrict__ typ, int* __restrict__ cur12,
                          int* __restrict__ slots, int E) {
  int e = blockIdx.x * 256 + threadIdx.x;
  if (e >= E) return;
  int pos = atomicAdd(&cur12[dst[e] * 12 + typ[e]], 1);
  slots[pos] = src[e];
}

__global__ void k_dis_rp(const int* __restrict__ rp, float* __restrict__ dis, int n, int E) {
  int v = blockIdx.x * 256 + threadIdx.x;
  if (v >= n) return;
  int e0 = rp[v], e1 = (v + 1 < n) ? rp[v + 1] : E;
  dis[v] = rsqrtf((float)(e1 - e0) + 1.0f);
}

__global__ void k_count_type(const int* __restrict__ dst, const int* __restrict__ typ,
                             float* __restrict__ cnt, int E) {
  int i = blockIdx.x * 256 + threadIdx.x;
  if (i < E) atomicAdd(&cnt[(size_t)typ[i] * NE + dst[i]], 1.0f);
}

__global__ void k_rcp(float* __restrict__ c, size_t n) {
  size_t i = (size_t)blockIdx.x * 256 + threadIdx.x;
  if (i < n) { float v = c[i]; c[i] = (v > 0.f) ? 1.0f / v : 0.f; }
}

// ---------------------------------------------------------------------------
// RGCN aggregate gather: one wave per node v; for 6 relations (static unroll)
// accumulate (1/cnt)*sum x[src] into a[rr][6] and write agg row (bf16 2304).
// Reads xb (23MB, cache-resident); writes agg sequentially.
// ---------------------------------------------------------------------------
template <bool FIRST>
__global__ void k_agg6(const unsigned short* __restrict__ xb, const float* __restrict__ rcp,
                       const int* __restrict__ rp, const int* __restrict__ bnd12,
                       const int* __restrict__ slots, unsigned short* __restrict__ agg,
                       int E) {
  int v = (int)((blockIdx.x * (size_t)blockDim.x + threadIdx.x) >> 6);
  int lane = threadIdx.x & 63;
  if (v >= NE) return;
  const int rbase = FIRST ? 0 : 6;
  float a[6][6] = {};
#pragma unroll
  for (int rr = 0; rr < 6; ++rr) {
    int rg = rbase + rr;
    int e0 = bnd12[v * 12 + rg];
    int e1 = (rg == 11) ? ((v + 1 < NE) ? rp[v + 1] : E) : bnd12[v * 12 + rg + 1];
    for (int e = e0; e < e1; ++e) {
      int s = slots[e];
      const uint32_t* xs = (const uint32_t*)(xb + (size_t)s * Dm);
#pragma unroll
      for (int i = 0; i < 3; ++i) {
        uint32_t u = xs[lane + 64 * i];
        a[rr][2 * i]     += bflo(u);
        a[rr][2 * i + 1] += bfhi(u);
      }
    }
    float nm = rcp[(size_t)rg * NE + v];
#pragma unroll
    for (int i = 0; i < 6; ++i) a[rr][i] *= nm;
  }
  uint32_t* ag = (uint32_t*)(agg + (size_t)v * 2304);
#pragma unroll
  for (int rr = 0; rr < 6; ++rr)
#pragma unroll
    for (int i = 0; i < 3; ++i)
      ag[rr * 192 + lane + 64 * i] = pkbf(a[rr][2 * i], a[rr][2 * i + 1]);
}

// ---------------------------------------------------------------------------
// bf16 GCN gather (one wave per dst row, 2-edge unrolled) — unchanged from r9.
// ---------------------------------------------------------------------------
template <int OUTM, int ACCM>
__global__ void k_gcn_gb(const unsigned short* __restrict__ x,
                         const float* __restrict__ dis,
                         const int* __restrict__ rp, const int* __restrict__ slots,
                         unsigned short* __restrict__ outb, float* __restrict__ acc,
                         int n, int E, float sc) {
  int v = (int)((blockIdx.x * (size_t)blockDim.x + threadIdx.x) >> 6);
  int lane = threadIdx.x & 63;
  if (v >= n) return;
  float dv = dis[v];
  const uint32_t* xr = (const uint32_t*)(x + (size_t)v * Dm);
  float xv[6];
#pragma unroll
  for (int i = 0; i < 3; ++i) {
    uint32_t u = xr[lane + 64 * i];
    xv[2 * i] = bflo(u); xv[2 * i + 1] = bfhi(u);
  }
  float a[6];
#pragma unroll
  for (int i = 0; i < 6; ++i) a[i] = dv * xv[i];
  int e0 = rp[v], e1 = (v + 1 < n) ? rp[v + 1] : E;
  int e = e0;
  for (; e + 2 <= e1; e += 2) {
    int s0 = slots[e], s1 = slots[e + 1];
    float c0 = dis[s0], c1 = dis[s1];
    const uint32_t* x0 = (const uint32_t*)(x + (size_t)s0 * Dm);
    const uint32_t* x1 = (const uint32_t*)(x + (size_t)s1 * Dm);
    uint32_t u0[3], u1[3];
#pragma unroll
    for (int i = 0; i < 3; ++i) { u0[i] = x0[lane + 64 * i]; u1[i] = x1[lane + 64 * i]; }
#pragma unroll
    for (int i = 0; i < 3; ++i) {
      a[2 * i]     = fmaf(c0, bflo(u0[i]), a[2 * i]);
      a[2 * i + 1] = fmaf(c0, bfhi(u0[i]), a[2 * i + 1]);
      a[2 * i]     = fmaf(c1, bflo(u1[i]), a[2 * i]);
      a[2 * i + 1] = fmaf(c1, bfhi(u1[i]), a[2 * i + 1]);
    }
  }
  if (e < e1) {
    int s0 = slots[e];
    float c0 = dis[s0];
    const uint32_t* x0 = (const uint32_t*)(x + (size_t)s0 * Dm);
#pragma unroll
    for (int i = 0; i < 3; ++i) {
      uint32_t u = x0[lane + 64 * i];
      a[2 * i]     = fmaf(c0, bflo(u), a[2 * i]);
      a[2 * i + 1] = fmaf(c0, bfhi(u), a[2 * i + 1]);
    }
  }
#pragma unroll
  for (int i = 0; i < 6; ++i) a[i] *= dv;
  if (OUTM == 1) {
    uint32_t* ob = (uint32_t*)(outb + (size_t)v * Dm);
#pragma unroll
    for (int i = 0; i < 3; ++i) ob[lane + 64 * i] = pkbf(a[2 * i], a[2 * i + 1]);
  }
  float* ar = acc + (size_t)v * Dm;
  float nw[6];
#pragma unroll
  for (int i = 0; i < 3; ++i) {
    int cidx = 2 * (lane + 64 * i);
    if (ACCM == 1) {
      float2 old = *(const float2*)(ar + cidx);
      nw[2 * i] = old.x + sc * a[2 * i];
      nw[2 * i + 1] = old.y + sc * a[2 * i + 1];
    } else if (ACCM == 2) {
      nw[2 * i] = sc * (xv[2 * i] + a[2 * i]);
      nw[2 * i + 1] = sc * (xv[2 * i + 1] + a[2 * i + 1]);
    } else {
      nw[2 * i] = sc * a[2 * i];
      nw[2 * i + 1] = sc * a[2 * i + 1];
    }
    *(float2*)(ar + cidx) = float2{nw[2 * i], nw[2 * i + 1]};
  }
  if (OUTM == 2) {
    uint32_t* ob = (uint32_t*)(outb + (size_t)v * Dm);
#pragma unroll
    for (int i = 0; i < 3; ++i) ob[lane + 64 * i] = pkbf(nw[2 * i], nw[2 * i + 1]);
  }
}

// ---------------------------------------------------------------------------
// bf16 MFMA GEMM, 128x128 (m97 structure). A[M][K], Wt[N][K] bf16.
// OUT: 0 = f32 C, 1 = bf16 C, 2 = f32 transposed prompt layout.
// ---------------------------------------------------------------------------
template <bool RELU, bool RES, int OUT>
__global__ __launch_bounds__(256) void mgemm_bf(
    const unsigned short* __restrict__ A, const unsigned short* __restrict__ Wt,
    const float* __restrict__ bias, const float* __restrict__ Rp,
    void* __restrict__ Cv, int M, int N, int K) {
  __shared__ __align__(16) unsigned short As[128 * 64];
  __shared__ __align__(16) unsigned short Bs[128 * 64];
  const int tid = threadIdx.x;
  const int lane = tid & 63;
  const int w = tid >> 6;
  const int bm = blockIdx.x * 128, bn = blockIdx.y * 128;
  const int wr = (w >> 1) * 64, wc = (w & 1) * 64;
  const int lrow = lane & 15, lq = lane >> 4;
  f32x4 acc[4][4] = {};
  const int prow_l = lane >> 3;
  const int pslot = lane & 7;

  for (int k0 = 0; k0 < K; k0 += 64) {
    __syncthreads();
#pragma unroll
    for (int j = 0; j < 4; ++j) {
      int seg = j * 4 + w;
      int prow = seg * 8 + prow_l;
      int aslot = pslot ^ (prow & 7);
      int arow = min(bm + prow, M - 1);
      gl16(A + (size_t)arow * K + k0 + aslot * 8, &As[seg * 512 + lane * 8]);
    }
#pragma unroll
    for (int j = 0; j < 4; ++j) {
      int seg = j * 4 + w;
      int prow = seg * 8 + prow_l;
      int bslot = pslot ^ (prow & 7);
      int brow = min(bn + prow, N - 1);
      gl16(Wt + (size_t)brow * K + k0 + bslot * 8, &Bs[seg * 512 + lane * 8]);
    }
    __syncthreads();
#pragma unroll
    for (int ks = 0; ks < 2; ++ks) {
      short8v af[4], bf[4];
      const int slot = ks * 4 + lq;
#pragma unroll
      for (int mr = 0; mr < 4; ++mr) {
        int r = wr + mr * 16 + lrow;
        af[mr] = *(const short8v*)&As[r * 64 + ((slot ^ (r & 7)) << 3)];
      }
#pragma unroll
      for (int nc = 0; nc < 4; ++nc) {
        int r = wc + nc * 16 + lrow;
        bf[nc] = *(const short8v*)&Bs[r * 64 + ((slot ^ (r & 7)) << 3)];
      }
#pragma unroll
      for (int mr = 0; mr < 4; ++mr)
#pragma unroll
        for (int nc = 0; nc < 4; ++nc)
          acc[mr][nc] = __builtin_amdgcn_mfma_f32_16x16x32_bf16(
              af[mr], bf[nc], acc[mr][nc], 0, 0, 0);
    }
  }
  // epilogue
  size_t colb[4];
  if (OUT == 2) {
#pragma unroll
    for (int nc = 0; nc < 4; ++nc) {
      int c = bn + wc + nc * 16 + lrow;
      int l = c / 1536, rem = c - l * 1536;
      int blk = rem / 768, rem2 = rem - blk * 768;
      int h2 = rem2 >> 6, dd = rem2 & 63;
      colb[nc] = (size_t)(l * 2 + blk) * 3145728 + (size_t)h2 * 16384 + dd;
    }
  }
#pragma unroll
  for (int mr = 0; mr < 4; ++mr) {
#pragma unroll
    for (int e = 0; e < 4; ++e) {
      int r = bm + wr + mr * 16 + lq * 4 + e;
      if (r >= M) continue;
      size_t rowoff = 0;
      if (OUT == 2) rowoff = (size_t)r * 64 + (size_t)(r >> 8) * 180224;
#pragma unroll
      for (int nc = 0; nc < 4; ++nc) {
        int c = bn + wc + nc * 16 + lrow;
        if (c >= N) continue;
        float v = acc[mr][nc][e];
        if (bias) v += bias[c];
        if (RES) v += Rp[(size_t)r * N + c];
        if (RELU) v = fmaxf(v, 0.f);
        if (OUT == 0) {
          ((float*)Cv)[(size_t)r * N + c] = v;
        } else if (OUT == 1) {
          ((unsigned short*)Cv)[(size_t)r * N + c] = f2bf(v);
        } else {
          ((float*)Cv)[colb[nc] + rowoff] = v;
        }
      }
    }
  }
}

// Fallback FINAL GEMM (ws too small): W f32 from d_in, in-kernel conversion.
__global__ __launch_bounds__(256) void mgemm_fin(
    const unsigned short* __restrict__ A, const float* __restrict__ W,
    const float* __restrict__ bias, float* __restrict__ O, int M, int N, int K) {
  __shared__ __align__(16) unsigned short As[128 * 64];
  __shared__ __align__(16) unsigned short Bs[128 * 64];
  const int tid = threadIdx.x;
  const int lane = tid & 63;
  const int w = tid >> 6;
  const int bm = blockIdx.x * 128, bn = blockIdx.y * 128;
  const int wr = (w >> 1) * 64, wc = (w & 1) * 64;
  const int lrow = lane & 15, lq = lane >> 4;
  f32x4 acc[4][4] = {};
  const int prow_l = lane >> 3;
  const int pslot = lane & 7;
  const int n_loc = tid & 127;
  const int kh = (tid >> 7) * 32;

  for (int k0 = 0; k0 < K; k0 += 64) {
    __syncthreads();
#pragma unroll
    for (int j = 0; j < 4; ++j) {
      int seg = j * 4 + w;
      int prow = seg * 8 + prow_l;
      int aslot = pslot ^ (prow & 7);
      gl16(A + (size_t)(bm + prow) * K + k0 + aslot * 8, &As[seg * 512 + lane * 8]);
    }
    float wv[32];
    const float* wp = W + (size_t)(k0 + kh) * N + bn + n_loc;
#pragma unroll
    for (int j = 0; j < 32; ++j) wv[j] = wp[(size_t)j * N];
#pragma unroll
    for (int c = 0; c < 4; ++c) {
      uint32_t u0 = pkbf(wv[8 * c + 0], wv[8 * c + 1]);
      uint32_t u1 = pkbf(wv[8 * c + 2], wv[8 * c + 3]);
      uint32_t u2 = pkbf(wv[8 * c + 4], wv[8 * c + 5]);
      uint32_t u3 = pkbf(wv[8 * c + 6], wv[8 * c + 7]);
      int s = (kh >> 3) + c;
      *(uint4*)&Bs[n_loc * 64 + ((s ^ (n_loc & 7)) << 3)] = uint4{u0, u1, u2, u3};
    }
    __syncthreads();
#pragma unroll
    for (int ks = 0; ks < 2; ++ks) {
      short8v af[4], bf[4];
      const int slot = ks * 4 + lq;
#pragma unroll
      for (int mr = 0; mr < 4; ++mr) {
        int r = wr + mr * 16 + lrow;
        af[mr] = *(const short8v*)&As[r * 64 + ((slot ^ (r & 7)) << 3)];
      }
#pragma unroll
      for (int nc = 0; nc < 4; ++nc) {
        int r = wc + nc * 16 + lrow;
        bf[nc] = *(const short8v*)&Bs[r * 64 + ((slot ^ (r & 7)) << 3)];
      }
#pragma unroll
      for (int mr = 0; mr < 4; ++mr)
#pragma unroll
        for (int nc = 0; nc < 4; ++nc)
          acc[mr][nc] = __builtin_amdgcn_mfma_f32_16x16x32_bf16(
              af[mr], bf[nc], acc[mr][nc], 0, 0, 0);
    }
  }
#pragma unroll
  for (int mr = 0; mr < 4; ++mr) {
#pragma unroll
    for (int e = 0; e < 4; ++e) {
      int r = bm + wr + mr * 16 + lq * 4 + e;
      int b = r >> 8, t = r & 255;
#pragma unroll
      for (int nc = 0; nc < 4; ++nc) {
        int c = bn + wc + nc * 16 + lrow;
        float v = acc[mr][nc][e] + bias[c];
        int l = c / 1536, rem = c - l * 1536;
        int blk = rem / 768, rem2 = rem - blk * 768;
        int hh = rem2 >> 6, dd = rem2 & 63;
        size_t oi = (((((size_t)l * 2 + blk) * 16 + b) * 12 + hh) * 256 + t) * 64 + dd;
        O[oi] = v;
      }
    }
  }
}

// ---------------------------------------------------------------------------
// fused cross-attention (bf16 inputs): one wave per (b,t)
// ---------------------------------------------------------------------------
__global__ __launch_bounds__(256) void k_attn(
    const unsigned short* __restrict__ qb, const unsigned short* __restrict__ eb_all,
    const unsigned short* __restrict__ tokb, float* __restrict__ pr0,
    unsigned short* __restrict__ pr0b) {
  int gw = (int)((blockIdx.x * (size_t)blockDim.x + threadIdx.x) >> 6);
  int lane = threadIdx.x & 63;
  if (gw >= NTOK) return;
  int b = gw >> 8;
  const unsigned short* qr = qb + (size_t)gw * Hm;
  float2 q[6];
#pragma unroll
  for (int i = 0; i < 6; ++i) {
    uint32_t u = *(const uint32_t*)(qr + 2 * lane + 128 * i);
    q[i] = float2{bflo(u), bfhi(u)};
  }
  const unsigned short* eb = eb_all + (size_t)b * LE * Hm;
  float myA = -3.0e38f;
  for (int e = 0; e < LE; ++e) {
    const unsigned short* er = eb + (size_t)e * Hm;
    float s = 0.f;
#pragma unroll
    for (int i = 0; i < 6; ++i) {
      uint32_t u = *(const uint32_t*)(er + 2 * lane + 128 * i);
      s = fmaf(q[i].x, bflo(u), s);
      s = fmaf(q[i].y, bfhi(u), s);
    }
#pragma unroll
    for (int off = 32; off > 0; off >>= 1) s += __shfl_xor(s, off);
    if (lane == e) myA = s * (1.0f / 768.0f);
  }
  float mx = myA;
#pragma unroll
  for (int off = 32; off > 0; off >>= 1) mx = fmaxf(mx, __shfl_xor(mx, off));
  float p = (lane < LE) ? expf(myA - mx) : 0.f;
  float sum = p;
#pragma unroll
  for (int off = 32; off > 0; off >>= 1) sum += __shfl_xor(sum, off);
  float wgt = p / sum;
  const unsigned short* tr = tokb + (size_t)gw * Hm;
  float2 a[6];
#pragma unroll
  for (int i = 0; i < 6; ++i) {
    uint32_t u = *(const uint32_t*)(tr + 2 * lane + 128 * i);
    a[i] = float2{bflo(u), bfhi(u)};
  }
  for (int e = 0; e < LE; ++e) {
    float we = __shfl(wgt, e);
    const unsigned short* er = eb + (size_t)e * Hm;
#pragma unroll
    for (int i = 0; i < 6; ++i) {
      uint32_t u = *(const uint32_t*)(er + 2 * lane + 128 * i);
      a[i].x = fmaf(we, bflo(u), a[i].x);
      a[i].y = fmaf(we, bfhi(u), a[i].y);
    }
  }
  float* orow = pr0 + (size_t)gw * Hm;
  unsigned short* obrow = pr0b + (size_t)gw * Hm;
#pragma unroll
  for (int i = 0; i < 6; ++i) {
    *(float2*)(orow + 2 * lane + 128 * i) = a[i];
    *(uint32_t*)(obrow + 2 * lane + 128 * i) = pkbf(a[i].x, a[i].y);
  }
}

// ---------------------------------------------------------------------------

extern "C" void kernel_launch(void* const* d_in, const int* in_sizes, int n_in,
                              void* d_out, int out_size, void* d_ws, size_t ws_size,
                              hipStream_t stream) {
  (void)in_sizes; (void)n_in; (void)out_size;

  const float* x_node = (const float*)d_in[0];
  const float* bases  = (const float*)d_in[1];
  const float* comp   = (const float*)d_in[2];
  const float* root   = (const float*)d_in[3];
  const float* rbias  = (const float*)d_in[4];
  const float* ep1w1  = (const float*)d_in[5];
  const float* ep1b1  = (const float*)d_in[6];
  const float* ep1w2  = (const float*)d_in[7];
  const float* ep1b2  = (const float*)d_in[8];
  const float* ep2w   = (const float*)d_in[9];
  const float* ep2b   = (const float*)d_in[10];
  const float* tp1w1  = (const float*)d_in[11];
  const float* tp1b1  = (const float*)d_in[12];
  const float* tp1w2  = (const float*)d_in[13];
  const float* tp1b2  = (const float*)d_in[14];
  const float* tp2w   = (const float*)d_in[15];
  const float* tp2b   = (const float*)d_in[16];
  const float* caw    = (const float*)d_in[17];
  const float* pp1w1  = (const float*)d_in[18];
  const float* pp1b1  = (const float*)d_in[19];
  const float* pp1w2  = (const float*)d_in[20];
  const float* pp1b2  = (const float*)d_in[21];
  const float* pp2w   = (const float*)d_in[22];
  const float* pp2b   = (const float*)d_in[23];
  const float* tokens = (const float*)d_in[24];
  const int* ei_kg = (const int*)d_in[25];
  const int* etype = (const int*)d_in[26];
  const int* ei_c  = (const int*)d_in[27];
  const int* ei_ts = (const int*)d_in[28];
  const int* ei_is = (const int*)d_in[29];
  const int* mte   = (const int*)d_in[30];
  const int* eids  = (const int*)d_in[31];

  float* O = (float*)d_out;
  unsigned short* xb    = (unsigned short*)(O + P_XB);
  unsigned short* wct2  = (unsigned short*)(O + P_WCT);
  float* rcpc  = O + P_CNT;
  float* ent0  = O + P_ENT0;
  unsigned short* aggb  = (unsigned short*)(O + P_HH);
  float* disc  = O + P_DIS;
  float* dist  = O + P_DIS + 30000;
  float* disi  = O + P_DIS + 36000;
  unsigned short* ent0b = (unsigned short*)(O + P_E0B);
  unsigned short* c1b   = (unsigned short*)(O + P_C1B);
  unsigned short* c2b   = (unsigned short*)(O + P_C2B);
  unsigned short* nfb   = (unsigned short*)(O + P_NFB);
  unsigned short* t1b   = (unsigned short*)(O + P_T1B);
  float* g1    = O + P_G1;
  float* accb  = O + P_ACC;
  unsigned short* entb  = (unsigned short*)(O + P_ENTB);
  unsigned short* hidb  = (unsigned short*)(O + P_HIDB);
  unsigned short* ent2b = (unsigned short*)(O + P_ENT2B);
  unsigned short* e768b = (unsigned short*)(O + P_E768B);
  unsigned short* tokb  = (unsigned short*)(O + P_TOKB);
  unsigned short* thidb = (unsigned short*)(O + P_THIDB);
  unsigned short* tok1b = (unsigned short*)(O + P_TOK1B);
  unsigned short* tok2b = (unsigned short*)(O + P_TOK2B);
  unsigned short* qb    = (unsigned short*)(O + P_QB);
  unsigned short* eemb  = (unsigned short*)(O + P_EEMB);
  float* pr0   = O + P_PR0;
  unsigned short* pr0b  = (unsigned short*)(O + P_PR0B);
  unsigned short* phidb = (unsigned short*)(O + P_PHIDB);
  unsigned short* wts   = (unsigned short*)(O + P_WT);

  int* iws = (int*)d_ws;
  unsigned short* p2b = (unsigned short*)d_ws;
  unsigned short* pp2t = (unsigned short*)d_ws + WS_PP2T_BYTE / 2;
  const bool ws_ok = (ws_size >= WS_NEED);
  int* cnt_i  = iws + I_CNT;
  int* part   = iws + I_PART;
  int* kg_rp  = iws + I_KG_RP;  int* kg_sl = iws + I_KG_SL;
  int* bnd12  = iws + I_BND12;  int* cur12 = iws + I_CUR12;
  int* c_rp   = iws + I_C_RP;   int* c_cur  = iws + I_C_CUR;   int* c_sl  = iws + I_C_SL;
  int* ts_rp  = iws + I_TS_RP;  int* ts_cur = iws + I_TS_CUR;  int* ts_sl = iws + I_TS_SL;
  int* is_rp  = iws + I_IS_RP;  int* is_cur = iws + I_IS_CUR;  int* is_sl = iws + I_IS_SL;

  const int EW = 256;

  // ---------------- phase A: conversions ----------------
  k_cvt<<<cdiv(NBf / 2, EW), EW, 0, stream>>>(x_node, xb, NBf / 2);
  k_wcat2<<<cdiv(12 * Dm * Dm, EW), EW, 0, stream>>>(comp, bases, wct2);
  k_cvt_t<<<dim3(Dm / 32, Dm / 32), 256, 0, stream>>>(root, wts + S_ROOT, Dm, Dm);
  k_cvt_t<<<dim3(192 / 32, Dm / 32), 256, 0, stream>>>(ep1w1, wts + S_EP1A, Dm, 192);
  k_cvt_t<<<dim3(Dm / 32, 192 / 32), 256, 0, stream>>>(ep1w2, wts + S_EP1B, 192, Dm);
  k_cvt_t<<<dim3(Hm / 32, Dm / 32), 256, 0, stream>>>(ep2w, wts + S_EP2, Dm, Hm);
  k_cvt_t<<<dim3(Dm / 32, Hm / 32), 256, 0, stream>>>(tp1w1, wts + S_TP1A, Hm, Dm);
  k_cvt_t<<<dim3(Hm / 32, Dm / 32), 256, 0, stream>>>(tp1w2, wts + S_TP1B, Dm, Hm);
  k_cvt_t<<<dim3(Hm / 32, Hm / 32), 256, 0, stream>>>(tp2w, wts + S_TP2, Hm, Hm);
  k_cvt_t<<<dim3(Hm / 32, Hm / 32), 256, 0, stream>>>(caw, wts + S_CAW, Hm, Hm);
  k_cvt_t<<<dim3(Dm / 32, Hm / 32), 256, 0, stream>>>(pp1w1, wts + S_PP1A, Hm, Dm);
  k_cvt_t<<<dim3(Hm / 32, Dm / 32), 256, 0, stream>>>(pp1w2, wts + S_PP1B, Dm, Hm);

  // ---------------- KG segmented CSR ----------------
  hipMemsetAsync(rcpc, 0, (size_t)12 * NE * 4, stream);
  k_count_type<<<cdiv(EKG, EW), EW, 0, stream>>>(ei_kg + EKG, etype, rcpc, EKG);
  hipMemsetAsync(cnt_i, 0, (size_t)NE * 4, stream);
  k_hist<<<cdiv(EKG, EW), EW, 0, stream>>>(ei_kg + EKG, cnt_i, EKG);
  {
    int nb = cdiv(NE, 256);
    k_scan_blk<<<nb, 256, 0, stream>>>(cnt_i, kg_rp, part, NE);
    k_scan_top<<<1, 256, 0, stream>>>(part, nb);
    k_scan_add<<<nb, 256, 0, stream>>>(kg_rp, part, NE);
  }
  k_seg<<<cdiv(NE, EW), EW, 0, stream>>>(rcpc, kg_rp, bnd12, NE);
  hipMemcpyAsync(cur12, bnd12, (size_t)NE * 12 * 4, hipMemcpyDeviceToDevice, stream);
  k_fill_kg<<<cdiv(EKG, EW), EW, 0, stream>>>(ei_kg, ei_kg + EKG, etype, cur12, kg_sl, EKG);
  k_rcp<<<cdiv((long)12 * NE, EW), EW, 0, stream>>>(rcpc, (size_t)12 * NE);

  // ---------------- other CSRs ----------------
  auto build_csr = [&](const int* ei, int n, int E, int* rp, int* cur, int* sl) {
    hipMemsetAsync(cnt_i, 0, (size_t)n * 4, stream);
    k_hist<<<cdiv(E, EW), EW, 0, stream>>>(ei + E, cnt_i, E);
    int nb = cdiv(n, 256);
    k_scan_blk<<<nb, 256, 0, stream>>>(cnt_i, rp, part, n);
    k_scan_top<<<1, 256, 0, stream>>>(part, nb);
    k_scan_add<<<nb, 256, 0, stream>>>(rp, part, n);
    hipMemcpyAsync(cur, rp, (size_t)n * 4, hipMemcpyDeviceToDevice, stream);
    k_fill<<<cdiv(E, EW), EW, 0, stream>>>(ei, ei + E, cur, sl, E);
  };
  build_csr(ei_c, NE, EC, c_rp, c_cur, c_sl);
  build_csr(ei_ts, NM, ES, ts_rp, ts_cur, ts_sl);
  build_csr(ei_is, NM, ES, is_rp, is_cur, is_sl);

  k_dis_rp<<<cdiv(NE, EW), EW, 0, stream>>>(c_rp, disc, NE, EC);
  k_dis_rp<<<cdiv(NM, EW), EW, 0, stream>>>(ts_rp, dist, NM, ES);
  k_dis_rp<<<cdiv(NM, EW), EW, 0, stream>>>(is_rp, disi, NM, ES);

  // ---------------- RGCN: aggregate-then-transform ----------------
  // ent0 = x @ root + bias + x
  mgemm_bf<false, true, 0><<<dim3(cdiv(NE, 128), cdiv(Dm, 128)), 256, 0, stream>>>(
      xb, wts + S_ROOT, rbias, x_node, ent0, NE, Dm, Dm);
  // rels 0..5: agg then ent0 += agg @ W (K=2304)
  k_agg6<true><<<cdiv((long)NE * 64, EW), EW, 0, stream>>>(
      xb, rcpc, kg_rp, bnd12, kg_sl, aggb, EKG);
  mgemm_bf<false, true, 0><<<dim3(cdiv(NE, 128), cdiv(Dm, 128)), 256, 0, stream>>>(
      aggb, wct2, nullptr, ent0, ent0, NE, Dm, 6 * Dm);
  // rels 6..11
  k_agg6<false><<<cdiv((long)NE * 64, EW), EW, 0, stream>>>(
      xb, rcpc, kg_rp, bnd12, kg_sl, aggb, EKG);
  mgemm_bf<false, true, 0><<<dim3(cdiv(NE, 128), cdiv(Dm, 128)), 256, 0, stream>>>(
      aggb, wct2 + 884736, nullptr, ent0, ent0, NE, Dm, 6 * Dm);
  // ent0b bf16 (over dead xb)
  k_cvt<<<cdiv(NBf / 2, EW), EW, 0, stream>>>(ent0, ent0b, NBf / 2);

  // ---------------- phase B: graph chains (bf16) ----------------
  k_gather_b<<<cdiv((long)NM * 192, EW), EW, 0, stream>>>(
      mte, (const uint32_t*)ent0b, (uint32_t*)nfb, NM, 192);
  k_gcn_gb<1, 3><<<cdiv((long)NM * 64, EW), EW, 0, stream>>>(
      nfb, dist, ts_rp, ts_sl, t1b, g1, NM, ES, 1.0f);
  k_gcn_gb<0, 1><<<cdiv((long)NM * 64, EW), EW, 0, stream>>>(
      t1b, dist, ts_rp, ts_sl, nullptr, g1, NM, ES, 1.0f);
  k_gcn_gb<1, 1><<<cdiv((long)NM * 64, EW), EW, 0, stream>>>(
      nfb, disi, is_rp, is_sl, t1b, g1, NM, ES, 1.0f);
  k_gcn_gb<0, 1><<<cdiv((long)NM * 64, EW), EW, 0, stream>>>(
      t1b, disi, is_rp, is_sl, nullptr, g1, NM, ES, 1.0f);
  // entity chain (0.25 folded)
  k_gcn_gb<1, 2><<<cdiv((long)NE * 64, EW), EW, 0, stream>>>(
      ent0b, disc, c_rp, c_sl, c1b, accb, NE, EC, 0.25f);
  k_gcn_gb<1, 1><<<cdiv((long)NE * 64, EW), EW, 0, stream>>>(
      c1b, disc, c_rp, c_sl, c2b, accb, NE, EC, 0.25f);
  k_scatter_movie<<<cdiv(MBF, EW), EW, 0, stream>>>(mte, g1, accb);
  k_gcn_gb<2, 1><<<cdiv((long)NE * 64, EW), EW, 0, stream>>>(
      c2b, disc, c_rp, c_sl, entb, accb, NE, EC, 0.25f);

  // pp2t conversion (CSR arrays now dead)
  if (ws_ok) {
    k_cvt_t<<<dim3(NO / 32, Hm / 32), 256, 0, stream>>>(pp2w, pp2t, Hm, NO);
  }

  // ---------------- entity MLP ----------------
  mgemm_bf<true, false, 1><<<dim3(cdiv(NE, 128), cdiv(192, 128)), 256, 0, stream>>>(
      entb, wts + S_EP1A, ep1b1, nullptr, hidb, NE, 192, Dm);
  mgemm_bf<false, true, 1><<<dim3(cdiv(NE, 128), cdiv(Dm, 128)), 256, 0, stream>>>(
      hidb, wts + S_EP1B, ep1b2, accb, ent2b, NE, Dm, 192);
  mgemm_bf<false, false, 1><<<dim3(cdiv(NE, 128), cdiv(Hm, 128)), 256, 0, stream>>>(
      ent2b, wts + S_EP2, ep2b, nullptr, e768b, NE, Hm, Dm);

  // ---------------- token path ----------------
  k_cvt<<<cdiv((long)NTOK * Hm / 2, EW), EW, 0, stream>>>(tokens, tokb, (size_t)NTOK * Hm / 2);
  mgemm_bf<true, false, 1><<<dim3(cdiv(NTOK, 128), cdiv(Dm, 128)), 256, 0, stream>>>(
      tokb, wts + S_TP1A, tp1b1, nullptr, thidb, NTOK, Dm, Hm);
  mgemm_bf<false, true, 1><<<dim3(cdiv(NTOK, 128), cdiv(Hm, 128)), 256, 0, stream>>>(
      thidb, wts + S_TP1B, tp1b2, tokens, tok1b, NTOK, Hm, Dm);
  mgemm_bf<false, false, 1><<<dim3(cdiv(NTOK, 128), cdiv(Hm, 128)), 256, 0, stream>>>(
      tok1b, wts + S_TP2, tp2b, nullptr, tok2b, NTOK, Hm, Hm);
  mgemm_bf<false, false, 1><<<dim3(cdiv(NTOK, 128), cdiv(Hm, 128)), 256, 0, stream>>>(
      tok2b, wts + S_CAW, nullptr, nullptr, qb, NTOK, Hm, Hm);

  k_gather_b<<<cdiv((long)Bc * LE * (Hm / 2), EW), EW, 0, stream>>>(
      eids, (const uint32_t*)e768b, (uint32_t*)eemb, Bc * LE, Hm / 2);
  k_attn<<<cdiv((long)NTOK * 64, 256), 256, 0, stream>>>(qb, eemb, tok2b, pr0, pr0b);

  mgemm_bf<true, false, 1><<<dim3(cdiv(NTOK, 128), cdiv(Dm, 128)), 256, 0, stream>>>(
      pr0b, wts + S_PP1A, pp1b1, nullptr, phidb, NTOK, Dm, Hm);
  mgemm_bf<false, true, 1><<<dim3(cdiv(NTOK, 128), cdiv(Hm, 128)), 256, 0, stream>>>(
      phidb, wts + S_PP1B, pp1b2, pr0, p2b, NTOK, Hm, Dm);

  // ---------------- final GEMM + transpose (reads ONLY d_ws/d_in) ---------
  if (ws_ok) {
    mgemm_bf<false, false, 2><<<dim3(NTOK / 128, NO / 128), 256, 0, stream>>>(
        p2b, pp2t, pp2b, nullptr, O, NTOK, NO, Hm);
  } else {
    mgemm_fin<<<dim3(NTOK / 128, NO / 128), 256, 0, stream>>>(
        p2b, pp2w, pp2b, O, NTOK, NO, Hm);
  }
}

// Round 11
// 1564.888 us; speedup vs baseline: 1.0628x; 1.0628x over previous
//
#include <hip/hip_runtime.h>
#include <hip/hip_bf16.h>
#include <cstdint>
#include <cstddef>

// ---------------------------------------------------------------------------
// MMPrompt pipeline, round 11 = r9 (1638us, split-CSR RGCN gathers - proven)
//   + r10's final-GEMM epilogue decomposition (296us final - proven).
//   r10's agg-then-transform RGCN reverted (cost ~84us).
// ---------------------------------------------------------------------------

namespace {

constexpr int NE   = 30000;
constexpr int NM   = 6000;
constexpr int Dm   = 384;
constexpr int Hm   = 768;
constexpr int EKG  = 200000;
constexpr int EC   = 200000;
constexpr int ES   = 80000;
constexpr int Bc   = 16;
constexpr int LE   = 48;
constexpr int NTOK = 4096;
constexpr int NO   = 18432;

constexpr size_t NBf = (size_t)NE * Dm;   // 11,520,000
constexpr size_t MBF = (size_t)NM * Dm;   // 2,304,000

// ---------------- d_out arena (f32-unit offsets) ----------------
// phase A (conversions + RGCN)
constexpr size_t P_XB    = 0;          // xb bf16 NE*384           ends 5,760,000
constexpr size_t P_WCT   = 5760000;    // wcat_t bf16 12*384*384   ends 6,644,736
constexpr size_t P_CNT   = 6644736;    // rcp cnt f32 12*NE        ends 7,004,736
constexpr size_t P_ENT0  = 7004736;    // f32 NE*384               ends 18,524,736
constexpr size_t P_HH    = 18524736;   // h bf16 NE*2304           ends 53,084,736
constexpr size_t P_DIS   = 53084736;   // disc+dist+disi f32       ends 53,126,736
// phase B (graph chains)
constexpr size_t P_E0B   = 0;          // ent0b bf16 NE*384  ends 2,880,000
constexpr size_t P_C1B   = 2880000;    // bf16 NE*384        ends 5,760,000
constexpr size_t P_C2B   = 5760000;    // bf16 NE*384        ends 8,640,000
constexpr size_t P_NFB   = 8640000;    // bf16 NM*384        ends 9,792,000
constexpr size_t P_T1B   = 9800000;    // bf16 NM*384        ends 10,952,000
constexpr size_t P_G1    = 11000000;   // f32 NM*384         ends 13,304,000
constexpr size_t P_ACC   = 41564736;   // f32 NE*384 (over dead hh) ends 53,084,736
constexpr size_t P_ENTB  = 55600000;   // bf16 NE*384        ends 61,360,000
// phase C
constexpr size_t P_HIDB  = 0;          // bf16 NE*192
constexpr size_t P_ENT2B = 2880000;    // bf16 NE*384
constexpr size_t P_E768B = 8640000;    // bf16 NE*768   ends 20,160,000
constexpr size_t P_TOKB  = 20160000;   // bf16 4096*768
constexpr size_t P_THIDB = 21732864;   // bf16 4096*384
constexpr size_t P_TOK1B = 22519296;   // bf16 4096*768
constexpr size_t P_TOK2B = 24092160;   // bf16 4096*768
constexpr size_t P_QB    = 25665024;   // bf16 4096*768
constexpr size_t P_EEMB  = 27237888;   // bf16 768*Hm
constexpr size_t P_PR0   = 27532800;   // f32 4096*768
constexpr size_t P_PR0B  = 30678528;   // bf16 4096*768
constexpr size_t P_PHIDB = 32251392;   // bf16 4096*384 ends 33,037,824
// whole-launch small weights (never read by the final GEMM)
constexpr size_t P_WT    = 74000000;   // ends < 75,497,472
constexpr size_t S_ROOT  = 0;
constexpr size_t S_EP1A  = 147456;
constexpr size_t S_EP1B  = 221184;
constexpr size_t S_EP2   = 294912;
constexpr size_t S_TP1A  = 589824;
constexpr size_t S_TP1B  = 884736;
constexpr size_t S_TP2   = 1179648;
constexpr size_t S_CAW   = 1769472;
constexpr size_t S_PP1A  = 2359296;
constexpr size_t S_PP1B  = 2654208;

// ---------------- d_ws layout (bytes) ----------------
constexpr size_t WI       = 6291456 / 4;
constexpr size_t I_CNT    = WI + 0;
constexpr size_t I_PART   = WI + 30000;
constexpr size_t I_KG_RP  = WI + 30256;
constexpr size_t I_KG_CA  = WI + 60256;   // cur for r<6 half
constexpr size_t I_KG_SL  = WI + 90256;
constexpr size_t I_C_RP   = WI + 290256;
constexpr size_t I_C_CUR  = WI + 320256;
constexpr size_t I_C_SL   = WI + 350256;
constexpr size_t I_TS_RP  = WI + 550256;
constexpr size_t I_TS_CUR = WI + 556256;
constexpr size_t I_TS_SL  = WI + 562256;
constexpr size_t I_IS_RP  = WI + 642256;
constexpr size_t I_IS_CUR = WI + 648256;
constexpr size_t I_IS_SL  = WI + 654256;  // ends WI+734,256
constexpr size_t I_KG_BND = WI + 734256;  // 30000
constexpr size_t I_KG_CB  = WI + 764256;  // 30000
constexpr size_t WS_PP2T_BYTE = 6291456;  // overlays CSR after its death
constexpr size_t WS_NEED      = 34603008;

inline int cdiv(long a, long b) { return (int)((a + b - 1) / b); }

} // namespace

typedef short short8v __attribute__((ext_vector_type(8)));
typedef float f32x4 __attribute__((ext_vector_type(4)));

__device__ __forceinline__ unsigned short f2bf(float f) {
  union { float f; uint32_t u; } v; v.f = f;
  uint32_t u = v.u;
  u += 0x7fffu + ((u >> 16) & 1u);
  return (unsigned short)(u >> 16);
}
__device__ __forceinline__ uint32_t pkbf(float a, float b) {
  __hip_bfloat162 h = __float22bfloat162_rn(float2{a, b});
  union { __hip_bfloat162 h; uint32_t u; } cv; cv.h = h;
  return cv.u;
}
__device__ __forceinline__ float bflo(uint32_t u) {
  union { uint32_t u; float f; } c; c.u = u << 16; return c.f;
}
__device__ __forceinline__ float bfhi(uint32_t u) {
  union { uint32_t u; float f; } c; c.u = u & 0xFFFF0000u; return c.f;
}

__device__ __forceinline__ void gl16(const void* g, void* l) {
  __builtin_amdgcn_global_load_lds(
      (const __attribute__((address_space(1))) void*)g,
      (__attribute__((address_space(3))) void*)l, 16, 0, 0);
}

// ---------------------------------------------------------------------------
// conversion / utility kernels
// ---------------------------------------------------------------------------

__global__ void k_cvt(const float* __restrict__ x, unsigned short* __restrict__ o, size_t n2) {
  size_t i = (size_t)blockIdx.x * 256 + threadIdx.x;
  if (i >= n2) return;
  float2 v = *(const float2*)(x + 2 * i);
  *(uint32_t*)(o + 2 * i) = pkbf(v.x, v.y);
}

// f32 W[K][N] -> bf16 Wt[N][K]
__global__ void k_cvt_t(const float* __restrict__ W, unsigned short* __restrict__ Wt,
                        int K, int N) {
  __shared__ float t[32][33];
  int tx = threadIdx.x & 31, ty = threadIdx.x >> 5;
  int n0 = blockIdx.x * 32, k0 = blockIdx.y * 32;
#pragma unroll
  for (int j = 0; j < 4; ++j)
    t[ty + 8 * j][tx] = W[(size_t)(k0 + ty + 8 * j) * N + n0 + tx];
  __syncthreads();
#pragma unroll
  for (int j = 0; j < 4; ++j) {
    int n = ty + 8 * j;
    Wt[(size_t)(n0 + n) * K + k0 + tx] = f2bf(t[tx][n]);
  }
}

// wcat_t[(r*384+o)*384 + i] = sum_b comp[r][b]*bases[b][i][o]  (bf16)
__global__ void k_wcat(const float* __restrict__ comp, const float* __restrict__ bases,
                       unsigned short* __restrict__ Wt) {
  int idx = blockIdx.x * 256 + threadIdx.x;
  if (idx >= 12 * Dm * Dm) return;
  int i = idx % Dm;
  int o = (idx / Dm) % Dm;
  int r = idx / (Dm * Dm);
  float s = 0.f;
#pragma unroll
  for (int b = 0; b < 8; ++b)
    s += comp[r * 8 + b] * bases[(size_t)b * Dm * Dm + (size_t)i * Dm + o];
  Wt[idx] = f2bf(s);
}

// gather bf16 rows as u32 chunks
__global__ void k_gather_b(const int* __restrict__ idx, const uint32_t* __restrict__ x2,
                           uint32_t* __restrict__ out2, int rows, int D2) {
  size_t i = (size_t)blockIdx.x * 256 + threadIdx.x;
  if (i >= (size_t)rows * D2) return;
  int r = (int)(i / D2);
  int c = (int)(i - (size_t)r * D2);
  out2[i] = x2[(size_t)idx[r] * D2 + c];
}

// ent[mte[m]][d] += 0.25*g[m][d]
__global__ void k_scatter_movie(const int* __restrict__ mte, const float* __restrict__ g,
                                float* __restrict__ ent) {
  size_t i = (size_t)blockIdx.x * 256 + threadIdx.x;
  if (i >= MBF) return;
  int m = (int)(i / Dm);
  int d = (int)(i - (size_t)m * Dm);
  atomicAdd(&ent[(size_t)mte[m] * Dm + d], 0.25f * g[i]);
}

// ---------------------------------------------------------------------------
// CSR build
// ---------------------------------------------------------------------------

__global__ void k_hist(const int* __restrict__ dst, int* __restrict__ cnt, int E) {
  int e = blockIdx.x * 256 + threadIdx.x;
  if (e < E) atomicAdd(&cnt[dst[e]], 1);
}

__global__ void k_hist_lt(const int* __restrict__ dst, const int* __restrict__ typ,
                          int* __restrict__ cnt, int E) {
  int e = blockIdx.x * 256 + threadIdx.x;
  if (e < E && typ[e] < 6) atomicAdd(&cnt[dst[e]], 1);
}

__global__ void k_add_i(const int* __restrict__ a, const int* __restrict__ b,
                        int* __restrict__ o, int n) {
  int i = blockIdx.x * 256 + threadIdx.x;
  if (i < n) o[i] = a[i] + b[i];
}

__global__ void k_scan_blk(const int* __restrict__ in, int* __restrict__ out,
                           int* __restrict__ part, int n) {
  __shared__ int s[256];
  int t = threadIdx.x;
  int g = blockIdx.x * 256 + t;
  int v = (g < n) ? in[g] : 0;
  s[t] = v;
  __syncthreads();
  for (int off = 1; off < 256; off <<= 1) {
    int add = (t >= off) ? s[t - off] : 0;
    __syncthreads();
    s[t] += add;
    __syncthreads();
  }
  if (g < n) out[g] = s[t] - v;
  if (t == 255) part[blockIdx.x] = s[255];
}

__global__ void k_scan_top(int* __restrict__ part, int nb) {
  __shared__ int s[256];
  int t = threadIdx.x;
  int v = (t < nb) ? part[t] : 0;
  s[t] = v;
  __syncthreads();
  for (int off = 1; off < 256; off <<= 1) {
    int add = (t >= off) ? s[t - off] : 0;
    __syncthreads();
    s[t] += add;
    __syncthreads();
  }
  if (t < nb) part[t] = s[t] - v;
}

__global__ void k_scan_add(int* __restrict__ out, const int* __restrict__ part, int n) {
  int g = blockIdx.x * 256 + threadIdx.x;
  if (g < n) out[g] += part[blockIdx.x];
}

__global__ void k_fill(const int* __restrict__ src, const int* __restrict__ dst,
                       int* __restrict__ cur, int* __restrict__ slots, int E) {
  int e = blockIdx.x * 256 + threadIdx.x;
  if (e >= E) return;
  int d = dst[e];
  int pos = atomicAdd(&cur[d], 1);
  slots[pos] = src[e];
}

// split fill: typ<6 edges go to [rp, bnd), others to [bnd, rp_next)
__global__ void k_fill_split(const int* __restrict__ src, const int* __restrict__ dst,
                             const int* __restrict__ typ, int* __restrict__ cur_a,
                             int* __restrict__ cur_b, int* __restrict__ slots, int E) {
  int e = blockIdx.x * 256 + threadIdx.x;
  if (e >= E) return;
  int d = dst[e];
  int* c = (typ[e] < 6) ? cur_a : cur_b;
  int pos = atomicAdd(&c[d], 1);
  slots[pos] = src[e] | (typ[e] << 16);
}

__global__ void k_dis_rp(const int* __restrict__ rp, float* __restrict__ dis, int n, int E) {
  int v = blockIdx.x * 256 + threadIdx.x;
  if (v >= n) return;
  int e0 = rp[v], e1 = (v + 1 < n) ? rp[v + 1] : E;
  dis[v] = rsqrtf((float)(e1 - e0) + 1.0f);
}

__global__ void k_count_type(const int* __restrict__ dst, const int* __restrict__ typ,
                             float* __restrict__ cnt, int E) {
  int i = blockIdx.x * 256 + threadIdx.x;
  if (i < E) atomicAdd(&cnt[(size_t)typ[i] * NE + dst[i]], 1.0f);
}

__global__ void k_rcp(float* __restrict__ c, size_t n) {
  size_t i = (size_t)blockIdx.x * 256 + threadIdx.x;
  if (i < n) { float v = c[i]; c[i] = (v > 0.f) ? 1.0f / v : 0.f; }
}

// ---------------------------------------------------------------------------
// bf16 GCN gather (one wave per dst row, 2-edge unrolled).
// OUTM: 0 none, 1 outb = bf16(a), 2 outb = bf16(acc_new).
// ACCM: 1 acc += sc*a; 2 acc = sc*(x[v]+a); 3 acc = sc*a.
// ---------------------------------------------------------------------------
template <int OUTM, int ACCM>
__global__ void k_gcn_gb(const unsigned short* __restrict__ x,
                         const float* __restrict__ dis,
                         const int* __restrict__ rp, const int* __restrict__ slots,
                         unsigned short* __restrict__ outb, float* __restrict__ acc,
                         int n, int E, float sc) {
  int v = (int)((blockIdx.x * (size_t)blockDim.x + threadIdx.x) >> 6);
  int lane = threadIdx.x & 63;
  if (v >= n) return;
  float dv = dis[v];
  const uint32_t* xr = (const uint32_t*)(x + (size_t)v * Dm);
  float xv[6];
#pragma unroll
  for (int i = 0; i < 3; ++i) {
    uint32_t u = xr[lane + 64 * i];
    xv[2 * i] = bflo(u); xv[2 * i + 1] = bfhi(u);
  }
  float a[6];
#pragma unroll
  for (int i = 0; i < 6; ++i) a[i] = dv * xv[i];
  int e0 = rp[v], e1 = (v + 1 < n) ? rp[v + 1] : E;
  int e = e0;
  for (; e + 2 <= e1; e += 2) {
    int s0 = slots[e], s1 = slots[e + 1];
    float c0 = dis[s0], c1 = dis[s1];
    const uint32_t* x0 = (const uint32_t*)(x + (size_t)s0 * Dm);
    const uint32_t* x1 = (const uint32_t*)(x + (size_t)s1 * Dm);
    uint32_t u0[3], u1[3];
#pragma unroll
    for (int i = 0; i < 3; ++i) { u0[i] = x0[lane + 64 * i]; u1[i] = x1[lane + 64 * i]; }
#pragma unroll
    for (int i = 0; i < 3; ++i) {
      a[2 * i]     = fmaf(c0, bflo(u0[i]), a[2 * i]);
      a[2 * i + 1] = fmaf(c0, bfhi(u0[i]), a[2 * i + 1]);
      a[2 * i]     = fmaf(c1, bflo(u1[i]), a[2 * i]);
      a[2 * i + 1] = fmaf(c1, bfhi(u1[i]), a[2 * i + 1]);
    }
  }
  if (e < e1) {
    int s0 = slots[e];
    float c0 = dis[s0];
    const uint32_t* x0 = (const uint32_t*)(x + (size_t)s0 * Dm);
#pragma unroll
    for (int i = 0; i < 3; ++i) {
      uint32_t u = x0[lane + 64 * i];
      a[2 * i]     = fmaf(c0, bflo(u), a[2 * i]);
      a[2 * i + 1] = fmaf(c0, bfhi(u), a[2 * i + 1]);
    }
  }
#pragma unroll
  for (int i = 0; i < 6; ++i) a[i] *= dv;
  if (OUTM == 1) {
    uint32_t* ob = (uint32_t*)(outb + (size_t)v * Dm);
#pragma unroll
    for (int i = 0; i < 3; ++i) ob[lane + 64 * i] = pkbf(a[2 * i], a[2 * i + 1]);
  }
  float* ar = acc + (size_t)v * Dm;
  float nw[6];
#pragma unroll
  for (int i = 0; i < 3; ++i) {
    int cidx = 2 * (lane + 64 * i);
    if (ACCM == 1) {
      float2 old = *(const float2*)(ar + cidx);
      nw[2 * i] = old.x + sc * a[2 * i];
      nw[2 * i + 1] = old.y + sc * a[2 * i + 1];
    } else if (ACCM == 2) {
      nw[2 * i] = sc * (xv[2 * i] + a[2 * i]);
      nw[2 * i + 1] = sc * (xv[2 * i + 1] + a[2 * i + 1]);
    } else {
      nw[2 * i] = sc * a[2 * i];
      nw[2 * i + 1] = sc * a[2 * i + 1];
    }
    *(float2*)(ar + cidx) = float2{nw[2 * i], nw[2 * i + 1]};
  }
  if (OUTM == 2) {
    uint32_t* ob = (uint32_t*)(outb + (size_t)v * Dm);
#pragma unroll
    for (int i = 0; i < 3; ++i) ob[lane + 64 * i] = pkbf(nw[2 * i], nw[2 * i + 1]);
  }
}

// ---------------------------------------------------------------------------
// RGCN gather, split-range (FIRST: r<6 edges in [rp,bnd); else [bnd,rp_next)),
// 2-edge unrolled, filter-free. EMITB: also emit ent0b bf16 (last call).
// ---------------------------------------------------------------------------
template <bool FIRST, bool EMITB>
__global__ void k_rgcn_g(const unsigned short* __restrict__ hh, const float* __restrict__ rcp,
                         const int* __restrict__ rp, const int* __restrict__ bnd,
                         const int* __restrict__ slots, float* __restrict__ ent0,
                         unsigned short* __restrict__ outb, int E) {
  int v = (int)((blockIdx.x * (size_t)blockDim.x + threadIdx.x) >> 6);
  int lane = threadIdx.x & 63;
  if (v >= NE) return;
  const int rbase = FIRST ? 0 : 6;
  int e0, e1;
  if (FIRST) { e0 = rp[v]; e1 = bnd[v]; }
  else       { e0 = bnd[v]; e1 = (v + 1 < NE) ? rp[v + 1] : E; }
  float* er = ent0 + (size_t)v * Dm;
  float2 a[3];
#pragma unroll
  for (int i = 0; i < 3; ++i) a[i] = *(const float2*)(er + 2 * lane + 128 * i);
  int e = e0;
  for (; e + 2 <= e1; e += 2) {
    int p0 = slots[e], p1 = slots[e + 1];
    int r0 = (p0 >> 16) - rbase, s0 = p0 & 0xFFFF;
    int r1 = (p1 >> 16) - rbase, s1 = p1 & 0xFFFF;
    float nm0 = rcp[(size_t)(r0 + rbase) * NE + v];
    float nm1 = rcp[(size_t)(r1 + rbase) * NE + v];
    const uint32_t* h0 = (const uint32_t*)(hh + (size_t)s0 * 2304 + (size_t)r0 * 384);
    const uint32_t* h1 = (const uint32_t*)(hh + (size_t)s1 * 2304 + (size_t)r1 * 384);
    uint32_t u0[3], u1[3];
#pragma unroll
    for (int i = 0; i < 3; ++i) { u0[i] = h0[lane + 64 * i]; u1[i] = h1[lane + 64 * i]; }
#pragma unroll
    for (int i = 0; i < 3; ++i) {
      a[i].x = fmaf(nm0, bflo(u0[i]), a[i].x);
      a[i].y = fmaf(nm0, bfhi(u0[i]), a[i].y);
      a[i].x = fmaf(nm1, bflo(u1[i]), a[i].x);
      a[i].y = fmaf(nm1, bfhi(u1[i]), a[i].y);
    }
  }
  if (e < e1) {
    int p0 = slots[e];
    int r0 = (p0 >> 16) - rbase, s0 = p0 & 0xFFFF;
    float nm0 = rcp[(size_t)(r0 + rbase) * NE + v];
    const uint32_t* h0 = (const uint32_t*)(hh + (size_t)s0 * 2304 + (size_t)r0 * 384);
#pragma unroll
    for (int i = 0; i < 3; ++i) {
      uint32_t u = h0[lane + 64 * i];
      a[i].x = fmaf(nm0, bflo(u), a[i].x);
      a[i].y = fmaf(nm0, bfhi(u), a[i].y);
    }
  }
#pragma unroll
  for (int i = 0; i < 3; ++i) *(float2*)(er + 2 * lane + 128 * i) = a[i];
  if (EMITB) {
    uint32_t* ob = (uint32_t*)(outb + (size_t)v * Dm);
#pragma unroll
    for (int i = 0; i < 3; ++i) ob[lane + 64 * i] = pkbf(a[i].x, a[i].y);
  }
}

// ---------------------------------------------------------------------------
// bf16 MFMA GEMM, 128x128 (m97 structure). A[M][K], Wt[N][K] bf16.
// OUT: 0 = f32 C, 1 = bf16 C, 2 = f32 transposed prompt layout (decomposed).
// ---------------------------------------------------------------------------
template <bool RELU, bool RES, int OUT>
__global__ __launch_bounds__(256) void mgemm_bf(
    const unsigned short* __restrict__ A, const unsigned short* __restrict__ Wt,
    const float* __restrict__ bias, const float* __restrict__ Rp,
    void* __restrict__ Cv, int M, int N, int K) {
  __shared__ __align__(16) unsigned short As[128 * 64];
  __shared__ __align__(16) unsigned short Bs[128 * 64];
  const int tid = threadIdx.x;
  const int lane = tid & 63;
  const int w = tid >> 6;
  const int bm = blockIdx.x * 128, bn = blockIdx.y * 128;
  const int wr = (w >> 1) * 64, wc = (w & 1) * 64;
  const int lrow = lane & 15, lq = lane >> 4;
  f32x4 acc[4][4] = {};
  const int prow_l = lane >> 3;
  const int pslot = lane & 7;

  for (int k0 = 0; k0 < K; k0 += 64) {
    __syncthreads();
#pragma unroll
    for (int j = 0; j < 4; ++j) {
      int seg = j * 4 + w;
      int prow = seg * 8 + prow_l;
      int aslot = pslot ^ (prow & 7);
      int arow = min(bm + prow, M - 1);
      gl16(A + (size_t)arow * K + k0 + aslot * 8, &As[seg * 512 + lane * 8]);
    }
#pragma unroll
    for (int j = 0; j < 4; ++j) {
      int seg = j * 4 + w;
      int prow = seg * 8 + prow_l;
      int bslot = pslot ^ (prow & 7);
      int brow = min(bn + prow, N - 1);
      gl16(Wt + (size_t)brow * K + k0 + bslot * 8, &Bs[seg * 512 + lane * 8]);
    }
    __syncthreads();
#pragma unroll
    for (int ks = 0; ks < 2; ++ks) {
      short8v af[4], bf[4];
      const int slot = ks * 4 + lq;
#pragma unroll
      for (int mr = 0; mr < 4; ++mr) {
        int r = wr + mr * 16 + lrow;
        af[mr] = *(const short8v*)&As[r * 64 + ((slot ^ (r & 7)) << 3)];
      }
#pragma unroll
      for (int nc = 0; nc < 4; ++nc) {
        int r = wc + nc * 16 + lrow;
        bf[nc] = *(const short8v*)&Bs[r * 64 + ((slot ^ (r & 7)) << 3)];
      }
#pragma unroll
      for (int mr = 0; mr < 4; ++mr)
#pragma unroll
        for (int nc = 0; nc < 4; ++nc)
          acc[mr][nc] = __builtin_amdgcn_mfma_f32_16x16x32_bf16(
              af[mr], bf[nc], acc[mr][nc], 0, 0, 0);
    }
  }
  // epilogue
  size_t colb[4];
  if (OUT == 2) {
#pragma unroll
    for (int nc = 0; nc < 4; ++nc) {
      int c = bn + wc + nc * 16 + lrow;
      int l = c / 1536, rem = c - l * 1536;
      int blk = rem / 768, rem2 = rem - blk * 768;
      int h2 = rem2 >> 6, dd = rem2 & 63;
      colb[nc] = (size_t)(l * 2 + blk) * 3145728 + (size_t)h2 * 16384 + dd;
    }
  }
#pragma unroll
  for (int mr = 0; mr < 4; ++mr) {
#pragma unroll
    for (int e = 0; e < 4; ++e) {
      int r = bm + wr + mr * 16 + lq * 4 + e;
      if (r >= M) continue;
      size_t rowoff = 0;
      if (OUT == 2) rowoff = (size_t)r * 64 + (size_t)(r >> 8) * 180224;
#pragma unroll
      for (int nc = 0; nc < 4; ++nc) {
        int c = bn + wc + nc * 16 + lrow;
        if (c >= N) continue;
        float v = acc[mr][nc][e];
        if (bias) v += bias[c];
        if (RES) v += Rp[(size_t)r * N + c];
        if (RELU) v = fmaxf(v, 0.f);
        if (OUT == 0) {
          ((float*)Cv)[(size_t)r * N + c] = v;
        } else if (OUT == 1) {
          ((unsigned short*)Cv)[(size_t)r * N + c] = f2bf(v);
        } else {
          ((float*)Cv)[colb[nc] + rowoff] = v;
        }
      }
    }
  }
}

// Fallback FINAL GEMM (ws too small): W f32 from d_in, in-kernel conversion.
__global__ __launch_bounds__(256) void mgemm_fin(
    const unsigned short* __restrict__ A, const float* __restrict__ W,
    const float* __restrict__ bias, float* __restrict__ O, int M, int N, int K) {
  __shared__ __align__(16) unsigned short As[128 * 64];
  __shared__ __align__(16) unsigned short Bs[128 * 64];
  const int tid = threadIdx.x;
  const int lane = tid & 63;
  const int w = tid >> 6;
  const int bm = blockIdx.x * 128, bn = blockIdx.y * 128;
  const int wr = (w >> 1) * 64, wc = (w & 1) * 64;
  const int lrow = lane & 15, lq = lane >> 4;
  f32x4 acc[4][4] = {};
  const int prow_l = lane >> 3;
  const int pslot = lane & 7;
  const int n_loc = tid & 127;
  const int kh = (tid >> 7) * 32;

  for (int k0 = 0; k0 < K; k0 += 64) {
    __syncthreads();
#pragma unroll
    for (int j = 0; j < 4; ++j) {
      int seg = j * 4 + w;
      int prow = seg * 8 + prow_l;
      int aslot = pslot ^ (prow & 7);
      gl16(A + (size_t)(bm + prow) * K + k0 + aslot * 8, &As[seg * 512 + lane * 8]);
    }
    float wv[32];
    const float* wp = W + (size_t)(k0 + kh) * N + bn + n_loc;
#pragma unroll
    for (int j = 0; j < 32; ++j) wv[j] = wp[(size_t)j * N];
#pragma unroll
    for (int c = 0; c < 4; ++c) {
      uint32_t u0 = pkbf(wv[8 * c + 0], wv[8 * c + 1]);
      uint32_t u1 = pkbf(wv[8 * c + 2], wv[8 * c + 3]);
      uint32_t u2 = pkbf(wv[8 * c + 4], wv[8 * c + 5]);
      uint32_t u3 = pkbf(wv[8 * c + 6], wv[8 * c + 7]);
      int s = (kh >> 3) + c;
      *(uint4*)&Bs[n_loc * 64 + ((s ^ (n_loc & 7)) << 3)] = uint4{u0, u1, u2, u3};
    }
    __syncthreads();
#pragma unroll
    for (int ks = 0; ks < 2; ++ks) {
      short8v af[4], bf[4];
      const int slot = ks * 4 + lq;
#pragma unroll
      for (int mr = 0; mr < 4; ++mr) {
        int r = wr + mr * 16 + lrow;
        af[mr] = *(const short8v*)&As[r * 64 + ((slot ^ (r & 7)) << 3)];
      }
#pragma unroll
      for (int nc = 0; nc < 4; ++nc) {
        int r = wc + nc * 16 + lrow;
        bf[nc] = *(const short8v*)&Bs[r * 64 + ((slot ^ (r & 7)) << 3)];
      }
#pragma unroll
      for (int mr = 0; mr < 4; ++mr)
#pragma unroll
        for (int nc = 0; nc < 4; ++nc)
          acc[mr][nc] = __builtin_amdgcn_mfma_f32_16x16x32_bf16(
              af[mr], bf[nc], acc[mr][nc], 0, 0, 0);
    }
  }
#pragma unroll
  for (int mr = 0; mr < 4; ++mr) {
#pragma unroll
    for (int e = 0; e < 4; ++e) {
      int r = bm + wr + mr * 16 + lq * 4 + e;
      int b = r >> 8, t = r & 255;
#pragma unroll
      for (int nc = 0; nc < 4; ++nc) {
        int c = bn + wc + nc * 16 + lrow;
        float v = acc[mr][nc][e] + bias[c];
        int l = c / 1536, rem = c - l * 1536;
        int blk = rem / 768, rem2 = rem - blk * 768;
        int hh = rem2 >> 6, dd = rem2 & 63;
        size_t oi = (((((size_t)l * 2 + blk) * 16 + b) * 12 + hh) * 256 + t) * 64 + dd;
        O[oi] = v;
      }
    }
  }
}

// ---------------------------------------------------------------------------
// fused cross-attention (bf16 inputs): one wave per (b,t)
// ---------------------------------------------------------------------------
__global__ __launch_bounds__(256) void k_attn(
    const unsigned short* __restrict__ qb, const unsigned short* __restrict__ eb_all,
    const unsigned short* __restrict__ tokb, float* __restrict__ pr0,
    unsigned short* __restrict__ pr0b) {
  int gw = (int)((blockIdx.x * (size_t)blockDim.x + threadIdx.x) >> 6);
  int lane = threadIdx.x & 63;
  if (gw >= NTOK) return;
  int b = gw >> 8;
  const unsigned short* qr = qb + (size_t)gw * Hm;
  float2 q[6];
#pragma unroll
  for (int i = 0; i < 6; ++i) {
    uint32_t u = *(const uint32_t*)(qr + 2 * lane + 128 * i);
    q[i] = float2{bflo(u), bfhi(u)};
  }
  const unsigned short* eb = eb_all + (size_t)b * LE * Hm;
  float myA = -3.0e38f;
  for (int e = 0; e < LE; ++e) {
    const unsigned short* er = eb + (size_t)e * Hm;
    float s = 0.f;
#pragma unroll
    for (int i = 0; i < 6; ++i) {
      uint32_t u = *(const uint32_t*)(er + 2 * lane + 128 * i);
      s = fmaf(q[i].x, bflo(u), s);
      s = fmaf(q[i].y, bfhi(u), s);
    }
#pragma unroll
    for (int off = 32; off > 0; off >>= 1) s += __shfl_xor(s, off);
    if (lane == e) myA = s * (1.0f / 768.0f);
  }
  float mx = myA;
#pragma unroll
  for (int off = 32; off > 0; off >>= 1) mx = fmaxf(mx, __shfl_xor(mx, off));
  float p = (lane < LE) ? expf(myA - mx) : 0.f;
  float sum = p;
#pragma unroll
  for (int off = 32; off > 0; off >>= 1) sum += __shfl_xor(sum, off);
  float wgt = p / sum;
  const unsigned short* tr = tokb + (size_t)gw * Hm;
  float2 a[6];
#pragma unroll
  for (int i = 0; i < 6; ++i) {
    uint32_t u = *(const uint32_t*)(tr + 2 * lane + 128 * i);
    a[i] = float2{bflo(u), bfhi(u)};
  }
  for (int e = 0; e < LE; ++e) {
    float we = __shfl(wgt, e);
    const unsigned short* er = eb + (size_t)e * Hm;
#pragma unroll
    for (int i = 0; i < 6; ++i) {
      uint32_t u = *(const uint32_t*)(er + 2 * lane + 128 * i);
      a[i].x = fmaf(we, bflo(u), a[i].x);
      a[i].y = fmaf(we, bfhi(u), a[i].y);
    }
  }
  float* orow = pr0 + (size_t)gw * Hm;
  unsigned short* obrow = pr0b + (size_t)gw * Hm;
#pragma unroll
  for (int i = 0; i < 6; ++i) {
    *(float2*)(orow + 2 * lane + 128 * i) = a[i];
    *(uint32_t*)(obrow + 2 * lane + 128 * i) = pkbf(a[i].x, a[i].y);
  }
}

// ---------------------------------------------------------------------------

extern "C" void kernel_launch(void* const* d_in, const int* in_sizes, int n_in,
                              void* d_out, int out_size, void* d_ws, size_t ws_size,
                              hipStream_t stream) {
  (void)in_sizes; (void)n_in; (void)out_size;

  const float* x_node = (const float*)d_in[0];
  const float* bases  = (const float*)d_in[1];
  const float* comp   = (const float*)d_in[2];
  const float* root   = (const float*)d_in[3];
  const float* rbias  = (const float*)d_in[4];
  const float* ep1w1  = (const float*)d_in[5];
  const float* ep1b1  = (const float*)d_in[6];
  const float* ep1w2  = (const float*)d_in[7];
  const float* ep1b2  = (const float*)d_in[8];
  const float* ep2w   = (const float*)d_in[9];
  const float* ep2b   = (const float*)d_in[10];
  const float* tp1w1  = (const float*)d_in[11];
  const float* tp1b1  = (const float*)d_in[12];
  const float* tp1w2  = (const float*)d_in[13];
  const float* tp1b2  = (const float*)d_in[14];
  const float* tp2w   = (const float*)d_in[15];
  const float* tp2b   = (const float*)d_in[16];
  const float* caw    = (const float*)d_in[17];
  const float* pp1w1  = (const float*)d_in[18];
  const float* pp1b1  = (const float*)d_in[19];
  const float* pp1w2  = (const float*)d_in[20];
  const float* pp1b2  = (const float*)d_in[21];
  const float* pp2w   = (const float*)d_in[22];
  const float* pp2b   = (const float*)d_in[23];
  const float* tokens = (const float*)d_in[24];
  const int* ei_kg = (const int*)d_in[25];
  const int* etype = (const int*)d_in[26];
  const int* ei_c  = (const int*)d_in[27];
  const int* ei_ts = (const int*)d_in[28];
  const int* ei_is = (const int*)d_in[29];
  const int* mte   = (const int*)d_in[30];
  const int* eids  = (const int*)d_in[31];

  float* O = (float*)d_out;
  unsigned short* xb    = (unsigned short*)(O + P_XB);
  unsigned short* wct   = (unsigned short*)(O + P_WCT);
  float* rcpc  = O + P_CNT;
  float* ent0  = O + P_ENT0;
  unsigned short* hh    = (unsigned short*)(O + P_HH);
  float* disc  = O + P_DIS;
  float* dist  = O + P_DIS + 30000;
  float* disi  = O + P_DIS + 36000;
  unsigned short* ent0b = (unsigned short*)(O + P_E0B);
  unsigned short* c1b   = (unsigned short*)(O + P_C1B);
  unsigned short* c2b   = (unsigned short*)(O + P_C2B);
  unsigned short* nfb   = (unsigned short*)(O + P_NFB);
  unsigned short* t1b   = (unsigned short*)(O + P_T1B);
  float* g1    = O + P_G1;
  float* accb  = O + P_ACC;
  unsigned short* entb  = (unsigned short*)(O + P_ENTB);
  unsigned short* hidb  = (unsigned short*)(O + P_HIDB);
  unsigned short* ent2b = (unsigned short*)(O + P_ENT2B);
  unsigned short* e768b = (unsigned short*)(O + P_E768B);
  unsigned short* tokb  = (unsigned short*)(O + P_TOKB);
  unsigned short* thidb = (unsigned short*)(O + P_THIDB);
  unsigned short* tok1b = (unsigned short*)(O + P_TOK1B);
  unsigned short* tok2b = (unsigned short*)(O + P_TOK2B);
  unsigned short* qb    = (unsigned short*)(O + P_QB);
  unsigned short* eemb  = (unsigned short*)(O + P_EEMB);
  float* pr0   = O + P_PR0;
  unsigned short* pr0b  = (unsigned short*)(O + P_PR0B);
  unsigned short* phidb = (unsigned short*)(O + P_PHIDB);
  unsigned short* wts   = (unsigned short*)(O + P_WT);

  int* iws = (int*)d_ws;
  unsigned short* p2b = (unsigned short*)d_ws;
  unsigned short* pp2t = (unsigned short*)d_ws + WS_PP2T_BYTE / 2;
  const bool ws_ok = (ws_size >= WS_NEED);
  int* cnt_i  = iws + I_CNT;
  int* part   = iws + I_PART;
  int* kg_rp  = iws + I_KG_RP;  int* kg_ca = iws + I_KG_CA;  int* kg_sl = iws + I_KG_SL;
  int* kg_bnd = iws + I_KG_BND; int* kg_cb = iws + I_KG_CB;
  int* c_rp   = iws + I_C_RP;   int* c_cur  = iws + I_C_CUR;   int* c_sl  = iws + I_C_SL;
  int* ts_rp  = iws + I_TS_RP;  int* ts_cur = iws + I_TS_CUR;  int* ts_sl = iws + I_TS_SL;
  int* is_rp  = iws + I_IS_RP;  int* is_cur = iws + I_IS_CUR;  int* is_sl = iws + I_IS_SL;

  const int EW = 256;

  // ---------------- phase A: conversions ----------------
  k_cvt<<<cdiv(NBf / 2, EW), EW, 0, stream>>>(x_node, xb, NBf / 2);
  k_wcat<<<cdiv(12 * Dm * Dm, EW), EW, 0, stream>>>(comp, bases, wct);
  k_cvt_t<<<dim3(Dm / 32, Dm / 32), 256, 0, stream>>>(root, wts + S_ROOT, Dm, Dm);
  k_cvt_t<<<dim3(192 / 32, Dm / 32), 256, 0, stream>>>(ep1w1, wts + S_EP1A, Dm, 192);
  k_cvt_t<<<dim3(Dm / 32, 192 / 32), 256, 0, stream>>>(ep1w2, wts + S_EP1B, 192, Dm);
  k_cvt_t<<<dim3(Hm / 32, Dm / 32), 256, 0, stream>>>(ep2w, wts + S_EP2, Dm, Hm);
  k_cvt_t<<<dim3(Dm / 32, Hm / 32), 256, 0, stream>>>(tp1w1, wts + S_TP1A, Hm, Dm);
  k_cvt_t<<<dim3(Hm / 32, Dm / 32), 256, 0, stream>>>(tp1w2, wts + S_TP1B, Dm, Hm);
  k_cvt_t<<<dim3(Hm / 32, Hm / 32), 256, 0, stream>>>(tp2w, wts + S_TP2, Hm, Hm);
  k_cvt_t<<<dim3(Hm / 32, Hm / 32), 256, 0, stream>>>(caw, wts + S_CAW, Hm, Hm);
  k_cvt_t<<<dim3(Dm / 32, Hm / 32), 256, 0, stream>>>(pp1w1, wts + S_PP1A, Hm, Dm);
  k_cvt_t<<<dim3(Hm / 32, Dm / 32), 256, 0, stream>>>(pp1w2, wts + S_PP1B, Dm, Hm);

  // ---------------- CSR builds ----------------
  // KG graph: split CSR (typ<6 in [rp,bnd), typ>=6 in [bnd,rp_next))
  hipMemsetAsync(cnt_i, 0, (size_t)NE * 4, stream);
  k_hist<<<cdiv(EKG, EW), EW, 0, stream>>>(ei_kg + EKG, cnt_i, EKG);
  {
    int nb = cdiv(NE, 256);
    k_scan_blk<<<nb, 256, 0, stream>>>(cnt_i, kg_rp, part, NE);
    k_scan_top<<<1, 256, 0, stream>>>(part, nb);
    k_scan_add<<<nb, 256, 0, stream>>>(kg_rp, part, NE);
  }
  hipMemsetAsync(cnt_i, 0, (size_t)NE * 4, stream);
  k_hist_lt<<<cdiv(EKG, EW), EW, 0, stream>>>(ei_kg + EKG, etype, cnt_i, EKG);
  k_add_i<<<cdiv(NE, EW), EW, 0, stream>>>(kg_rp, cnt_i, kg_bnd, NE);
  hipMemcpyAsync(kg_ca, kg_rp, (size_t)NE * 4, hipMemcpyDeviceToDevice, stream);
  hipMemcpyAsync(kg_cb, kg_bnd, (size_t)NE * 4, hipMemcpyDeviceToDevice, stream);
  k_fill_split<<<cdiv(EKG, EW), EW, 0, stream>>>(
      ei_kg, ei_kg + EKG, etype, kg_ca, kg_cb, kg_sl, EKG);

  auto build_csr = [&](const int* ei, int n, int E, int* rp, int* cur, int* sl) {
    hipMemsetAsync(cnt_i, 0, (size_t)n * 4, stream);
    k_hist<<<cdiv(E, EW), EW, 0, stream>>>(ei + E, cnt_i, E);
    int nb = cdiv(n, 256);
    k_scan_blk<<<nb, 256, 0, stream>>>(cnt_i, rp, part, n);
    k_scan_top<<<1, 256, 0, stream>>>(part, nb);
    k_scan_add<<<nb, 256, 0, stream>>>(rp, part, n);
    hipMemcpyAsync(cur, rp, (size_t)n * 4, hipMemcpyDeviceToDevice, stream);
    k_fill<<<cdiv(E, EW), EW, 0, stream>>>(ei, ei + E, cur, sl, E);
  };
  build_csr(ei_c, NE, EC, c_rp, c_cur, c_sl);
  build_csr(ei_ts, NM, ES, ts_rp, ts_cur, ts_sl);
  build_csr(ei_is, NM, ES, is_rp, is_cur, is_sl);

  k_dis_rp<<<cdiv(NE, EW), EW, 0, stream>>>(c_rp, disc, NE, EC);
  k_dis_rp<<<cdiv(NM, EW), EW, 0, stream>>>(ts_rp, dist, NM, ES);
  k_dis_rp<<<cdiv(NM, EW), EW, 0, stream>>>(is_rp, disi, NM, ES);

  hipMemsetAsync(rcpc, 0, (size_t)12 * NE * 4, stream);
  k_count_type<<<cdiv(EKG, EW), EW, 0, stream>>>(ei_kg + EKG, etype, rcpc, EKG);
  k_rcp<<<cdiv((long)12 * NE, EW), EW, 0, stream>>>(rcpc, (size_t)12 * NE);

  // ---------------- RGCN ----------------
  mgemm_bf<false, true, 0><<<dim3(cdiv(NE, 128), cdiv(Dm, 128)), 256, 0, stream>>>(
      xb, wts + S_ROOT, rbias, x_node, ent0, NE, Dm, Dm);
  mgemm_bf<false, false, 1><<<dim3(cdiv(NE, 128), cdiv(6 * Dm, 128)), 256, 0, stream>>>(
      xb, wct, nullptr, nullptr, hh, NE, 6 * Dm, Dm);
  k_rgcn_g<true, false><<<cdiv((long)NE * 64, EW), EW, 0, stream>>>(
      hh, rcpc, kg_rp, kg_bnd, kg_sl, ent0, nullptr, EKG);
  mgemm_bf<false, false, 1><<<dim3(cdiv(NE, 128), cdiv(6 * Dm, 128)), 256, 0, stream>>>(
      xb, wct + (size_t)6 * Dm * Dm, nullptr, nullptr, hh, NE, 6 * Dm, Dm);
  // last RGCN gather also emits ent0b (bf16) — xb dead by now
  k_rgcn_g<false, true><<<cdiv((long)NE * 64, EW), EW, 0, stream>>>(
      hh, rcpc, kg_rp, kg_bnd, kg_sl, ent0, ent0b, EKG);

  // ---------------- phase B: graph chains (bf16) ----------------
  k_gather_b<<<cdiv((long)NM * 192, EW), EW, 0, stream>>>(
      mte, (const uint32_t*)ent0b, (uint32_t*)nfb, NM, 192);
  k_gcn_gb<1, 3><<<cdiv((long)NM * 64, EW), EW, 0, stream>>>(
      nfb, dist, ts_rp, ts_sl, t1b, g1, NM, ES, 1.0f);
  k_gcn_gb<0, 1><<<cdiv((long)NM * 64, EW), EW, 0, stream>>>(
      t1b, dist, ts_rp, ts_sl, nullptr, g1, NM, ES, 1.0f);
  k_gcn_gb<1, 1><<<cdiv((long)NM * 64, EW), EW, 0, stream>>>(
      nfb, disi, is_rp, is_sl, t1b, g1, NM, ES, 1.0f);
  k_gcn_gb<0, 1><<<cdiv((long)NM * 64, EW), EW, 0, stream>>>(
      t1b, disi, is_rp, is_sl, nullptr, g1, NM, ES, 1.0f);
  // entity chain (0.25 folded): accb = 0.25*(ent0+c1) += 0.25*c2 += movie += 0.25*c3
  k_gcn_gb<1, 2><<<cdiv((long)NE * 64, EW), EW, 0, stream>>>(
      ent0b, disc, c_rp, c_sl, c1b, accb, NE, EC, 0.25f);
  k_gcn_gb<1, 1><<<cdiv((long)NE * 64, EW), EW, 0, stream>>>(
      c1b, disc, c_rp, c_sl, c2b, accb, NE, EC, 0.25f);
  k_scatter_movie<<<cdiv(MBF, EW), EW, 0, stream>>>(mte, g1, accb);
  k_gcn_gb<2, 1><<<cdiv((long)NE * 64, EW), EW, 0, stream>>>(
      c2b, disc, c_rp, c_sl, entb, accb, NE, EC, 0.25f);

  // pp2t conversion (CSR arrays now dead)
  if (ws_ok) {
    k_cvt_t<<<dim3(NO / 32, Hm / 32), 256, 0, stream>>>(pp2w, pp2t, Hm, NO);
  }

  // ---------------- entity MLP ----------------
  mgemm_bf<true, false, 1><<<dim3(cdiv(NE, 128), cdiv(192, 128)), 256, 0, stream>>>(
      entb, wts + S_EP1A, ep1b1, nullptr, hidb, NE, 192, Dm);
  mgemm_bf<false, true, 1><<<dim3(cdiv(NE, 128), cdiv(Dm, 128)), 256, 0, stream>>>(
      hidb, wts + S_EP1B, ep1b2, accb, ent2b, NE, Dm, 192);
  mgemm_bf<false, false, 1><<<dim3(cdiv(NE, 128), cdiv(Hm, 128)), 256, 0, stream>>>(
      ent2b, wts + S_EP2, ep2b, nullptr, e768b, NE, Hm, Dm);

  // ---------------- token path ----------------
  k_cvt<<<cdiv((long)NTOK * Hm / 2, EW), EW, 0, stream>>>(tokens, tokb, (size_t)NTOK * Hm / 2);
  mgemm_bf<true, false, 1><<<dim3(cdiv(NTOK, 128), cdiv(Dm, 128)), 256, 0, stream>>>(
      tokb, wts + S_TP1A, tp1b1, nullptr, thidb, NTOK, Dm, Hm);
  mgemm_bf<false, true, 1><<<dim3(cdiv(NTOK, 128), cdiv(Hm, 128)), 256, 0, stream>>>(
      thidb, wts + S_TP1B, tp1b2, tokens, tok1b, NTOK, Hm, Dm);
  mgemm_bf<false, false, 1><<<dim3(cdiv(NTOK, 128), cdiv(Hm, 128)), 256, 0, stream>>>(
      tok1b, wts + S_TP2, tp2b, nullptr, tok2b, NTOK, Hm, Hm);
  mgemm_bf<false, false, 1><<<dim3(cdiv(NTOK, 128), cdiv(Hm, 128)), 256, 0, stream>>>(
      tok2b, wts + S_CAW, nullptr, nullptr, qb, NTOK, Hm, Hm);

  k_gather_b<<<cdiv((long)Bc * LE * (Hm / 2), EW), EW, 0, stream>>>(
      eids, (const uint32_t*)e768b, (uint32_t*)eemb, Bc * LE, Hm / 2);
  k_attn<<<cdiv((long)NTOK * 64, 256), 256, 0, stream>>>(qb, eemb, tok2b, pr0, pr0b);

  mgemm_bf<true, false, 1><<<dim3(cdiv(NTOK, 128), cdiv(Dm, 128)), 256, 0, stream>>>(
      pr0b, wts + S_PP1A, pp1b1, nullptr, phidb, NTOK, Dm, Hm);
  mgemm_bf<false, true, 1><<<dim3(cdiv(NTOK, 128), cdiv(Hm, 128)), 256, 0, stream>>>(
      phidb, wts + S_PP1B, pp1b2, pr0, p2b, NTOK, Hm, Dm);

  // ---------------- final GEMM + transpose (reads ONLY d_ws/d_in) ---------
  if (ws_ok) {
    mgemm_bf<false, false, 2><<<dim3(NTOK / 128, NO / 128), 256, 0, stream>>>(
        p2b, pp2t, pp2b, nullptr, O, NTOK, NO, Hm);
  } else {
    mgemm_fin<<<dim3(NTOK / 128, NO / 128), 256, 0, stream>>>(
        p2b, pp2w, pp2b, O, NTOK, NO, Hm);
  }
}

// Round 12
// 1554.808 us; speedup vs baseline: 1.0697x; 1.0065x over previous
//
#include <hip/hip_runtime.h>
#include <hip/hip_bf16.h>
#include <cstdint>
#include <cstddef>

// ---------------------------------------------------------------------------
// MMPrompt pipeline, round 12 = r11 (1565us)
//  + chunked-XCD swizzle on the FINAL GEMM only (B-panel L2 locality;
//    each XCD owns 18 contiguous bn-strips).
//  + 10 weight-conversions merged into 1 kernel; cursor memcpys folded
//    into the scan kernels (~14 fewer graph nodes).
// ---------------------------------------------------------------------------

namespace {

constexpr int NE   = 30000;
constexpr int NM   = 6000;
constexpr int Dm   = 384;
constexpr int Hm   = 768;
constexpr int EKG  = 200000;
constexpr int EC   = 200000;
constexpr int ES   = 80000;
constexpr int Bc   = 16;
constexpr int LE   = 48;
constexpr int NTOK = 4096;
constexpr int NO   = 18432;

constexpr size_t NBf = (size_t)NE * Dm;   // 11,520,000
constexpr size_t MBF = (size_t)NM * Dm;   // 2,304,000

// ---------------- d_out arena (f32-unit offsets) ----------------
constexpr size_t P_XB    = 0;
constexpr size_t P_WCT   = 5760000;
constexpr size_t P_CNT   = 6644736;
constexpr size_t P_ENT0  = 7004736;
constexpr size_t P_HH    = 18524736;
constexpr size_t P_DIS   = 53084736;
constexpr size_t P_E0B   = 0;
constexpr size_t P_C1B   = 2880000;
constexpr size_t P_C2B   = 5760000;
constexpr size_t P_NFB   = 8640000;
constexpr size_t P_T1B   = 9800000;
constexpr size_t P_G1    = 11000000;
constexpr size_t P_ACC   = 41564736;
constexpr size_t P_ENTB  = 55600000;
constexpr size_t P_HIDB  = 0;
constexpr size_t P_ENT2B = 2880000;
constexpr size_t P_E768B = 8640000;
constexpr size_t P_TOKB  = 20160000;
constexpr size_t P_THIDB = 21732864;
constexpr size_t P_TOK1B = 22519296;
constexpr size_t P_TOK2B = 24092160;
constexpr size_t P_QB    = 25665024;
constexpr size_t P_EEMB  = 27237888;
constexpr size_t P_PR0   = 27532800;
constexpr size_t P_PR0B  = 30678528;
constexpr size_t P_PHIDB = 32251392;
constexpr size_t P_WT    = 74000000;
constexpr size_t S_ROOT  = 0;
constexpr size_t S_EP1A  = 147456;
constexpr size_t S_EP1B  = 221184;
constexpr size_t S_EP2   = 294912;
constexpr size_t S_TP1A  = 589824;
constexpr size_t S_TP1B  = 884736;
constexpr size_t S_TP2   = 1179648;
constexpr size_t S_CAW   = 1769472;
constexpr size_t S_PP1A  = 2359296;
constexpr size_t S_PP1B  = 2654208;

// ---------------- d_ws layout ----------------
constexpr size_t WI       = 6291456 / 4;
constexpr size_t I_CNT    = WI + 0;
constexpr size_t I_PART   = WI + 30000;
constexpr size_t I_KG_RP  = WI + 30256;
constexpr size_t I_KG_CA  = WI + 60256;
constexpr size_t I_KG_SL  = WI + 90256;
constexpr size_t I_C_RP   = WI + 290256;
constexpr size_t I_C_CUR  = WI + 320256;
constexpr size_t I_C_SL   = WI + 350256;
constexpr size_t I_TS_RP  = WI + 550256;
constexpr size_t I_TS_CUR = WI + 556256;
constexpr size_t I_TS_SL  = WI + 562256;
constexpr size_t I_IS_RP  = WI + 642256;
constexpr size_t I_IS_CUR = WI + 648256;
constexpr size_t I_IS_SL  = WI + 654256;
constexpr size_t I_KG_BND = WI + 734256;
constexpr size_t I_KG_CB  = WI + 764256;
constexpr size_t WS_PP2T_BYTE = 6291456;
constexpr size_t WS_NEED      = 34603008;

inline int cdiv(long a, long b) { return (int)((a + b - 1) / b); }

} // namespace

typedef short short8v __attribute__((ext_vector_type(8)));
typedef float f32x4 __attribute__((ext_vector_type(4)));

__device__ __forceinline__ unsigned short f2bf(float f) {
  union { float f; uint32_t u; } v; v.f = f;
  uint32_t u = v.u;
  u += 0x7fffu + ((u >> 16) & 1u);
  return (unsigned short)(u >> 16);
}
__device__ __forceinline__ uint32_t pkbf(float a, float b) {
  __hip_bfloat162 h = __float22bfloat162_rn(float2{a, b});
  union { __hip_bfloat162 h; uint32_t u; } cv; cv.h = h;
  return cv.u;
}
__device__ __forceinline__ float bflo(uint32_t u) {
  union { uint32_t u; float f; } c; c.u = u << 16; return c.f;
}
__device__ __forceinline__ float bfhi(uint32_t u) {
  union { uint32_t u; float f; } c; c.u = u & 0xFFFF0000u; return c.f;
}

__device__ __forceinline__ void gl16(const void* g, void* l) {
  __builtin_amdgcn_global_load_lds(
      (const __attribute__((address_space(1))) void*)g,
      (__attribute__((address_space(3))) void*)l, 16, 0, 0);
}

// ---------------------------------------------------------------------------
// conversion / utility kernels
// ---------------------------------------------------------------------------

__global__ void k_cvt(const float* __restrict__ x, unsigned short* __restrict__ o, size_t n2) {
  size_t i = (size_t)blockIdx.x * 256 + threadIdx.x;
  if (i >= n2) return;
  float2 v = *(const float2*)(x + 2 * i);
  *(uint32_t*)(o + 2 * i) = pkbf(v.x, v.y);
}

// f32 W[K][N] -> bf16 Wt[N][K] (single weight; used for pp2t only)
__global__ void k_cvt_t(const float* __restrict__ W, unsigned short* __restrict__ Wt,
                        int K, int N) {
  __shared__ float t[32][33];
  int tx = threadIdx.x & 31, ty = threadIdx.x >> 5;
  int n0 = blockIdx.x * 32, k0 = blockIdx.y * 32;
#pragma unroll
  for (int j = 0; j < 4; ++j)
    t[ty + 8 * j][tx] = W[(size_t)(k0 + ty + 8 * j) * N + n0 + tx];
  __syncthreads();
#pragma unroll
  for (int j = 0; j < 4; ++j) {
    int n = ty + 8 * j;
    Wt[(size_t)(n0 + n) * K + k0 + tx] = f2bf(t[tx][n]);
  }
}

// batched weight transpose-convert: 10 weights, tile table compile-time.
// tiles: root 144 | ep1a 72 | ep1b 72 | ep2 288 | tp1a 288 | tp1b 288 |
//        tp2 576 | caw 576 | pp1a 288 | pp1b 288  => 2880 total
__global__ void k_cvt_t_all(
    const float* s0, unsigned short* d0, const float* s1, unsigned short* d1,
    const float* s2, unsigned short* d2, const float* s3, unsigned short* d3,
    const float* s4, unsigned short* d4, const float* s5, unsigned short* d5,
    const float* s6, unsigned short* d6, const float* s7, unsigned short* d7,
    const float* s8, unsigned short* d8, const float* s9, unsigned short* d9) {
  __shared__ float t[32][33];
  int tile = blockIdx.x;
  const float* W; unsigned short* Wt; int K, N, base;
  if      (tile < 144)  { W = s0; Wt = d0; K = 384; N = 384; base = 0; }
  else if (tile < 216)  { W = s1; Wt = d1; K = 384; N = 192; base = 144; }
  else if (tile < 288)  { W = s2; Wt = d2; K = 192; N = 384; base = 216; }
  else if (tile < 576)  { W = s3; Wt = d3; K = 384; N = 768; base = 288; }
  else if (tile < 864)  { W = s4; Wt = d4; K = 768; N = 384; base = 576; }
  else if (tile < 1152) { W = s5; Wt = d5; K = 384; N = 768; base = 864; }
  else if (tile < 1728) { W = s6; Wt = d6; K = 768; N = 768; base = 1152; }
  else if (tile < 2304) { W = s7; Wt = d7; K = 768; N = 768; base = 1728; }
  else if (tile < 2592) { W = s8; Wt = d8; K = 768; N = 384; base = 2304; }
  else                  { W = s9; Wt = d9; K = 384; N = 768; base = 2592; }
  int lt = tile - base;
  int ntx = N >> 5;
  int n0 = (lt % ntx) * 32, k0 = (lt / ntx) * 32;
  int tx = threadIdx.x & 31, ty = threadIdx.x >> 5;
#pragma unroll
  for (int j = 0; j < 4; ++j)
    t[ty + 8 * j][tx] = W[(size_t)(k0 + ty + 8 * j) * N + n0 + tx];
  __syncthreads();
#pragma unroll
  for (int j = 0; j < 4; ++j) {
    int n = ty + 8 * j;
    Wt[(size_t)(n0 + n) * K + k0 + tx] = f2bf(t[tx][n]);
  }
}

// wcat_t[(r*384+o)*384 + i] = sum_b comp[r][b]*bases[b][i][o]  (bf16)
__global__ void k_wcat(const float* __restrict__ comp, const float* __restrict__ bases,
                       unsigned short* __restrict__ Wt) {
  int idx = blockIdx.x * 256 + threadIdx.x;
  if (idx >= 12 * Dm * Dm) return;
  int i = idx % Dm;
  int o = (idx / Dm) % Dm;
  int r = idx / (Dm * Dm);
  float s = 0.f;
#pragma unroll
  for (int b = 0; b < 8; ++b)
    s += comp[r * 8 + b] * bases[(size_t)b * Dm * Dm + (size_t)i * Dm + o];
  Wt[idx] = f2bf(s);
}

// gather bf16 rows as u32 chunks
__global__ void k_gather_b(const int* __restrict__ idx, const uint32_t* __restrict__ x2,
                           uint32_t* __restrict__ out2, int rows, int D2) {
  size_t i = (size_t)blockIdx.x * 256 + threadIdx.x;
  if (i >= (size_t)rows * D2) return;
  int r = (int)(i / D2);
  int c = (int)(i - (size_t)r * D2);
  out2[i] = x2[(size_t)idx[r] * D2 + c];
}

// ent[mte[m]][d] += 0.25*g[m][d]
__global__ void k_scatter_movie(const int* __restrict__ mte, const float* __restrict__ g,
                                float* __restrict__ ent) {
  size_t i = (size_t)blockIdx.x * 256 + threadIdx.x;
  if (i >= MBF) return;
  int m = (int)(i / Dm);
  int d = (int)(i - (size_t)m * Dm);
  atomicAdd(&ent[(size_t)mte[m] * Dm + d], 0.25f * g[i]);
}

// ---------------------------------------------------------------------------
// CSR build
// ---------------------------------------------------------------------------

__global__ void k_hist(const int* __restrict__ dst, int* __restrict__ cnt, int E) {
  int e = blockIdx.x * 256 + threadIdx.x;
  if (e < E) atomicAdd(&cnt[dst[e]], 1);
}

__global__ void k_hist_lt(const int* __restrict__ dst, const int* __restrict__ typ,
                          int* __restrict__ cnt, int E) {
  int e = blockIdx.x * 256 + threadIdx.x;
  if (e < E && typ[e] < 6) atomicAdd(&cnt[dst[e]], 1);
}

// o = a+b; o2 = o (bnd + its cursor copy)
__global__ void k_add_i(const int* __restrict__ a, const int* __restrict__ b,
                        int* __restrict__ o, int* __restrict__ o2, int n) {
  int i = blockIdx.x * 256 + threadIdx.x;
  if (i < n) { int v = a[i] + b[i]; o[i] = v; o2[i] = v; }
}

__global__ void k_scan_blk(const int* __restrict__ in, int* __restrict__ out,
                           int* __restrict__ part, int n) {
  __shared__ int s[256];
  int t = threadIdx.x;
  int g = blockIdx.x * 256 + t;
  int v = (g < n) ? in[g] : 0;
  s[t] = v;
  __syncthreads();
  for (int off = 1; off < 256; off <<= 1) {
    int add = (t >= off) ? s[t - off] : 0;
    __syncthreads();
    s[t] += add;
    __syncthreads();
  }
  if (g < n) out[g] = s[t] - v;
  if (t == 255) part[blockIdx.x] = s[255];
}

__global__ void k_scan_top(int* __restrict__ part, int nb) {
  __shared__ int s[256];
  int t = threadIdx.x;
  int v = (t < nb) ? part[t] : 0;
  s[t] = v;
  __syncthreads();
  for (int off = 1; off < 256; off <<= 1) {
    int add = (t >= off) ? s[t - off] : 0;
    __syncthreads();
    s[t] += add;
    __syncthreads();
  }
  if (t < nb) part[t] = s[t] - v;
}

// out += part; cur = out (folds the cursor memcpy)
__global__ void k_scan_add(int* __restrict__ out, const int* __restrict__ part,
                           int* __restrict__ cur, int n) {
  int g = blockIdx.x * 256 + threadIdx.x;
  if (g < n) { int v = out[g] + part[blockIdx.x]; out[g] = v; cur[g] = v; }
}

__global__ void k_fill(const int* __restrict__ src, const int* __restrict__ dst,
                       int* __restrict__ cur, int* __restrict__ slots, int E) {
  int e = blockIdx.x * 256 + threadIdx.x;
  if (e >= E) return;
  int d = dst[e];
  int pos = atomicAdd(&cur[d], 1);
  slots[pos] = src[e];
}

// split fill: typ<6 edges go to [rp, bnd), others to [bnd, rp_next)
__global__ void k_fill_split(const int* __restrict__ src, const int* __restrict__ dst,
                             const int* __restrict__ typ, int* __restrict__ cur_a,
                             int* __restrict__ cur_b, int* __restrict__ slots, int E) {
  int e = blockIdx.x * 256 + threadIdx.x;
  if (e >= E) return;
  int d = dst[e];
  int* c = (typ[e] < 6) ? cur_a : cur_b;
  int pos = atomicAdd(&c[d], 1);
  slots[pos] = src[e] | (typ[e] << 16);
}

__global__ void k_dis_rp(const int* __restrict__ rp, float* __restrict__ dis, int n, int E) {
  int v = blockIdx.x * 256 + threadIdx.x;
  if (v >= n) return;
  int e0 = rp[v], e1 = (v + 1 < n) ? rp[v + 1] : E;
  dis[v] = rsqrtf((float)(e1 - e0) + 1.0f);
}

__global__ void k_count_type(const int* __restrict__ dst, const int* __restrict__ typ,
                             float* __restrict__ cnt, int E) {
  int i = blockIdx.x * 256 + threadIdx.x;
  if (i < E) atomicAdd(&cnt[(size_t)typ[i] * NE + dst[i]], 1.0f);
}

__global__ void k_rcp(float* __restrict__ c, size_t n) {
  size_t i = (size_t)blockIdx.x * 256 + threadIdx.x;
  if (i < n) { float v = c[i]; c[i] = (v > 0.f) ? 1.0f / v : 0.f; }
}

// ---------------------------------------------------------------------------
// bf16 GCN gather (one wave per dst row, 2-edge unrolled).
// OUTM: 0 none, 1 outb = bf16(a), 2 outb = bf16(acc_new).
// ACCM: 1 acc += sc*a; 2 acc = sc*(x[v]+a); 3 acc = sc*a.
// ---------------------------------------------------------------------------
template <int OUTM, int ACCM>
__global__ void k_gcn_gb(const unsigned short* __restrict__ x,
                         const float* __restrict__ dis,
                         const int* __restrict__ rp, const int* __restrict__ slots,
                         unsigned short* __restrict__ outb, float* __restrict__ acc,
                         int n, int E, float sc) {
  int v = (int)((blockIdx.x * (size_t)blockDim.x + threadIdx.x) >> 6);
  int lane = threadIdx.x & 63;
  if (v >= n) return;
  float dv = dis[v];
  const uint32_t* xr = (const uint32_t*)(x + (size_t)v * Dm);
  float xv[6];
#pragma unroll
  for (int i = 0; i < 3; ++i) {
    uint32_t u = xr[lane + 64 * i];
    xv[2 * i] = bflo(u); xv[2 * i + 1] = bfhi(u);
  }
  float a[6];
#pragma unroll
  for (int i = 0; i < 6; ++i) a[i] = dv * xv[i];
  int e0 = rp[v], e1 = (v + 1 < n) ? rp[v + 1] : E;
  int e = e0;
  for (; e + 2 <= e1; e += 2) {
    int s0 = slots[e], s1 = slots[e + 1];
    float c0 = dis[s0], c1 = dis[s1];
    const uint32_t* x0 = (const uint32_t*)(x + (size_t)s0 * Dm);
    const uint32_t* x1 = (const uint32_t*)(x + (size_t)s1 * Dm);
    uint32_t u0[3], u1[3];
#pragma unroll
    for (int i = 0; i < 3; ++i) { u0[i] = x0[lane + 64 * i]; u1[i] = x1[lane + 64 * i]; }
#pragma unroll
    for (int i = 0; i < 3; ++i) {
      a[2 * i]     = fmaf(c0, bflo(u0[i]), a[2 * i]);
      a[2 * i + 1] = fmaf(c0, bfhi(u0[i]), a[2 * i + 1]);
      a[2 * i]     = fmaf(c1, bflo(u1[i]), a[2 * i]);
      a[2 * i + 1] = fmaf(c1, bfhi(u1[i]), a[2 * i + 1]);
    }
  }
  if (e < e1) {
    int s0 = slots[e];
    float c0 = dis[s0];
    const uint32_t* x0 = (const uint32_t*)(x + (size_t)s0 * Dm);
#pragma unroll
    for (int i = 0; i < 3; ++i) {
      uint32_t u = x0[lane + 64 * i];
      a[2 * i]     = fmaf(c0, bflo(u), a[2 * i]);
      a[2 * i + 1] = fmaf(c0, bfhi(u), a[2 * i + 1]);
    }
  }
#pragma unroll
  for (int i = 0; i < 6; ++i) a[i] *= dv;
  if (OUTM == 1) {
    uint32_t* ob = (uint32_t*)(outb + (size_t)v * Dm);
#pragma unroll
    for (int i = 0; i < 3; ++i) ob[lane + 64 * i] = pkbf(a[2 * i], a[2 * i + 1]);
  }
  float* ar = acc + (size_t)v * Dm;
  float nw[6];
#pragma unroll
  for (int i = 0; i < 3; ++i) {
    int cidx = 2 * (lane + 64 * i);
    if (ACCM == 1) {
      float2 old = *(const float2*)(ar + cidx);
      nw[2 * i] = old.x + sc * a[2 * i];
      nw[2 * i + 1] = old.y + sc * a[2 * i + 1];
    } else if (ACCM == 2) {
      nw[2 * i] = sc * (xv[2 * i] + a[2 * i]);
      nw[2 * i + 1] = sc * (xv[2 * i + 1] + a[2 * i + 1]);
    } else {
      nw[2 * i] = sc * a[2 * i];
      nw[2 * i + 1] = sc * a[2 * i + 1];
    }
    *(float2*)(ar + cidx) = float2{nw[2 * i], nw[2 * i + 1]};
  }
  if (OUTM == 2) {
    uint32_t* ob = (uint32_t*)(outb + (size_t)v * Dm);
#pragma unroll
    for (int i = 0; i < 3; ++i) ob[lane + 64 * i] = pkbf(nw[2 * i], nw[2 * i + 1]);
  }
}

// ---------------------------------------------------------------------------
// RGCN gather, split-range, 2-edge unrolled. EMITB: emit ent0b bf16 (last).
// ---------------------------------------------------------------------------
template <bool FIRST, bool EMITB>
__global__ void k_rgcn_g(const unsigned short* __restrict__ hh, const float* __restrict__ rcp,
                         const int* __restrict__ rp, const int* __restrict__ bnd,
                         const int* __restrict__ slots, float* __restrict__ ent0,
                         unsigned short* __restrict__ outb, int E) {
  int v = (int)((blockIdx.x * (size_t)blockDim.x + threadIdx.x) >> 6);
  int lane = threadIdx.x & 63;
  if (v >= NE) return;
  const int rbase = FIRST ? 0 : 6;
  int e0, e1;
  if (FIRST) { e0 = rp[v]; e1 = bnd[v]; }
  else       { e0 = bnd[v]; e1 = (v + 1 < NE) ? rp[v + 1] : E; }
  float* er = ent0 + (size_t)v * Dm;
  float2 a[3];
#pragma unroll
  for (int i = 0; i < 3; ++i) a[i] = *(const float2*)(er + 2 * lane + 128 * i);
  int e = e0;
  for (; e + 2 <= e1; e += 2) {
    int p0 = slots[e], p1 = slots[e + 1];
    int r0 = (p0 >> 16) - rbase, s0 = p0 & 0xFFFF;
    int r1 = (p1 >> 16) - rbase, s1 = p1 & 0xFFFF;
    float nm0 = rcp[(size_t)(r0 + rbase) * NE + v];
    float nm1 = rcp[(size_t)(r1 + rbase) * NE + v];
    const uint32_t* h0 = (const uint32_t*)(hh + (size_t)s0 * 2304 + (size_t)r0 * 384);
    const uint32_t* h1 = (const uint32_t*)(hh + (size_t)s1 * 2304 + (size_t)r1 * 384);
    uint32_t u0[3], u1[3];
#pragma unroll
    for (int i = 0; i < 3; ++i) { u0[i] = h0[lane + 64 * i]; u1[i] = h1[lane + 64 * i]; }
#pragma unroll
    for (int i = 0; i < 3; ++i) {
      a[i].x = fmaf(nm0, bflo(u0[i]), a[i].x);
      a[i].y = fmaf(nm0, bfhi(u0[i]), a[i].y);
      a[i].x = fmaf(nm1, bflo(u1[i]), a[i].x);
      a[i].y = fmaf(nm1, bfhi(u1[i]), a[i].y);
    }
  }
  if (e < e1) {
    int p0 = slots[e];
    int r0 = (p0 >> 16) - rbase, s0 = p0 & 0xFFFF;
    float nm0 = rcp[(size_t)(r0 + rbase) * NE + v];
    const uint32_t* h0 = (const uint32_t*)(hh + (size_t)s0 * 2304 + (size_t)r0 * 384);
#pragma unroll
    for (int i = 0; i < 3; ++i) {
      uint32_t u = h0[lane + 64 * i];
      a[i].x = fmaf(nm0, bflo(u), a[i].x);
      a[i].y = fmaf(nm0, bfhi(u), a[i].y);
    }
  }
#pragma unroll
  for (int i = 0; i < 3; ++i) *(float2*)(er + 2 * lane + 128 * i) = a[i];
  if (EMITB) {
    uint32_t* ob = (uint32_t*)(outb + (size_t)v * Dm);
#pragma unroll
    for (int i = 0; i < 3; ++i) ob[lane + 64 * i] = pkbf(a[i].x, a[i].y);
  }
}

// ---------------------------------------------------------------------------
// bf16 MFMA GEMM, 128x128 (m97 structure). A[M][K], Wt[N][K] bf16.
// OUT: 0 = f32 C, 1 = bf16 C, 2 = f32 transposed prompt layout (decomposed).
// SWZ: 1 = chunked-XCD block remap (requires nwg % 8 == 0).
// ---------------------------------------------------------------------------
template <bool RELU, bool RES, int OUT, int SWZ>
__global__ __launch_bounds__(256) void mgemm_bf(
    const unsigned short* __restrict__ A, const unsigned short* __restrict__ Wt,
    const float* __restrict__ bias, const float* __restrict__ Rp,
    void* __restrict__ Cv, int M, int N, int K) {
  __shared__ __align__(16) unsigned short As[128 * 64];
  __shared__ __align__(16) unsigned short Bs[128 * 64];
  const int tid = threadIdx.x;
  const int lane = tid & 63;
  const int w = tid >> 6;
  int bm, bn;
  if (SWZ) {
    int bid = blockIdx.y * gridDim.x + blockIdx.x;
    int cpx = (gridDim.x * gridDim.y) >> 3;
    int swz = (bid & 7) * cpx + (bid >> 3);
    bm = (swz % gridDim.x) * 128;
    bn = (swz / gridDim.x) * 128;
  } else {
    bm = blockIdx.x * 128;
    bn = blockIdx.y * 128;
  }
  const int wr = (w >> 1) * 64, wc = (w & 1) * 64;
  const int lrow = lane & 15, lq = lane >> 4;
  f32x4 acc[4][4] = {};
  const int prow_l = lane >> 3;
  const int pslot = lane & 7;

  for (int k0 = 0; k0 < K; k0 += 64) {
    __syncthreads();
#pragma unroll
    for (int j = 0; j < 4; ++j) {
      int seg = j * 4 + w;
      int prow = seg * 8 + prow_l;
      int aslot = pslot ^ (prow & 7);
      int arow = min(bm + prow, M - 1);
      gl16(A + (size_t)arow * K + k0 + aslot * 8, &As[seg * 512 + lane * 8]);
    }
#pragma unroll
    for (int j = 0; j < 4; ++j) {
      int seg = j * 4 + w;
      int prow = seg * 8 + prow_l;
      int bslot = pslot ^ (prow & 7);
      int brow = min(bn + prow, N - 1);
      gl16(Wt + (size_t)brow * K + k0 + bslot * 8, &Bs[seg * 512 + lane * 8]);
    }
    __syncthreads();
#pragma unroll
    for (int ks = 0; ks < 2; ++ks) {
      short8v af[4], bf[4];
      const int slot = ks * 4 + lq;
#pragma unroll
      for (int mr = 0; mr < 4; ++mr) {
        int r = wr + mr * 16 + lrow;
        af[mr] = *(const short8v*)&As[r * 64 + ((slot ^ (r & 7)) << 3)];
      }
#pragma unroll
      for (int nc = 0; nc < 4; ++nc) {
        int r = wc + nc * 16 + lrow;
        bf[nc] = *(const short8v*)&Bs[r * 64 + ((slot ^ (r & 7)) << 3)];
      }
#pragma unroll
      for (int mr = 0; mr < 4; ++mr)
#pragma unroll
        for (int nc = 0; nc < 4; ++nc)
          acc[mr][nc] = __builtin_amdgcn_mfma_f32_16x16x32_bf16(
              af[mr], bf[nc], acc[mr][nc], 0, 0, 0);
    }
  }
  // epilogue
  size_t colb[4];
  if (OUT == 2) {
#pragma unroll
    for (int nc = 0; nc < 4; ++nc) {
      int c = bn + wc + nc * 16 + lrow;
      int l = c / 1536, rem = c - l * 1536;
      int blk = rem / 768, rem2 = rem - blk * 768;
      int h2 = rem2 >> 6, dd = rem2 & 63;
      colb[nc] = (size_t)(l * 2 + blk) * 3145728 + (size_t)h2 * 16384 + dd;
    }
  }
#pragma unroll
  for (int mr = 0; mr < 4; ++mr) {
#pragma unroll
    for (int e = 0; e < 4; ++e) {
      int r = bm + wr + mr * 16 + lq * 4 + e;
      if (r >= M) continue;
      size_t rowoff = 0;
      if (OUT == 2) rowoff = (size_t)r * 64 + (size_t)(r >> 8) * 180224;
#pragma unroll
      for (int nc = 0; nc < 4; ++nc) {
        int c = bn + wc + nc * 16 + lrow;
        if (c >= N) continue;
        float v = acc[mr][nc][e];
        if (bias) v += bias[c];
        if (RES) v += Rp[(size_t)r * N + c];
        if (RELU) v = fmaxf(v, 0.f);
        if (OUT == 0) {
          ((float*)Cv)[(size_t)r * N + c] = v;
        } else if (OUT == 1) {
          ((unsigned short*)Cv)[(size_t)r * N + c] = f2bf(v);
        } else {
          ((float*)Cv)[colb[nc] + rowoff] = v;
        }
      }
    }
  }
}

// Fallback FINAL GEMM (ws too small): W f32 from d_in, in-kernel conversion.
__global__ __launch_bounds__(256) void mgemm_fin(
    const unsigned short* __restrict__ A, const float* __restrict__ W,
    const float* __restrict__ bias, float* __restrict__ O, int M, int N, int K) {
  __shared__ __align__(16) unsigned short As[128 * 64];
  __shared__ __align__(16) unsigned short Bs[128 * 64];
  const int tid = threadIdx.x;
  const int lane = tid & 63;
  const int w = tid >> 6;
  const int bm = blockIdx.x * 128, bn = blockIdx.y * 128;
  const int wr = (w >> 1) * 64, wc = (w & 1) * 64;
  const int lrow = lane & 15, lq = lane >> 4;
  f32x4 acc[4][4] = {};
  const int prow_l = lane >> 3;
  const int pslot = lane & 7;
  const int n_loc = tid & 127;
  const int kh = (tid >> 7) * 32;

  for (int k0 = 0; k0 < K; k0 += 64) {
    __syncthreads();
#pragma unroll
    for (int j = 0; j < 4; ++j) {
      int seg = j * 4 + w;
      int prow = seg * 8 + prow_l;
      int aslot = pslot ^ (prow & 7);
      gl16(A + (size_t)(bm + prow) * K + k0 + aslot * 8, &As[seg * 512 + lane * 8]);
    }
    float wv[32];
    const float* wp = W + (size_t)(k0 + kh) * N + bn + n_loc;
#pragma unroll
    for (int j = 0; j < 32; ++j) wv[j] = wp[(size_t)j * N];
#pragma unroll
    for (int c = 0; c < 4; ++c) {
      uint32_t u0 = pkbf(wv[8 * c + 0], wv[8 * c + 1]);
      uint32_t u1 = pkbf(wv[8 * c + 2], wv[8 * c + 3]);
      uint32_t u2 = pkbf(wv[8 * c + 4], wv[8 * c + 5]);
      uint32_t u3 = pkbf(wv[8 * c + 6], wv[8 * c + 7]);
      int s = (kh >> 3) + c;
      *(uint4*)&Bs[n_loc * 64 + ((s ^ (n_loc & 7)) << 3)] = uint4{u0, u1, u2, u3};
    }
    __syncthreads();
#pragma unroll
    for (int ks = 0; ks < 2; ++ks) {
      short8v af[4], bf[4];
      const int slot = ks * 4 + lq;
#pragma unroll
      for (int mr = 0; mr < 4; ++mr) {
        int r = wr + mr * 16 + lrow;
        af[mr] = *(const short8v*)&As[r * 64 + ((slot ^ (r & 7)) << 3)];
      }
#pragma unroll
      for (int nc = 0; nc < 4; ++nc) {
        int r = wc + nc * 16 + lrow;
        bf[nc] = *(const short8v*)&Bs[r * 64 + ((slot ^ (r & 7)) << 3)];
      }
#pragma unroll
      for (int mr = 0; mr < 4; ++mr)
#pragma unroll
        for (int nc = 0; nc < 4; ++nc)
          acc[mr][nc] = __builtin_amdgcn_mfma_f32_16x16x32_bf16(
              af[mr], bf[nc], acc[mr][nc], 0, 0, 0);
    }
  }
#pragma unroll
  for (int mr = 0; mr < 4; ++mr) {
#pragma unroll
    for (int e = 0; e < 4; ++e) {
      int r = bm + wr + mr * 16 + lq * 4 + e;
      int b = r >> 8, t = r & 255;
#pragma unroll
      for (int nc = 0; nc < 4; ++nc) {
        int c = bn + wc + nc * 16 + lrow;
        float v = acc[mr][nc][e] + bias[c];
        int l = c / 1536, rem = c - l * 1536;
        int blk = rem / 768, rem2 = rem - blk * 768;
        int hh = rem2 >> 6, dd = rem2 & 63;
        size_t oi = (((((size_t)l * 2 + blk) * 16 + b) * 12 + hh) * 256 + t) * 64 + dd;
        O[oi] = v;
      }
    }
  }
}

// ---------------------------------------------------------------------------
// fused cross-attention (bf16 inputs): one wave per (b,t)
// ---------------------------------------------------------------------------
__global__ __launch_bounds__(256) void k_attn(
    const unsigned short* __restrict__ qb, const unsigned short* __restrict__ eb_all,
    const unsigned short* __restrict__ tokb, float* __restrict__ pr0,
    unsigned short* __restrict__ pr0b) {
  int gw = (int)((blockIdx.x * (size_t)blockDim.x + threadIdx.x) >> 6);
  int lane = threadIdx.x & 63;
  if (gw >= NTOK) return;
  int b = gw >> 8;
  const unsigned short* qr = qb + (size_t)gw * Hm;
  float2 q[6];
#pragma unroll
  for (int i = 0; i < 6; ++i) {
    uint32_t u = *(const uint32_t*)(qr + 2 * lane + 128 * i);
    q[i] = float2{bflo(u), bfhi(u)};
  }
  const unsigned short* eb = eb_all + (size_t)b * LE * Hm;
  float myA = -3.0e38f;
  for (int e = 0; e < LE; ++e) {
    const unsigned short* er = eb + (size_t)e * Hm;
    float s = 0.f;
#pragma unroll
    for (int i = 0; i < 6; ++i) {
      uint32_t u = *(const uint32_t*)(er + 2 * lane + 128 * i);
      s = fmaf(q[i].x, bflo(u), s);
      s = fmaf(q[i].y, bfhi(u), s);
    }
#pragma unroll
    for (int off = 32; off > 0; off >>= 1) s += __shfl_xor(s, off);
    if (lane == e) myA = s * (1.0f / 768.0f);
  }
  float mx = myA;
#pragma unroll
  for (int off = 32; off > 0; off >>= 1) mx = fmaxf(mx, __shfl_xor(mx, off));
  float p = (lane < LE) ? expf(myA - mx) : 0.f;
  float sum = p;
#pragma unroll
  for (int off = 32; off > 0; off >>= 1) sum += __shfl_xor(sum, off);
  float wgt = p / sum;
  const unsigned short* tr = tokb + (size_t)gw * Hm;
  float2 a[6];
#pragma unroll
  for (int i = 0; i < 6; ++i) {
    uint32_t u = *(const uint32_t*)(tr + 2 * lane + 128 * i);
    a[i] = float2{bflo(u), bfhi(u)};
  }
  for (int e = 0; e < LE; ++e) {
    float we = __shfl(wgt, e);
    const unsigned short* er = eb + (size_t)e * Hm;
#pragma unroll
    for (int i = 0; i < 6; ++i) {
      uint32_t u = *(const uint32_t*)(er + 2 * lane + 128 * i);
      a[i].x = fmaf(we, bflo(u), a[i].x);
      a[i].y = fmaf(we, bfhi(u), a[i].y);
    }
  }
  float* orow = pr0 + (size_t)gw * Hm;
  unsigned short* obrow = pr0b + (size_t)gw * Hm;
#pragma unroll
  for (int i = 0; i < 6; ++i) {
    *(float2*)(orow + 2 * lane + 128 * i) = a[i];
    *(uint32_t*)(obrow + 2 * lane + 128 * i) = pkbf(a[i].x, a[i].y);
  }
}

// ---------------------------------------------------------------------------

extern "C" void kernel_launch(void* const* d_in, const int* in_sizes, int n_in,
                              void* d_out, int out_size, void* d_ws, size_t ws_size,
                              hipStream_t stream) {
  (void)in_sizes; (void)n_in; (void)out_size;

  const float* x_node = (const float*)d_in[0];
  const float* bases  = (const float*)d_in[1];
  const float* comp   = (const float*)d_in[2];
  const float* root   = (const float*)d_in[3];
  const float* rbias  = (const float*)d_in[4];
  const float* ep1w1  = (const float*)d_in[5];
  const float* ep1b1  = (const float*)d_in[6];
  const float* ep1w2  = (const float*)d_in[7];
  const float* ep1b2  = (const float*)d_in[8];
  const float* ep2w   = (const float*)d_in[9];
  const float* ep2b   = (const float*)d_in[10];
  const float* tp1w1  = (const float*)d_in[11];
  const float* tp1b1  = (const float*)d_in[12];
  const float* tp1w2  = (const float*)d_in[13];
  const float* tp1b2  = (const float*)d_in[14];
  const float* tp2w   = (const float*)d_in[15];
  const float* tp2b   = (const float*)d_in[16];
  const float* caw    = (const float*)d_in[17];
  const float* pp1w1  = (const float*)d_in[18];
  const float* pp1b1  = (const float*)d_in[19];
  const float* pp1w2  = (const float*)d_in[20];
  const float* pp1b2  = (const float*)d_in[21];
  const float* pp2w   = (const float*)d_in[22];
  const float* pp2b   = (const float*)d_in[23];
  const float* tokens = (const float*)d_in[24];
  const int* ei_kg = (const int*)d_in[25];
  const int* etype = (const int*)d_in[26];
  const int* ei_c  = (const int*)d_in[27];
  const int* ei_ts = (const int*)d_in[28];
  const int* ei_is = (const int*)d_in[29];
  const int* mte   = (const int*)d_in[30];
  const int* eids  = (const int*)d_in[31];

  float* O = (float*)d_out;
  unsigned short* xb    = (unsigned short*)(O + P_XB);
  unsigned short* wct   = (unsigned short*)(O + P_WCT);
  float* rcpc  = O + P_CNT;
  float* ent0  = O + P_ENT0;
  unsigned short* hh    = (unsigned short*)(O + P_HH);
  float* disc  = O + P_DIS;
  float* dist  = O + P_DIS + 30000;
  float* disi  = O + P_DIS + 36000;
  unsigned short* ent0b = (unsigned short*)(O + P_E0B);
  unsigned short* c1b   = (unsigned short*)(O + P_C1B);
  unsigned short* c2b   = (unsigned short*)(O + P_C2B);
  unsigned short* nfb   = (unsigned short*)(O + P_NFB);
  unsigned short* t1b   = (unsigned short*)(O + P_T1B);
  float* g1    = O + P_G1;
  float* accb  = O + P_ACC;
  unsigned short* entb  = (unsigned short*)(O + P_ENTB);
  unsigned short* hidb  = (unsigned short*)(O + P_HIDB);
  unsigned short* ent2b = (unsigned short*)(O + P_ENT2B);
  unsigned short* e768b = (unsigned short*)(O + P_E768B);
  unsigned short* tokb  = (unsigned short*)(O + P_TOKB);
  unsigned short* thidb = (unsigned short*)(O + P_THIDB);
  unsigned short* tok1b = (unsigned short*)(O + P_TOK1B);
  unsigned short* tok2b = (unsigned short*)(O + P_TOK2B);
  unsigned short* qb    = (unsigned short*)(O + P_QB);
  unsigned short* eemb  = (unsigned short*)(O + P_EEMB);
  float* pr0   = O + P_PR0;
  unsigned short* pr0b  = (unsigned short*)(O + P_PR0B);
  unsigned short* phidb = (unsigned short*)(O + P_PHIDB);
  unsigned short* wts   = (unsigned short*)(O + P_WT);

  int* iws = (int*)d_ws;
  unsigned short* p2b = (unsigned short*)d_ws;
  unsigned short* pp2t = (unsigned short*)d_ws + WS_PP2T_BYTE / 2;
  const bool ws_ok = (ws_size >= WS_NEED);
  int* cnt_i  = iws + I_CNT;
  int* part   = iws + I_PART;
  int* kg_rp  = iws + I_KG_RP;  int* kg_ca = iws + I_KG_CA;  int* kg_sl = iws + I_KG_SL;
  int* kg_bnd = iws + I_KG_BND; int* kg_cb = iws + I_KG_CB;
  int* c_rp   = iws + I_C_RP;   int* c_cur  = iws + I_C_CUR;   int* c_sl  = iws + I_C_SL;
  int* ts_rp  = iws + I_TS_RP;  int* ts_cur = iws + I_TS_CUR;  int* ts_sl = iws + I_TS_SL;
  int* is_rp  = iws + I_IS_RP;  int* is_cur = iws + I_IS_CUR;  int* is_sl = iws + I_IS_SL;

  const int EW = 256;

  // ---------------- phase A: conversions ----------------
  k_cvt<<<cdiv(NBf / 2, EW), EW, 0, stream>>>(x_node, xb, NBf / 2);
  k_wcat<<<cdiv(12 * Dm * Dm, EW), EW, 0, stream>>>(comp, bases, wct);
  k_cvt_t_all<<<2880, 256, 0, stream>>>(
      root, wts + S_ROOT, ep1w1, wts + S_EP1A, ep1w2, wts + S_EP1B,
      ep2w, wts + S_EP2, tp1w1, wts + S_TP1A, tp1w2, wts + S_TP1B,
      tp2w, wts + S_TP2, caw, wts + S_CAW, pp1w1, wts + S_PP1A,
      pp1w2, wts + S_PP1B);

  // ---------------- CSR builds ----------------
  // KG graph: split CSR (typ<6 in [rp,bnd), typ>=6 in [bnd,rp_next))
  hipMemsetAsync(cnt_i, 0, (size_t)NE * 4, stream);
  k_hist<<<cdiv(EKG, EW), EW, 0, stream>>>(ei_kg + EKG, cnt_i, EKG);
  {
    int nb = cdiv(NE, 256);
    k_scan_blk<<<nb, 256, 0, stream>>>(cnt_i, kg_rp, part, NE);
    k_scan_top<<<1, 256, 0, stream>>>(part, nb);
    k_scan_add<<<nb, 256, 0, stream>>>(kg_rp, part, kg_ca, NE);
  }
  hipMemsetAsync(cnt_i, 0, (size_t)NE * 4, stream);
  k_hist_lt<<<cdiv(EKG, EW), EW, 0, stream>>>(ei_kg + EKG, etype, cnt_i, EKG);
  k_add_i<<<cdiv(NE, EW), EW, 0, stream>>>(kg_rp, cnt_i, kg_bnd, kg_cb, NE);
  k_fill_split<<<cdiv(EKG, EW), EW, 0, stream>>>(
      ei_kg, ei_kg + EKG, etype, kg_ca, kg_cb, kg_sl, EKG);

  auto build_csr = [&](const int* ei, int n, int E, int* rp, int* cur, int* sl) {
    hipMemsetAsync(cnt_i, 0, (size_t)n * 4, stream);
    k_hist<<<cdiv(E, EW), EW, 0, stream>>>(ei + E, cnt_i, E);
    int nb = cdiv(n, 256);
    k_scan_blk<<<nb, 256, 0, stream>>>(cnt_i, rp, part, n);
    k_scan_top<<<1, 256, 0, stream>>>(part, nb);
    k_scan_add<<<nb, 256, 0, stream>>>(rp, part, cur, n);
    k_fill<<<cdiv(E, EW), EW, 0, stream>>>(ei, ei + E, cur, sl, E);
  };
  build_csr(ei_c, NE, EC, c_rp, c_cur, c_sl);
  build_csr(ei_ts, NM, ES, ts_rp, ts_cur, ts_sl);
  build_csr(ei_is, NM, ES, is_rp, is_cur, is_sl);

  k_dis_rp<<<cdiv(NE, EW), EW, 0, stream>>>(c_rp, disc, NE, EC);
  k_dis_rp<<<cdiv(NM, EW), EW, 0, stream>>>(ts_rp, dist, NM, ES);
  k_dis_rp<<<cdiv(NM, EW), EW, 0, stream>>>(is_rp, disi, NM, ES);

  hipMemsetAsync(rcpc, 0, (size_t)12 * NE * 4, stream);
  k_count_type<<<cdiv(EKG, EW), EW, 0, stream>>>(ei_kg + EKG, etype, rcpc, EKG);
  k_rcp<<<cdiv((long)12 * NE, EW), EW, 0, stream>>>(rcpc, (size_t)12 * NE);

  // ---------------- RGCN ----------------
  mgemm_bf<false, true, 0, 0><<<dim3(cdiv(NE, 128), cdiv(Dm, 128)), 256, 0, stream>>>(
      xb, wts + S_ROOT, rbias, x_node, ent0, NE, Dm, Dm);
  mgemm_bf<false, false, 1, 0><<<dim3(cdiv(NE, 128), cdiv(6 * Dm, 128)), 256, 0, stream>>>(
      xb, wct, nullptr, nullptr, hh, NE, 6 * Dm, Dm);
  k_rgcn_g<true, false><<<cdiv((long)NE * 64, EW), EW, 0, stream>>>(
      hh, rcpc, kg_rp, kg_bnd, kg_sl, ent0, nullptr, EKG);
  mgemm_bf<false, false, 1, 0><<<dim3(cdiv(NE, 128), cdiv(6 * Dm, 128)), 256, 0, stream>>>(
      xb, wct + (size_t)6 * Dm * Dm, nullptr, nullptr, hh, NE, 6 * Dm, Dm);
  k_rgcn_g<false, true><<<cdiv((long)NE * 64, EW), EW, 0, stream>>>(
      hh, rcpc, kg_rp, kg_bnd, kg_sl, ent0, ent0b, EKG);

  // ---------------- phase B: graph chains (bf16) ----------------
  k_gather_b<<<cdiv((long)NM * 192, EW), EW, 0, stream>>>(
      mte, (const uint32_t*)ent0b, (uint32_t*)nfb, NM, 192);
  k_gcn_gb<1, 3><<<cdiv((long)NM * 64, EW), EW, 0, stream>>>(
      nfb, dist, ts_rp, ts_sl, t1b, g1, NM, ES, 1.0f);
  k_gcn_gb<0, 1><<<cdiv((long)NM * 64, EW), EW, 0, stream>>>(
      t1b, dist, ts_rp, ts_sl, nullptr, g1, NM, ES, 1.0f);
  k_gcn_gb<1, 1><<<cdiv((long)NM * 64, EW), EW, 0, stream>>>(
      nfb, disi, is_rp, is_sl, t1b, g1, NM, ES, 1.0f);
  k_gcn_gb<0, 1><<<cdiv((long)NM * 64, EW), EW, 0, stream>>>(
      t1b, disi, is_rp, is_sl, nullptr, g1, NM, ES, 1.0f);
  // entity chain (0.25 folded)
  k_gcn_gb<1, 2><<<cdiv((long)NE * 64, EW), EW, 0, stream>>>(
      ent0b, disc, c_rp, c_sl, c1b, accb, NE, EC, 0.25f);
  k_gcn_gb<1, 1><<<cdiv((long)NE * 64, EW), EW, 0, stream>>>(
      c1b, disc, c_rp, c_sl, c2b, accb, NE, EC, 0.25f);
  k_scatter_movie<<<cdiv(MBF, EW), EW, 0, stream>>>(mte, g1, accb);
  k_gcn_gb<2, 1><<<cdiv((long)NE * 64, EW), EW, 0, stream>>>(
      c2b, disc, c_rp, c_sl, entb, accb, NE, EC, 0.25f);

  // pp2t conversion (CSR arrays now dead)
  if (ws_ok) {
    k_cvt_t<<<dim3(NO / 32, Hm / 32), 256, 0, stream>>>(pp2w, pp2t, Hm, NO);
  }

  // ---------------- entity MLP ----------------
  mgemm_bf<true, false, 1, 0><<<dim3(cdiv(NE, 128), cdiv(192, 128)), 256, 0, stream>>>(
      entb, wts + S_EP1A, ep1b1, nullptr, hidb, NE, 192, Dm);
  mgemm_bf<false, true, 1, 0><<<dim3(cdiv(NE, 128), cdiv(Dm, 128)), 256, 0, stream>>>(
      hidb, wts + S_EP1B, ep1b2, accb, ent2b, NE, Dm, 192);
  mgemm_bf<false, false, 1, 0><<<dim3(cdiv(NE, 128), cdiv(Hm, 128)), 256, 0, stream>>>(
      ent2b, wts + S_EP2, ep2b, nullptr, e768b, NE, Hm, Dm);

  // ---------------- token path ----------------
  k_cvt<<<cdiv((long)NTOK * Hm / 2, EW), EW, 0, stream>>>(tokens, tokb, (size_t)NTOK * Hm / 2);
  mgemm_bf<true, false, 1, 0><<<dim3(cdiv(NTOK, 128), cdiv(Dm, 128)), 256, 0, stream>>>(
      tokb, wts + S_TP1A, tp1b1, nullptr, thidb, NTOK, Dm, Hm);
  mgemm_bf<false, true, 1, 0><<<dim3(cdiv(NTOK, 128), cdiv(Hm, 128)), 256, 0, stream>>>(
      thidb, wts + S_TP1B, tp1b2, tokens, tok1b, NTOK, Hm, Dm);
  mgemm_bf<false, false, 1, 0><<<dim3(cdiv(NTOK, 128), cdiv(Hm, 128)), 256, 0, stream>>>(
      tok1b, wts + S_TP2, tp2b, nullptr, tok2b, NTOK, Hm, Hm);
  mgemm_bf<false, false, 1, 0><<<dim3(cdiv(NTOK, 128), cdiv(Hm, 128)), 256, 0, stream>>>(
      tok2b, wts + S_CAW, nullptr, nullptr, qb, NTOK, Hm, Hm);

  k_gather_b<<<cdiv((long)Bc * LE * (Hm / 2), EW), EW, 0, stream>>>(
      eids, (const uint32_t*)e768b, (uint32_t*)eemb, Bc * LE, Hm / 2);
  k_attn<<<cdiv((long)NTOK * 64, 256), 256, 0, stream>>>(qb, eemb, tok2b, pr0, pr0b);

  mgemm_bf<true, false, 1, 0><<<dim3(cdiv(NTOK, 128), cdiv(Dm, 128)), 256, 0, stream>>>(
      pr0b, wts + S_PP1A, pp1b1, nullptr, phidb, NTOK, Dm, Hm);
  mgemm_bf<false, true, 1, 0><<<dim3(cdiv(NTOK, 128), cdiv(Hm, 128)), 256, 0, stream>>>(
      phidb, wts + S_PP1B, pp1b2, pr0, p2b, NTOK, Hm, Dm);

  // ---------------- final GEMM + transpose (chunked-XCD swizzle) ----------
  if (ws_ok) {
    mgemm_bf<false, false, 2, 1><<<dim3(NTOK / 128, NO / 128), 256, 0, stream>>>(
        p2b, pp2t, pp2b, nullptr, O, NTOK, NO, Hm);
  } else {
    mgemm_fin<<<dim3(NTOK / 128, NO / 128), 256, 0, stream>>>(
        p2b, pp2w, pp2b, O, NTOK, NO, Hm);
  }
}

// Round 14
// 1518.137 us; speedup vs baseline: 1.0955x; 1.0242x over previous
//
#include <hip/hip_runtime.h>
#include <hip/hip_bf16.h>
#include <cstdint>
#include <cstddef>

// ---------------------------------------------------------------------------
// MMPrompt pipeline, round 14 = r13's fused gathers + a fully DISJOINT phase-B
// overlay. r13's NaN: phase-B buffers were spaced at half their true size
// (bf16 NE*384 = 5,760,000 f32, spacing was 2,880,000) — fusion made the
// aliases live; f32 g1 stores were later read as c2b bf16 => NaN. All phase-B
// regions are now pairwise disjoint (and legacy r7+ overlaps removed too).
// ---------------------------------------------------------------------------

namespace {

constexpr int NE   = 30000;
constexpr int NM   = 6000;
constexpr int Dm   = 384;
constexpr int Hm   = 768;
constexpr int EKG  = 200000;
constexpr int EC   = 200000;
constexpr int ES   = 80000;
constexpr int Bc   = 16;
constexpr int LE   = 48;
constexpr int NTOK = 4096;
constexpr int NO   = 18432;

constexpr size_t NBf = (size_t)NE * Dm;
constexpr size_t MBF = (size_t)NM * Dm;

// ---------------- d_out arena (f32-unit offsets) ----------------
// phase A: xb[0,5.76M) wct[5.76M,6.64M) rcpc[6.64M,7.00M) ent0[7.00M,18.52M)
//          hh[18.52M,53.08M) dis[53.08M,53.13M)
constexpr size_t P_XB    = 0;
constexpr size_t P_WCT   = 5760000;
constexpr size_t P_CNT   = 6644736;
constexpr size_t P_ENT0  = 7004736;
constexpr size_t P_HH    = 18524736;
constexpr size_t P_DIS   = 53084736;
// phase B (ALL PAIRWISE DISJOINT; over dead xb / ent0 / hh):
constexpr size_t P_E0B   = 0;          // bf16 NE*384: [0, 5,760,000)
constexpr size_t P_C1B   = 7004736;    // bf16 NE*384: [7,004,736, 12,764,736)
constexpr size_t P_C2B   = 12764736;   // bf16 NE*384: [12,764,736, 18,524,736)
constexpr size_t P_NFB   = 18600000;   // bf16 NM*384: ends 19,752,000
constexpr size_t P_T1B   = 19800000;   // bf16 NM*384: ends 20,952,000
constexpr size_t P_G1    = 21000000;   // f32  NM*384: ends 23,304,000
constexpr size_t P_T2B   = 23400000;   // bf16 NM*384: ends 24,552,000
constexpr size_t P_G2    = 24600000;   // f32  NM*384: ends 26,904,000
constexpr size_t P_ACC   = 41564736;   // f32  NE*384: ends 53,084,736 (dead hh)
constexpr size_t P_ENTB  = 55600000;   // bf16 NE*384: ends 61,360,000
// phase C (writers run after the phase-B buffers they overlay are dead):
constexpr size_t P_HIDB  = 0;          // bf16 NE*192: [0, 2,880,000)
constexpr size_t P_ENT2B = 2880000;    // bf16 NE*384: ends 8,640,000
constexpr size_t P_E768B = 8640000;    // bf16 NE*768: ends 20,160,000
constexpr size_t P_TOKB  = 20160000;   // bf16 4096*768: ends 21,732,864
constexpr size_t P_THIDB = 21732864;   // bf16 4096*384
constexpr size_t P_TOK1B = 22519296;   // bf16 4096*768
constexpr size_t P_TOK2B = 24092160;   // bf16 4096*768
constexpr size_t P_QB    = 25665024;   // bf16 4096*768
constexpr size_t P_EEMB  = 27237888;   // bf16 768*Hm
constexpr size_t P_PR0   = 27532800;   // f32 4096*768
constexpr size_t P_PR0B  = 30678528;   // bf16 4096*768
constexpr size_t P_PHIDB = 32251392;   // bf16 4096*384: ends 33,037,824
constexpr size_t P_WT    = 74000000;
constexpr size_t S_ROOT  = 0;
constexpr size_t S_EP1A  = 147456;
constexpr size_t S_EP1B  = 221184;
constexpr size_t S_EP2   = 294912;
constexpr size_t S_TP1A  = 589824;
constexpr size_t S_TP1B  = 884736;
constexpr size_t S_TP2   = 1179648;
constexpr size_t S_CAW   = 1769472;
constexpr size_t S_PP1A  = 2359296;
constexpr size_t S_PP1B  = 2654208;

// ---------------- d_ws layout ----------------
constexpr size_t WI       = 6291456 / 4;
constexpr size_t I_CNT    = WI + 0;
constexpr size_t I_PART   = WI + 30000;
constexpr size_t I_KG_RP  = WI + 30256;
constexpr size_t I_KG_CA  = WI + 60256;
constexpr size_t I_KG_SL  = WI + 90256;
constexpr size_t I_C_RP   = WI + 290256;
constexpr size_t I_C_CUR  = WI + 320256;
constexpr size_t I_C_SL   = WI + 350256;
constexpr size_t I_TS_RP  = WI + 550256;
constexpr size_t I_TS_CUR = WI + 556256;
constexpr size_t I_TS_SL  = WI + 562256;
constexpr size_t I_IS_RP  = WI + 642256;
constexpr size_t I_IS_CUR = WI + 648256;
constexpr size_t I_IS_SL  = WI + 654256;
constexpr size_t I_KG_BND = WI + 734256;
constexpr size_t I_KG_CB  = WI + 764256;
constexpr size_t WS_PP2T_BYTE = 6291456;
constexpr size_t WS_NEED      = 34603008;

constexpr int NBLK_E = (NE * 64) / 256;   // 7500
constexpr int NBLK_M = (NM * 64) / 256;   // 1500

inline int cdiv(long a, long b) { return (int)((a + b - 1) / b); }

} // namespace

typedef short short8v __attribute__((ext_vector_type(8)));
typedef float f32x4 __attribute__((ext_vector_type(4)));

__device__ __forceinline__ unsigned short f2bf(float f) {
  union { float f; uint32_t u; } v; v.f = f;
  uint32_t u = v.u;
  u += 0x7fffu + ((u >> 16) & 1u);
  return (unsigned short)(u >> 16);
}
__device__ __forceinline__ uint32_t pkbf(float a, float b) {
  __hip_bfloat162 h = __float22bfloat162_rn(float2{a, b});
  union { __hip_bfloat162 h; uint32_t u; } cv; cv.h = h;
  return cv.u;
}
__device__ __forceinline__ float bflo(uint32_t u) {
  union { uint32_t u; float f; } c; c.u = u << 16; return c.f;
}
__device__ __forceinline__ float bfhi(uint32_t u) {
  union { uint32_t u; float f; } c; c.u = u & 0xFFFF0000u; return c.f;
}

__device__ __forceinline__ void gl16(const void* g, void* l) {
  __builtin_amdgcn_global_load_lds(
      (const __attribute__((address_space(1))) void*)g,
      (__attribute__((address_space(3))) void*)l, 16, 0, 0);
}

// ---------------------------------------------------------------------------
// conversion / utility kernels
// ---------------------------------------------------------------------------

__global__ void k_cvt(const float* __restrict__ x, unsigned short* __restrict__ o, size_t n2) {
  size_t i = (size_t)blockIdx.x * 256 + threadIdx.x;
  if (i >= n2) return;
  float2 v = *(const float2*)(x + 2 * i);
  *(uint32_t*)(o + 2 * i) = pkbf(v.x, v.y);
}

// f32 W[K][N] -> bf16 Wt[N][K] (pp2t only)
__global__ void k_cvt_t(const float* __restrict__ W, unsigned short* __restrict__ Wt,
                        int K, int N) {
  __shared__ float t[32][33];
  int tx = threadIdx.x & 31, ty = threadIdx.x >> 5;
  int n0 = blockIdx.x * 32, k0 = blockIdx.y * 32;
#pragma unroll
  for (int j = 0; j < 4; ++j)
    t[ty + 8 * j][tx] = W[(size_t)(k0 + ty + 8 * j) * N + n0 + tx];
  __syncthreads();
#pragma unroll
  for (int j = 0; j < 4; ++j) {
    int n = ty + 8 * j;
    Wt[(size_t)(n0 + n) * K + k0 + tx] = f2bf(t[tx][n]);
  }
}

// batched weight transpose-convert (10 weights; 2880 tiles)
__global__ void k_cvt_t_all(
    const float* s0, unsigned short* d0, const float* s1, unsigned short* d1,
    const float* s2, unsigned short* d2, const float* s3, unsigned short* d3,
    const float* s4, unsigned short* d4, const float* s5, unsigned short* d5,
    const float* s6, unsigned short* d6, const float* s7, unsigned short* d7,
    const float* s8, unsigned short* d8, const float* s9, unsigned short* d9) {
  __shared__ float t[32][33];
  int tile = blockIdx.x;
  const float* W; unsigned short* Wt; int K, N, base;
  if      (tile < 144)  { W = s0; Wt = d0; K = 384; N = 384; base = 0; }
  else if (tile < 216)  { W = s1; Wt = d1; K = 384; N = 192; base = 144; }
  else if (tile < 288)  { W = s2; Wt = d2; K = 192; N = 384; base = 216; }
  else if (tile < 576)  { W = s3; Wt = d3; K = 384; N = 768; base = 288; }
  else if (tile < 864)  { W = s4; Wt = d4; K = 768; N = 384; base = 576; }
  else if (tile < 1152) { W = s5; Wt = d5; K = 384; N = 768; base = 864; }
  else if (tile < 1728) { W = s6; Wt = d6; K = 768; N = 768; base = 1152; }
  else if (tile < 2304) { W = s7; Wt = d7; K = 768; N = 768; base = 1728; }
  else if (tile < 2592) { W = s8; Wt = d8; K = 768; N = 384; base = 2304; }
  else                  { W = s9; Wt = d9; K = 384; N = 768; base = 2592; }
  int lt = tile - base;
  int ntx = N >> 5;
  int n0 = (lt % ntx) * 32, k0 = (lt / ntx) * 32;
  int tx = threadIdx.x & 31, ty = threadIdx.x >> 5;
#pragma unroll
  for (int j = 0; j < 4; ++j)
    t[ty + 8 * j][tx] = W[(size_t)(k0 + ty + 8 * j) * N + n0 + tx];
  __syncthreads();
#pragma unroll
  for (int j = 0; j < 4; ++j) {
    int n = ty + 8 * j;
    Wt[(size_t)(n0 + n) * K + k0 + tx] = f2bf(t[tx][n]);
  }
}

__global__ void k_wcat(const float* __restrict__ comp, const float* __restrict__ bases,
                       unsigned short* __restrict__ Wt) {
  int idx = blockIdx.x * 256 + threadIdx.x;
  if (idx >= 12 * Dm * Dm) return;
  int i = idx % Dm;
  int o = (idx / Dm) % Dm;
  int r = idx / (Dm * Dm);
  float s = 0.f;
#pragma unroll
  for (int b = 0; b < 8; ++b)
    s += comp[r * 8 + b] * bases[(size_t)b * Dm * Dm + (size_t)i * Dm + o];
  Wt[idx] = f2bf(s);
}

__global__ void k_gather_b(const int* __restrict__ idx, const uint32_t* __restrict__ x2,
                           uint32_t* __restrict__ out2, int rows, int D2) {
  size_t i = (size_t)blockIdx.x * 256 + threadIdx.x;
  if (i >= (size_t)rows * D2) return;
  int r = (int)(i / D2);
  int c = (int)(i - (size_t)r * D2);
  out2[i] = x2[(size_t)idx[r] * D2 + c];
}

// ent[mte[m]][d] += 0.25*(g1[m][d]+g2[m][d])
__global__ void k_scatter_movie2(const int* __restrict__ mte, const float* __restrict__ g1,
                                 const float* __restrict__ g2, float* __restrict__ ent) {
  size_t i = (size_t)blockIdx.x * 256 + threadIdx.x;
  if (i >= MBF) return;
  int m = (int)(i / Dm);
  int d = (int)(i - (size_t)m * Dm);
  atomicAdd(&ent[(size_t)mte[m] * Dm + d], 0.25f * (g1[i] + g2[i]));
}

// ---------------------------------------------------------------------------
// CSR build
// ---------------------------------------------------------------------------

__global__ void k_hist(const int* __restrict__ dst, int* __restrict__ cnt, int E) {
  int e = blockIdx.x * 256 + threadIdx.x;
  if (e < E) atomicAdd(&cnt[dst[e]], 1);
}

__global__ void k_hist_lt(const int* __restrict__ dst, const int* __restrict__ typ,
                          int* __restrict__ cnt, int E) {
  int e = blockIdx.x * 256 + threadIdx.x;
  if (e < E && typ[e] < 6) atomicAdd(&cnt[dst[e]], 1);
}

__global__ void k_add_i(const int* __restrict__ a, const int* __restrict__ b,
                        int* __restrict__ o, int* __restrict__ o2, int n) {
  int i = blockIdx.x * 256 + threadIdx.x;
  if (i < n) { int v = a[i] + b[i]; o[i] = v; o2[i] = v; }
}

__global__ void k_scan_blk(const int* __restrict__ in, int* __restrict__ out,
                           int* __restrict__ part, int n) {
  __shared__ int s[256];
  int t = threadIdx.x;
  int g = blockIdx.x * 256 + t;
  int v = (g < n) ? in[g] : 0;
  s[t] = v;
  __syncthreads();
  for (int off = 1; off < 256; off <<= 1) {
    int add = (t >= off) ? s[t - off] : 0;
    __syncthreads();
    s[t] += add;
    __syncthreads();
  }
  if (g < n) out[g] = s[t] - v;
  if (t == 255) part[blockIdx.x] = s[255];
}

__global__ void k_scan_top(int* __restrict__ part, int nb) {
  __shared__ int s[256];
  int t = threadIdx.x;
  int v = (t < nb) ? part[t] : 0;
  s[t] = v;
  __syncthreads();
  for (int off = 1; off < 256; off <<= 1) {
    int add = (t >= off) ? s[t - off] : 0;
    __syncthreads();
    s[t] += add;
    __syncthreads();
  }
  if (t < nb) part[t] = s[t] - v;
}

__global__ void k_scan_add(int* __restrict__ out, const int* __restrict__ part,
                           int* __restrict__ cur, int n) {
  int g = blockIdx.x * 256 + threadIdx.x;
  if (g < n) { int v = out[g] + part[blockIdx.x]; out[g] = v; cur[g] = v; }
}

__global__ void k_fill(const int* __restrict__ src, const int* __restrict__ dst,
                       int* __restrict__ cur, int* __restrict__ slots, int E) {
  int e = blockIdx.x * 256 + threadIdx.x;
  if (e >= E) return;
  int d = dst[e];
  int pos = atomicAdd(&cur[d], 1);
  slots[pos] = src[e];
}

__global__ void k_fill_split(const int* __restrict__ src, const int* __restrict__ dst,
                             const int* __restrict__ typ, int* __restrict__ cur_a,
                             int* __restrict__ cur_b, int* __restrict__ slots, int E) {
  int e = blockIdx.x * 256 + threadIdx.x;
  if (e >= E) return;
  int d = dst[e];
  int* c = (typ[e] < 6) ? cur_a : cur_b;
  int pos = atomicAdd(&c[d], 1);
  slots[pos] = src[e] | (typ[e] << 16);
}

__global__ void k_dis_rp(const int* __restrict__ rp, float* __restrict__ dis, int n, int E) {
  int v = blockIdx.x * 256 + threadIdx.x;
  if (v >= n) return;
  int e0 = rp[v], e1 = (v + 1 < n) ? rp[v + 1] : E;
  dis[v] = rsqrtf((float)(e1 - e0) + 1.0f);
}

__global__ void k_count_type(const int* __restrict__ dst, const int* __restrict__ typ,
                             float* __restrict__ cnt, int E) {
  int i = blockIdx.x * 256 + threadIdx.x;
  if (i < E) atomicAdd(&cnt[(size_t)typ[i] * NE + dst[i]], 1.0f);
}

__global__ void k_rcp(float* __restrict__ c, size_t n) {
  size_t i = (size_t)blockIdx.x * 256 + threadIdx.x;
  if (i < n) { float v = c[i]; c[i] = (v > 0.f) ? 1.0f / v : 0.f; }
}

// ---------------------------------------------------------------------------
// GCN gather body: one wave per dst row, 2-edge unrolled.
// OUTM: 0 none, 1 outb=bf16(a), 2 outb=bf16(acc_new).
// ACCM: 1 acc += sc*a; 2 acc = sc*(x[v]+a); 3 acc = sc*a.
// ---------------------------------------------------------------------------
template <int OUTM, int ACCM>
__device__ __forceinline__ void gcn_body(
    const unsigned short* __restrict__ x, const float* __restrict__ dis,
    const int* __restrict__ rp, const int* __restrict__ slots,
    unsigned short* __restrict__ outb, float* __restrict__ acc,
    int n, int E, float sc, int blk) {
  int v = (int)(((size_t)blk * 256 + threadIdx.x) >> 6);
  int lane = threadIdx.x & 63;
  if (v >= n) return;
  float dv = dis[v];
  const uint32_t* xr = (const uint32_t*)(x + (size_t)v * Dm);
  float xv[6];
#pragma unroll
  for (int i = 0; i < 3; ++i) {
    uint32_t u = xr[lane + 64 * i];
    xv[2 * i] = bflo(u); xv[2 * i + 1] = bfhi(u);
  }
  float a[6];
#pragma unroll
  for (int i = 0; i < 6; ++i) a[i] = dv * xv[i];
  int e0 = rp[v], e1 = (v + 1 < n) ? rp[v + 1] : E;
  int e = e0;
  for (; e + 2 <= e1; e += 2) {
    int s0 = slots[e], s1 = slots[e + 1];
    float c0 = dis[s0], c1 = dis[s1];
    const uint32_t* x0 = (const uint32_t*)(x + (size_t)s0 * Dm);
    const uint32_t* x1 = (const uint32_t*)(x + (size_t)s1 * Dm);
    uint32_t u0[3], u1[3];
#pragma unroll
    for (int i = 0; i < 3; ++i) { u0[i] = x0[lane + 64 * i]; u1[i] = x1[lane + 64 * i]; }
#pragma unroll
    for (int i = 0; i < 3; ++i) {
      a[2 * i]     = fmaf(c0, bflo(u0[i]), a[2 * i]);
      a[2 * i + 1] = fmaf(c0, bfhi(u0[i]), a[2 * i + 1]);
      a[2 * i]     = fmaf(c1, bflo(u1[i]), a[2 * i]);
      a[2 * i + 1] = fmaf(c1, bfhi(u1[i]), a[2 * i + 1]);
    }
  }
  if (e < e1) {
    int s0 = slots[e];
    float c0 = dis[s0];
    const uint32_t* x0 = (const uint32_t*)(x + (size_t)s0 * Dm);
#pragma unroll
    for (int i = 0; i < 3; ++i) {
      uint32_t u = x0[lane + 64 * i];
      a[2 * i]     = fmaf(c0, bflo(u), a[2 * i]);
      a[2 * i + 1] = fmaf(c0, bfhi(u), a[2 * i + 1]);
    }
  }
#pragma unroll
  for (int i = 0; i < 6; ++i) a[i] *= dv;
  if (OUTM == 1) {
    uint32_t* ob = (uint32_t*)(outb + (size_t)v * Dm);
#pragma unroll
    for (int i = 0; i < 3; ++i) ob[lane + 64 * i] = pkbf(a[2 * i], a[2 * i + 1]);
  }
  float* ar = acc + (size_t)v * Dm;
  float nw[6];
#pragma unroll
  for (int i = 0; i < 3; ++i) {
    int cidx = 2 * (lane + 64 * i);
    if (ACCM == 1) {
      float2 old = *(const float2*)(ar + cidx);
      nw[2 * i] = old.x + sc * a[2 * i];
      nw[2 * i + 1] = old.y + sc * a[2 * i + 1];
    } else if (ACCM == 2) {
      nw[2 * i] = sc * (xv[2 * i] + a[2 * i]);
      nw[2 * i + 1] = sc * (xv[2 * i + 1] + a[2 * i + 1]);
    } else {
      nw[2 * i] = sc * a[2 * i];
      nw[2 * i + 1] = sc * a[2 * i + 1];
    }
    *(float2*)(ar + cidx) = float2{nw[2 * i], nw[2 * i + 1]};
  }
  if (OUTM == 2) {
    uint32_t* ob = (uint32_t*)(outb + (size_t)v * Dm);
#pragma unroll
    for (int i = 0; i < 3; ++i) ob[lane + 64 * i] = pkbf(nw[2 * i], nw[2 * i + 1]);
  }
}

template <int OUTM, int ACCM>
__global__ void k_gcn_gb(const unsigned short* __restrict__ x, const float* __restrict__ dis,
                         const int* __restrict__ rp, const int* __restrict__ slots,
                         unsigned short* __restrict__ outb, float* __restrict__ acc,
                         int n, int E, float sc) {
  gcn_body<OUTM, ACCM>(x, dis, rp, slots, outb, acc, n, E, sc, blockIdx.x);
}

// fused round 1: c1 (entity) || ts1 || is1
__global__ void k_gcn_r1(const unsigned short* e0b, const float* disc,
                         const int* c_rp, const int* c_sl,
                         unsigned short* c1b, float* accb,
                         const unsigned short* nfb,
                         const float* dist, const int* ts_rp, const int* ts_sl,
                         unsigned short* t1b, float* g1,
                         const float* disi, const int* is_rp, const int* is_sl,
                         unsigned short* t2b, float* g2) {
  int blk = blockIdx.x;
  if (blk < NBLK_E) {
    gcn_body<1, 2>(e0b, disc, c_rp, c_sl, c1b, accb, NE, EC, 0.25f, blk);
  } else if (blk < NBLK_E + NBLK_M) {
    gcn_body<1, 3>(nfb, dist, ts_rp, ts_sl, t1b, g1, NM, ES, 1.0f, blk - NBLK_E);
  } else {
    gcn_body<1, 3>(nfb, disi, is_rp, is_sl, t2b, g2, NM, ES, 1.0f, blk - NBLK_E - NBLK_M);
  }
}

// fused round 2: c2 (entity) || ts2 || is2
__global__ void k_gcn_r2(const unsigned short* c1b, const float* disc,
                         const int* c_rp, const int* c_sl,
                         unsigned short* c2b, float* accb,
                         const unsigned short* t1b,
                         const float* dist, const int* ts_rp, const int* ts_sl, float* g1,
                         const unsigned short* t2b,
                         const float* disi, const int* is_rp, const int* is_sl, float* g2) {
  int blk = blockIdx.x;
  if (blk < NBLK_E) {
    gcn_body<1, 1>(c1b, disc, c_rp, c_sl, c2b, accb, NE, EC, 0.25f, blk);
  } else if (blk < NBLK_E + NBLK_M) {
    gcn_body<0, 1>(t1b, dist, ts_rp, ts_sl, nullptr, g1, NM, ES, 1.0f, blk - NBLK_E);
  } else {
    gcn_body<0, 1>(t2b, disi, is_rp, is_sl, nullptr, g2, NM, ES, 1.0f, blk - NBLK_E - NBLK_M);
  }
}

// ---------------------------------------------------------------------------
// RGCN gather, split-range, 2-edge unrolled. EMITB: emit ent0b bf16 (last).
// ---------------------------------------------------------------------------
template <bool FIRST, bool EMITB>
__global__ void k_rgcn_g(const unsigned short* __restrict__ hh, const float* __restrict__ rcp,
                         const int* __restrict__ rp, const int* __restrict__ bnd,
                         const int* __restrict__ slots, float* __restrict__ ent0,
                         unsigned short* __restrict__ outb, int E) {
  int v = (int)((blockIdx.x * (size_t)blockDim.x + threadIdx.x) >> 6);
  int lane = threadIdx.x & 63;
  if (v >= NE) return;
  const int rbase = FIRST ? 0 : 6;
  int e0, e1;
  if (FIRST) { e0 = rp[v]; e1 = bnd[v]; }
  else       { e0 = bnd[v]; e1 = (v + 1 < NE) ? rp[v + 1] : E; }
  float* er = ent0 + (size_t)v * Dm;
  float2 a[3];
#pragma unroll
  for (int i = 0; i < 3; ++i) a[i] = *(const float2*)(er + 2 * lane + 128 * i);
  int e = e0;
  for (; e + 2 <= e1; e += 2) {
    int p0 = slots[e], p1 = slots[e + 1];
    int r0 = (p0 >> 16) - rbase, s0 = p0 & 0xFFFF;
    int r1 = (p1 >> 16) - rbase, s1 = p1 & 0xFFFF;
    float nm0 = rcp[(size_t)(r0 + rbase) * NE + v];
    float nm1 = rcp[(size_t)(r1 + rbase) * NE + v];
    const uint32_t* h0 = (const uint32_t*)(hh + (size_t)s0 * 2304 + (size_t)r0 * 384);
    const uint32_t* h1 = (const uint32_t*)(hh + (size_t)s1 * 2304 + (size_t)r1 * 384);
    uint32_t u0[3], u1[3];
#pragma unroll
    for (int i = 0; i < 3; ++i) { u0[i] = h0[lane + 64 * i]; u1[i] = h1[lane + 64 * i]; }
#pragma unroll
    for (int i = 0; i < 3; ++i) {
      a[i].x = fmaf(nm0, bflo(u0[i]), a[i].x);
      a[i].y = fmaf(nm0, bfhi(u0[i]), a[i].y);
      a[i].x = fmaf(nm1, bflo(u1[i]), a[i].x);
      a[i].y = fmaf(nm1, bfhi(u1[i]), a[i].y);
    }
  }
  if (e < e1) {
    int p0 = slots[e];
    int r0 = (p0 >> 16) - rbase, s0 = p0 & 0xFFFF;
    float nm0 = rcp[(size_t)(r0 + rbase) * NE + v];
    const uint32_t* h0 = (const uint32_t*)(hh + (size_t)s0 * 2304 + (size_t)r0 * 384);
#pragma unroll
    for (int i = 0; i < 3; ++i) {
      uint32_t u = h0[lane + 64 * i];
      a[i].x = fmaf(nm0, bflo(u), a[i].x);
      a[i].y = fmaf(nm0, bfhi(u), a[i].y);
    }
  }
#pragma unroll
  for (int i = 0; i < 3; ++i) *(float2*)(er + 2 * lane + 128 * i) = a[i];
  if (EMITB) {
    uint32_t* ob = (uint32_t*)(outb + (size_t)v * Dm);
#pragma unroll
    for (int i = 0; i < 3; ++i) ob[lane + 64 * i] = pkbf(a[i].x, a[i].y);
  }
}

// ---------------------------------------------------------------------------
// bf16 MFMA GEMM, 128x128 (m97 structure). A[M][K], Wt[N][K] bf16.
// OUT: 0 = f32 C, 1 = bf16 C, 2 = f32 transposed prompt layout (decomposed).
// ---------------------------------------------------------------------------
template <bool RELU, bool RES, int OUT>
__global__ __launch_bounds__(256) void mgemm_bf(
    const unsigned short* __restrict__ A, const unsigned short* __restrict__ Wt,
    const float* __restrict__ bias, const float* __restrict__ Rp,
    void* __restrict__ Cv, int M, int N, int K) {
  __shared__ __align__(16) unsigned short As[128 * 64];
  __shared__ __align__(16) unsigned short Bs[128 * 64];
  const int tid = threadIdx.x;
  const int lane = tid & 63;
  const int w = tid >> 6;
  const int bm = blockIdx.x * 128, bn = blockIdx.y * 128;
  const int wr = (w >> 1) * 64, wc = (w & 1) * 64;
  const int lrow = lane & 15, lq = lane >> 4;
  f32x4 acc[4][4] = {};
  const int prow_l = lane >> 3;
  const int pslot = lane & 7;

  for (int k0 = 0; k0 < K; k0 += 64) {
    __syncthreads();
#pragma unroll
    for (int j = 0; j < 4; ++j) {
      int seg = j * 4 + w;
      int prow = seg * 8 + prow_l;
      int aslot = pslot ^ (prow & 7);
      int arow = min(bm + prow, M - 1);
      gl16(A + (size_t)arow * K + k0 + aslot * 8, &As[seg * 512 + lane * 8]);
    }
#pragma unroll
    for (int j = 0; j < 4; ++j) {
      int seg = j * 4 + w;
      int prow = seg * 8 + prow_l;
      int bslot = pslot ^ (prow & 7);
      int brow = min(bn + prow, N - 1);
      gl16(Wt + (size_t)brow * K + k0 + bslot * 8, &Bs[seg * 512 + lane * 8]);
    }
    __syncthreads();
#pragma unroll
    for (int ks = 0; ks < 2; ++ks) {
      short8v af[4], bf[4];
      const int slot = ks * 4 + lq;
#pragma unroll
      for (int mr = 0; mr < 4; ++mr) {
        int r = wr + mr * 16 + lrow;
        af[mr] = *(const short8v*)&As[r * 64 + ((slot ^ (r & 7)) << 3)];
      }
#pragma unroll
      for (int nc = 0; nc < 4; ++nc) {
        int r = wc + nc * 16 + lrow;
        bf[nc] = *(const short8v*)&Bs[r * 64 + ((slot ^ (r & 7)) << 3)];
      }
#pragma unroll
      for (int mr = 0; mr < 4; ++mr)
#pragma unroll
        for (int nc = 0; nc < 4; ++nc)
          acc[mr][nc] = __builtin_amdgcn_mfma_f32_16x16x32_bf16(
              af[mr], bf[nc], acc[mr][nc], 0, 0, 0);
    }
  }
  size_t colb[4];
  if (OUT == 2) {
#pragma unroll
    for (int nc = 0; nc < 4; ++nc) {
      int c = bn + wc + nc * 16 + lrow;
      int l = c / 1536, rem = c - l * 1536;
      int blk = rem / 768, rem2 = rem - blk * 768;
      int h2 = rem2 >> 6, dd = rem2 & 63;
      colb[nc] = (size_t)(l * 2 + blk) * 3145728 + (size_t)h2 * 16384 + dd;
    }
  }
#pragma unroll
  for (int mr = 0; mr < 4; ++mr) {
#pragma unroll
    for (int e = 0; e < 4; ++e) {
      int r = bm + wr + mr * 16 + lq * 4 + e;
      if (r >= M) continue;
      size_t rowoff = 0;
      if (OUT == 2) rowoff = (size_t)r * 64 + (size_t)(r >> 8) * 180224;
#pragma unroll
      for (int nc = 0; nc < 4; ++nc) {
        int c = bn + wc + nc * 16 + lrow;
        if (c >= N) continue;
        float v = acc[mr][nc][e];
        if (bias) v += bias[c];
        if (RES) v += Rp[(size_t)r * N + c];
        if (RELU) v = fmaxf(v, 0.f);
        if (OUT == 0) {
          ((float*)Cv)[(size_t)r * N + c] = v;
        } else if (OUT == 1) {
          ((unsigned short*)Cv)[(size_t)r * N + c] = f2bf(v);
        } else {
          ((float*)Cv)[colb[nc] + rowoff] = v;
        }
      }
    }
  }
}

// Fallback FINAL GEMM (ws too small): W f32 from d_in, in-kernel conversion.
__global__ __launch_bounds__(256) void mgemm_fin(
    const unsigned short* __restrict__ A, const float* __restrict__ W,
    const float* __restrict__ bias, float* __restrict__ O, int M, int N, int K) {
  __shared__ __align__(16) unsigned short As[128 * 64];
  __shared__ __align__(16) unsigned short Bs[128 * 64];
  const int tid = threadIdx.x;
  const int lane = tid & 63;
  const int w = tid >> 6;
  const int bm = blockIdx.x * 128, bn = blockIdx.y * 128;
  const int wr = (w >> 1) * 64, wc = (w & 1) * 64;
  const int lrow = lane & 15, lq = lane >> 4;
  f32x4 acc[4][4] = {};
  const int prow_l = lane >> 3;
  const int pslot = lane & 7;
  const int n_loc = tid & 127;
  const int kh = (tid >> 7) * 32;

  for (int k0 = 0; k0 < K; k0 += 64) {
    __syncthreads();
#pragma unroll
    for (int j = 0; j < 4; ++j) {
      int seg = j * 4 + w;
      int prow = seg * 8 + prow_l;
      int aslot = pslot ^ (prow & 7);
      gl16(A + (size_t)(bm + prow) * K + k0 + aslot * 8, &As[seg * 512 + lane * 8]);
    }
    float wv[32];
    const float* wp = W + (size_t)(k0 + kh) * N + bn + n_loc;
#pragma unroll
    for (int j = 0; j < 32; ++j) wv[j] = wp[(size_t)j * N];
#pragma unroll
    for (int c = 0; c < 4; ++c) {
      uint32_t u0 = pkbf(wv[8 * c + 0], wv[8 * c + 1]);
      uint32_t u1 = pkbf(wv[8 * c + 2], wv[8 * c + 3]);
      uint32_t u2 = pkbf(wv[8 * c + 4], wv[8 * c + 5]);
      uint32_t u3 = pkbf(wv[8 * c + 6], wv[8 * c + 7]);
      int s = (kh >> 3) + c;
      *(uint4*)&Bs[n_loc * 64 + ((s ^ (n_loc & 7)) << 3)] = uint4{u0, u1, u2, u3};
    }
    __syncthreads();
#pragma unroll
    for (int ks = 0; ks < 2; ++ks) {
      short8v af[4], bf[4];
      const int slot = ks * 4 + lq;
#pragma unroll
      for (int mr = 0; mr < 4; ++mr) {
        int r = wr + mr * 16 + lrow;
        af[mr] = *(const short8v*)&As[r * 64 + ((slot ^ (r & 7)) << 3)];
      }
#pragma unroll
      for (int nc = 0; nc < 4; ++nc) {
        int r = wc + nc * 16 + lrow;
        bf[nc] = *(const short8v*)&Bs[r * 64 + ((slot ^ (r & 7)) << 3)];
      }
#pragma unroll
      for (int mr = 0; mr < 4; ++mr)
#pragma unroll
        for (int nc = 0; nc < 4; ++nc)
          acc[mr][nc] = __builtin_amdgcn_mfma_f32_16x16x32_bf16(
              af[mr], bf[nc], acc[mr][nc], 0, 0, 0);
    }
  }
#pragma unroll
  for (int mr = 0; mr < 4; ++mr) {
#pragma unroll
    for (int e = 0; e < 4; ++e) {
      int r = bm + wr + mr * 16 + lq * 4 + e;
      int b = r >> 8, t = r & 255;
#pragma unroll
      for (int nc = 0; nc < 4; ++nc) {
        int c = bn + wc + nc * 16 + lrow;
        float v = acc[mr][nc][e] + bias[c];
        int l = c / 1536, rem = c - l * 1536;
        int blk = rem / 768, rem2 = rem - blk * 768;
        int hh = rem2 >> 6, dd = rem2 & 63;
        size_t oi = (((((size_t)l * 2 + blk) * 16 + b) * 12 + hh) * 256 + t) * 64 + dd;
        O[oi] = v;
      }
    }
  }
}

// ---------------------------------------------------------------------------
// fused cross-attention (bf16 inputs): one wave per (b,t)
// ---------------------------------------------------------------------------
__global__ __launch_bounds__(256) void k_attn(
    const unsigned short* __restrict__ qb, const unsigned short* __restrict__ eb_all,
    const unsigned short* __restrict__ tokb, float* __restrict__ pr0,
    unsigned short* __restrict__ pr0b) {
  int gw = (int)((blockIdx.x * (size_t)blockDim.x + threadIdx.x) >> 6);
  int lane = threadIdx.x & 63;
  if (gw >= NTOK) return;
  int b = gw >> 8;
  const unsigned short* qr = qb + (size_t)gw * Hm;
  float2 q[6];
#pragma unroll
  for (int i = 0; i < 6; ++i) {
    uint32_t u = *(const uint32_t*)(qr + 2 * lane + 128 * i);
    q[i] = float2{bflo(u), bfhi(u)};
  }
  const unsigned short* eb = eb_all + (size_t)b * LE * Hm;
  float myA = -3.0e38f;
  for (int e = 0; e < LE; ++e) {
    const unsigned short* er = eb + (size_t)e * Hm;
    float s = 0.f;
#pragma unroll
    for (int i = 0; i < 6; ++i) {
      uint32_t u = *(const uint32_t*)(er + 2 * lane + 128 * i);
      s = fmaf(q[i].x, bflo(u), s);
      s = fmaf(q[i].y, bfhi(u), s);
    }
#pragma unroll
    for (int off = 32; off > 0; off >>= 1) s += __shfl_xor(s, off);
    if (lane == e) myA = s * (1.0f / 768.0f);
  }
  float mx = myA;
#pragma unroll
  for (int off = 32; off > 0; off >>= 1) mx = fmaxf(mx, __shfl_xor(mx, off));
  float p = (lane < LE) ? expf(myA - mx) : 0.f;
  float sum = p;
#pragma unroll
  for (int off = 32; off > 0; off >>= 1) sum += __shfl_xor(sum, off);
  float wgt = p / sum;
  const unsigned short* tr = tokb + (size_t)gw * Hm;
  float2 a[6];
#pragma unroll
  for (int i = 0; i < 6; ++i) {
    uint32_t u = *(const uint32_t*)(tr + 2 * lane + 128 * i);
    a[i] = float2{bflo(u), bfhi(u)};
  }
  for (int e = 0; e < LE; ++e) {
    float we = __shfl(wgt, e);
    const unsigned short* er = eb + (size_t)e * Hm;
#pragma unroll
    for (int i = 0; i < 6; ++i) {
      uint32_t u = *(const uint32_t*)(er + 2 * lane + 128 * i);
      a[i].x = fmaf(we, bflo(u), a[i].x);
      a[i].y = fmaf(we, bfhi(u), a[i].y);
    }
  }
  float* orow = pr0 + (size_t)gw * Hm;
  unsigned short* obrow = pr0b + (size_t)gw * Hm;
#pragma unroll
  for (int i = 0; i < 6; ++i) {
    *(float2*)(orow + 2 * lane + 128 * i) = a[i];
    *(uint32_t*)(obrow + 2 * lane + 128 * i) = pkbf(a[i].x, a[i].y);
  }
}

// ---------------------------------------------------------------------------

extern "C" void kernel_launch(void* const* d_in, const int* in_sizes, int n_in,
                              void* d_out, int out_size, void* d_ws, size_t ws_size,
                              hipStream_t stream) {
  (void)in_sizes; (void)n_in; (void)out_size;

  const float* x_node = (const float*)d_in[0];
  const float* bases  = (const float*)d_in[1];
  const float* comp   = (const float*)d_in[2];
  const float* root   = (const float*)d_in[3];
  const float* rbias  = (const float*)d_in[4];
  const float* ep1w1  = (const float*)d_in[5];
  const float* ep1b1  = (const float*)d_in[6];
  const float* ep1w2  = (const float*)d_in[7];
  const float* ep1b2  = (const float*)d_in[8];
  const float* ep2w   = (const float*)d_in[9];
  const float* ep2b   = (const float*)d_in[10];
  const float* tp1w1  = (const float*)d_in[11];
  const float* tp1b1  = (const float*)d_in[12];
  const float* tp1w2  = (const float*)d_in[13];
  const float* tp1b2  = (const float*)d_in[14];
  const float* tp2w   = (const float*)d_in[15];
  const float* tp2b   = (const float*)d_in[16];
  const float* caw    = (const float*)d_in[17];
  const float* pp1w1  = (const float*)d_in[18];
  const float* pp1b1  = (const float*)d_in[19];
  const float* pp1w2  = (const float*)d_in[20];
  const float* pp1b2  = (const float*)d_in[21];
  const float* pp2w   = (const float*)d_in[22];
  const float* pp2b   = (const float*)d_in[23];
  const float* tokens = (const float*)d_in[24];
  const int* ei_kg = (const int*)d_in[25];
  const int* etype = (const int*)d_in[26];
  const int* ei_c  = (const int*)d_in[27];
  const int* ei_ts = (const int*)d_in[28];
  const int* ei_is = (const int*)d_in[29];
  const int* mte   = (const int*)d_in[30];
  const int* eids  = (const int*)d_in[31];

  float* O = (float*)d_out;
  unsigned short* xb    = (unsigned short*)(O + P_XB);
  unsigned short* wct   = (unsigned short*)(O + P_WCT);
  float* rcpc  = O + P_CNT;
  float* ent0  = O + P_ENT0;
  unsigned short* hh    = (unsigned short*)(O + P_HH);
  float* disc  = O + P_DIS;
  float* dist  = O + P_DIS + 30000;
  float* disi  = O + P_DIS + 36000;
  unsigned short* ent0b = (unsigned short*)(O + P_E0B);
  unsigned short* c1b   = (unsigned short*)(O + P_C1B);
  unsigned short* c2b   = (unsigned short*)(O + P_C2B);
  unsigned short* nfb   = (unsigned short*)(O + P_NFB);
  unsigned short* t1b   = (unsigned short*)(O + P_T1B);
  unsigned short* t2b   = (unsigned short*)(O + P_T2B);
  float* g1    = O + P_G1;
  float* g2    = O + P_G2;
  float* accb  = O + P_ACC;
  unsigned short* entb  = (unsigned short*)(O + P_ENTB);
  unsigned short* hidb  = (unsigned short*)(O + P_HIDB);
  unsigned short* ent2b = (unsigned short*)(O + P_ENT2B);
  unsigned short* e768b = (unsigned short*)(O + P_E768B);
  unsigned short* tokb  = (unsigned short*)(O + P_TOKB);
  unsigned short* thidb = (unsigned short*)(O + P_THIDB);
  unsigned short* tok1b = (unsigned short*)(O + P_TOK1B);
  unsigned short* tok2b = (unsigned short*)(O + P_TOK2B);
  unsigned short* qb    = (unsigned short*)(O + P_QB);
  unsigned short* eemb  = (unsigned short*)(O + P_EEMB);
  float* pr0   = O + P_PR0;
  unsigned short* pr0b  = (unsigned short*)(O + P_PR0B);
  unsigned short* phidb = (unsigned short*)(O + P_PHIDB);
  unsigned short* wts   = (unsigned short*)(O + P_WT);

  int* iws = (int*)d_ws;
  unsigned short* p2b = (unsigned short*)d_ws;
  unsigned short* pp2t = (unsigned short*)d_ws + WS_PP2T_BYTE / 2;
  const bool ws_ok = (ws_size >= WS_NEED);
  int* cnt_i  = iws + I_CNT;
  int* part   = iws + I_PART;
  int* kg_rp  = iws + I_KG_RP;  int* kg_ca = iws + I_KG_CA;  int* kg_sl = iws + I_KG_SL;
  int* kg_bnd = iws + I_KG_BND; int* kg_cb = iws + I_KG_CB;
  int* c_rp   = iws + I_C_RP;   int* c_cur  = iws + I_C_CUR;   int* c_sl  = iws + I_C_SL;
  int* ts_rp  = iws + I_TS_RP;  int* ts_cur = iws + I_TS_CUR;  int* ts_sl = iws + I_TS_SL;
  int* is_rp  = iws + I_IS_RP;  int* is_cur = iws + I_IS_CUR;  int* is_sl = iws + I_IS_SL;

  const int EW = 256;

  // ---------------- phase A: conversions ----------------
  k_cvt<<<cdiv(NBf / 2, EW), EW, 0, stream>>>(x_node, xb, NBf / 2);
  k_wcat<<<cdiv(12 * Dm * Dm, EW), EW, 0, stream>>>(comp, bases, wct);
  k_cvt_t_all<<<2880, 256, 0, stream>>>(
      root, wts + S_ROOT, ep1w1, wts + S_EP1A, ep1w2, wts + S_EP1B,
      ep2w, wts + S_EP2, tp1w1, wts + S_TP1A, tp1w2, wts + S_TP1B,
      tp2w, wts + S_TP2, caw, wts + S_CAW, pp1w1, wts + S_PP1A,
      pp1w2, wts + S_PP1B);

  // ---------------- CSR builds ----------------
  hipMemsetAsync(cnt_i, 0, (size_t)NE * 4, stream);
  k_hist<<<cdiv(EKG, EW), EW, 0, stream>>>(ei_kg + EKG, cnt_i, EKG);
  {
    int nb = cdiv(NE, 256);
    k_scan_blk<<<nb, 256, 0, stream>>>(cnt_i, kg_rp, part, NE);
    k_scan_top<<<1, 256, 0, stream>>>(part, nb);
    k_scan_add<<<nb, 256, 0, stream>>>(kg_rp, part, kg_ca, NE);
  }
  hipMemsetAsync(cnt_i, 0, (size_t)NE * 4, stream);
  k_hist_lt<<<cdiv(EKG, EW), EW, 0, stream>>>(ei_kg + EKG, etype, cnt_i, EKG);
  k_add_i<<<cdiv(NE, EW), EW, 0, stream>>>(kg_rp, cnt_i, kg_bnd, kg_cb, NE);
  k_fill_split<<<cdiv(EKG, EW), EW, 0, stream>>>(
      ei_kg, ei_kg + EKG, etype, kg_ca, kg_cb, kg_sl, EKG);

  auto build_csr = [&](const int* ei, int n, int E, int* rp, int* cur, int* sl) {
    hipMemsetAsync(cnt_i, 0, (size_t)n * 4, stream);
    k_hist<<<cdiv(E, EW), EW, 0, stream>>>(ei + E, cnt_i, E);
    int nb = cdiv(n, 256);
    k_scan_blk<<<nb, 256, 0, stream>>>(cnt_i, rp, part, n);
    k_scan_top<<<1, 256, 0, stream>>>(part, nb);
    k_scan_add<<<nb, 256, 0, stream>>>(rp, part, cur, n);
    k_fill<<<cdiv(E, EW), EW, 0, stream>>>(ei, ei + E, cur, sl, E);
  };
  build_csr(ei_c, NE, EC, c_rp, c_cur, c_sl);
  build_csr(ei_ts, NM, ES, ts_rp, ts_cur, ts_sl);
  build_csr(ei_is, NM, ES, is_rp, is_cur, is_sl);

  k_dis_rp<<<cdiv(NE, EW), EW, 0, stream>>>(c_rp, disc, NE, EC);
  k_dis_rp<<<cdiv(NM, EW), EW, 0, stream>>>(ts_rp, dist, NM, ES);
  k_dis_rp<<<cdiv(NM, EW), EW, 0, stream>>>(is_rp, disi, NM, ES);

  hipMemsetAsync(rcpc, 0, (size_t)12 * NE * 4, stream);
  k_count_type<<<cdiv(EKG, EW), EW, 0, stream>>>(ei_kg + EKG, etype, rcpc, EKG);
  k_rcp<<<cdiv((long)12 * NE, EW), EW, 0, stream>>>(rcpc, (size_t)12 * NE);

  // ---------------- RGCN ----------------
  mgemm_bf<false, true, 0><<<dim3(cdiv(NE, 128), cdiv(Dm, 128)), 256, 0, stream>>>(
      xb, wts + S_ROOT, rbias, x_node, ent0, NE, Dm, Dm);
  mgemm_bf<false, false, 1><<<dim3(cdiv(NE, 128), cdiv(6 * Dm, 128)), 256, 0, stream>>>(
      xb, wct, nullptr, nullptr, hh, NE, 6 * Dm, Dm);
  k_rgcn_g<true, false><<<cdiv((long)NE * 64, EW), EW, 0, stream>>>(
      hh, rcpc, kg_rp, kg_bnd, kg_sl, ent0, nullptr, EKG);
  mgemm_bf<false, false, 1><<<dim3(cdiv(NE, 128), cdiv(6 * Dm, 128)), 256, 0, stream>>>(
      xb, wct + (size_t)6 * Dm * Dm, nullptr, nullptr, hh, NE, 6 * Dm, Dm);
  // last RGCN gather also emits ent0b (bf16) — xb dead by now
  k_rgcn_g<false, true><<<cdiv((long)NE * 64, EW), EW, 0, stream>>>(
      hh, rcpc, kg_rp, kg_bnd, kg_sl, ent0, ent0b, EKG);

  // ---------------- phase B: fused graph chains (disjoint buffers) --------
  k_gather_b<<<cdiv((long)NM * 192, EW), EW, 0, stream>>>(
      mte, (const uint32_t*)ent0b, (uint32_t*)nfb, NM, 192);
  // R1: c1 || ts1 || is1
  k_gcn_r1<<<NBLK_E + 2 * NBLK_M, 256, 0, stream>>>(
      ent0b, disc, c_rp, c_sl, c1b, accb,
      nfb, dist, ts_rp, ts_sl, t1b, g1,
      disi, is_rp, is_sl, t2b, g2);
  // R2: c2 || ts2 || is2
  k_gcn_r2<<<NBLK_E + 2 * NBLK_M, 256, 0, stream>>>(
      c1b, disc, c_rp, c_sl, c2b, accb,
      t1b, dist, ts_rp, ts_sl, g1,
      t2b, disi, is_rp, is_sl, g2);
  // movie contribution, then final entity pass (emits entb)
  k_scatter_movie2<<<cdiv(MBF, EW), EW, 0, stream>>>(mte, g1, g2, accb);
  k_gcn_gb<2, 1><<<NBLK_E, 256, 0, stream>>>(
      c2b, disc, c_rp, c_sl, entb, accb, NE, EC, 0.25f);

  // pp2t conversion (CSR arrays now dead)
  if (ws_ok) {
    k_cvt_t<<<dim3(NO / 32, Hm / 32), 256, 0, stream>>>(pp2w, pp2t, Hm, NO);
  }

  // ---------------- entity MLP ----------------
  mgemm_bf<true, false, 1><<<dim3(cdiv(NE, 128), cdiv(192, 128)), 256, 0, stream>>>(
      entb, wts + S_EP1A, ep1b1, nullptr, hidb, NE, 192, Dm);
  mgemm_bf<false, true, 1><<<dim3(cdiv(NE, 128), cdiv(Dm, 128)), 256, 0, stream>>>(
      hidb, wts + S_EP1B, ep1b2, accb, ent2b, NE, Dm, 192);
  mgemm_bf<false, false, 1><<<dim3(cdiv(NE, 128), cdiv(Hm, 128)), 256, 0, stream>>>(
      ent2b, wts + S_EP2, ep2b, nullptr, e768b, NE, Hm, Dm);

  // ---------------- token path ----------------
  k_cvt<<<cdiv((long)NTOK * Hm / 2, EW), EW, 0, stream>>>(tokens, tokb, (size_t)NTOK * Hm / 2);
  mgemm_bf<true, false, 1><<<dim3(cdiv(NTOK, 128), cdiv(Dm, 128)), 256, 0, stream>>>(
      tokb, wts + S_TP1A, tp1b1, nullptr, thidb, NTOK, Dm, Hm);
  mgemm_bf<false, true, 1><<<dim3(cdiv(NTOK, 128), cdiv(Hm, 128)), 256, 0, stream>>>(
      thidb, wts + S_TP1B, tp1b2, tokens, tok1b, NTOK, Hm, Dm);
  mgemm_bf<false, false, 1><<<dim3(cdiv(NTOK, 128), cdiv(Hm, 128)), 256, 0, stream>>>(
      tok1b, wts + S_TP2, tp2b, nullptr, tok2b, NTOK, Hm, Hm);
  mgemm_bf<false, false, 1><<<dim3(cdiv(NTOK, 128), cdiv(Hm, 128)), 256, 0, stream>>>(
      tok2b, wts + S_CAW, nullptr, nullptr, qb, NTOK, Hm, Hm);

  k_gather_b<<<cdiv((long)Bc * LE * (Hm / 2), EW), EW, 0, stream>>>(
      eids, (const uint32_t*)e768b, (uint32_t*)eemb, Bc * LE, Hm / 2);
  k_attn<<<cdiv((long)NTOK * 64, 256), 256, 0, stream>>>(qb, eemb, tok2b, pr0, pr0b);

  mgemm_bf<true, false, 1><<<dim3(cdiv(NTOK, 128), cdiv(Dm, 128)), 256, 0, stream>>>(
      pr0b, wts + S_PP1A, pp1b1, nullptr, phidb, NTOK, Dm, Hm);
  mgemm_bf<false, true, 1><<<dim3(cdiv(NTOK, 128), cdiv(Hm, 128)), 256, 0, stream>>>(
      phidb, wts + S_PP1B, pp1b2, pr0, p2b, NTOK, Hm, Dm);

  // ---------------- final GEMM + transpose (reads ONLY d_ws/d_in) ---------
  if (ws_ok) {
    mgemm_bf<false, false, 2><<<dim3(NTOK / 128, NO / 128), 256, 0, stream>>>(
        p2b, pp2t, pp2b, nullptr, O, NTOK, NO, Hm);
  } else {
    mgemm_fin<<<dim3(NTOK / 128, NO / 128), 256, 0, stream>>>(
        p2b, pp2w, pp2b, O, NTOK, NO, Hm);
  }
}

// Round 15
// 1429.798 us; speedup vs baseline: 1.1632x; 1.0618x over previous
//
#include <hip/hip_runtime.h>
#include <hip/hip_bf16.h>
#include <cstdint>
#include <cstddef>

// ---------------------------------------------------------------------------
// MMPrompt pipeline, round 15 = r14 (1518us, all-disjoint overlay, fused
// gathers) + LDS-transpose epilogue on the FINAL GEMM: each wave re-stages
// its 64x64 f32 tile through private LDS and writes 256B-contiguous runs
// (was 64B scattered quads -> ~1.0 TB/s write throughput).
// ---------------------------------------------------------------------------

namespace {

constexpr int NE   = 30000;
constexpr int NM   = 6000;
constexpr int Dm   = 384;
constexpr int Hm   = 768;
constexpr int EKG  = 200000;
constexpr int EC   = 200000;
constexpr int ES   = 80000;
constexpr int Bc   = 16;
constexpr int LE   = 48;
constexpr int NTOK = 4096;
constexpr int NO   = 18432;

constexpr size_t NBf = (size_t)NE * Dm;
constexpr size_t MBF = (size_t)NM * Dm;

// ---------------- d_out arena (f32-unit offsets) ----------------
constexpr size_t P_XB    = 0;
constexpr size_t P_WCT   = 5760000;
constexpr size_t P_CNT   = 6644736;
constexpr size_t P_ENT0  = 7004736;
constexpr size_t P_HH    = 18524736;
constexpr size_t P_DIS   = 53084736;
// phase B (all pairwise disjoint):
constexpr size_t P_E0B   = 0;          // bf16 NE*384: [0, 5,760,000)
constexpr size_t P_C1B   = 7004736;    // bf16 NE*384
constexpr size_t P_C2B   = 12764736;   // bf16 NE*384
constexpr size_t P_NFB   = 18600000;   // bf16 NM*384
constexpr size_t P_T1B   = 19800000;   // bf16 NM*384
constexpr size_t P_G1    = 21000000;   // f32  NM*384
constexpr size_t P_T2B   = 23400000;   // bf16 NM*384
constexpr size_t P_G2    = 24600000;   // f32  NM*384
constexpr size_t P_ACC   = 41564736;   // f32  NE*384
constexpr size_t P_ENTB  = 55600000;   // bf16 NE*384
// phase C:
constexpr size_t P_HIDB  = 0;
constexpr size_t P_ENT2B = 2880000;
constexpr size_t P_E768B = 8640000;
constexpr size_t P_TOKB  = 20160000;
constexpr size_t P_THIDB = 21732864;
constexpr size_t P_TOK1B = 22519296;
constexpr size_t P_TOK2B = 24092160;
constexpr size_t P_QB    = 25665024;
constexpr size_t P_EEMB  = 27237888;
constexpr size_t P_PR0   = 27532800;
constexpr size_t P_PR0B  = 30678528;
constexpr size_t P_PHIDB = 32251392;
constexpr size_t P_WT    = 74000000;
constexpr size_t S_ROOT  = 0;
constexpr size_t S_EP1A  = 147456;
constexpr size_t S_EP1B  = 221184;
constexpr size_t S_EP2   = 294912;
constexpr size_t S_TP1A  = 589824;
constexpr size_t S_TP1B  = 884736;
constexpr size_t S_TP2   = 1179648;
constexpr size_t S_CAW   = 1769472;
constexpr size_t S_PP1A  = 2359296;
constexpr size_t S_PP1B  = 2654208;

// ---------------- d_ws layout ----------------
constexpr size_t WI       = 6291456 / 4;
constexpr size_t I_CNT    = WI + 0;
constexpr size_t I_PART   = WI + 30000;
constexpr size_t I_KG_RP  = WI + 30256;
constexpr size_t I_KG_CA  = WI + 60256;
constexpr size_t I_KG_SL  = WI + 90256;
constexpr size_t I_C_RP   = WI + 290256;
constexpr size_t I_C_CUR  = WI + 320256;
constexpr size_t I_C_SL   = WI + 350256;
constexpr size_t I_TS_RP  = WI + 550256;
constexpr size_t I_TS_CUR = WI + 556256;
constexpr size_t I_TS_SL  = WI + 562256;
constexpr size_t I_IS_RP  = WI + 642256;
constexpr size_t I_IS_CUR = WI + 648256;
constexpr size_t I_IS_SL  = WI + 654256;
constexpr size_t I_KG_BND = WI + 734256;
constexpr size_t I_KG_CB  = WI + 764256;
constexpr size_t WS_PP2T_BYTE = 6291456;
constexpr size_t WS_NEED      = 34603008;

constexpr int NBLK_E = (NE * 64) / 256;   // 7500
constexpr int NBLK_M = (NM * 64) / 256;   // 1500

inline int cdiv(long a, long b) { return (int)((a + b - 1) / b); }

} // namespace

typedef short short8v __attribute__((ext_vector_type(8)));
typedef float f32x4 __attribute__((ext_vector_type(4)));

__device__ __forceinline__ unsigned short f2bf(float f) {
  union { float f; uint32_t u; } v; v.f = f;
  uint32_t u = v.u;
  u += 0x7fffu + ((u >> 16) & 1u);
  return (unsigned short)(u >> 16);
}
__device__ __forceinline__ uint32_t pkbf(float a, float b) {
  __hip_bfloat162 h = __float22bfloat162_rn(float2{a, b});
  union { __hip_bfloat162 h; uint32_t u; } cv; cv.h = h;
  return cv.u;
}
__device__ __forceinline__ float bflo(uint32_t u) {
  union { uint32_t u; float f; } c; c.u = u << 16; return c.f;
}
__device__ __forceinline__ float bfhi(uint32_t u) {
  union { uint32_t u; float f; } c; c.u = u & 0xFFFF0000u; return c.f;
}

__device__ __forceinline__ void gl16(const void* g, void* l) {
  __builtin_amdgcn_global_load_lds(
      (const __attribute__((address_space(1))) void*)g,
      (__attribute__((address_space(3))) void*)l, 16, 0, 0);
}

// ---------------------------------------------------------------------------
// conversion / utility kernels
// ---------------------------------------------------------------------------

__global__ void k_cvt(const float* __restrict__ x, unsigned short* __restrict__ o, size_t n2) {
  size_t i = (size_t)blockIdx.x * 256 + threadIdx.x;
  if (i >= n2) return;
  float2 v = *(const float2*)(x + 2 * i);
  *(uint32_t*)(o + 2 * i) = pkbf(v.x, v.y);
}

// f32 W[K][N] -> bf16 Wt[N][K] (pp2t only)
__global__ void k_cvt_t(const float* __restrict__ W, unsigned short* __restrict__ Wt,
                        int K, int N) {
  __shared__ float t[32][33];
  int tx = threadIdx.x & 31, ty = threadIdx.x >> 5;
  int n0 = blockIdx.x * 32, k0 = blockIdx.y * 32;
#pragma unroll
  for (int j = 0; j < 4; ++j)
    t[ty + 8 * j][tx] = W[(size_t)(k0 + ty + 8 * j) * N + n0 + tx];
  __syncthreads();
#pragma unroll
  for (int j = 0; j < 4; ++j) {
    int n = ty + 8 * j;
    Wt[(size_t)(n0 + n) * K + k0 + tx] = f2bf(t[tx][n]);
  }
}

// batched weight transpose-convert (10 weights; 2880 tiles)
__global__ void k_cvt_t_all(
    const float* s0, unsigned short* d0, const float* s1, unsigned short* d1,
    const float* s2, unsigned short* d2, const float* s3, unsigned short* d3,
    const float* s4, unsigned short* d4, const float* s5, unsigned short* d5,
    const float* s6, unsigned short* d6, const float* s7, unsigned short* d7,
    const float* s8, unsigned short* d8, const float* s9, unsigned short* d9) {
  __shared__ float t[32][33];
  int tile = blockIdx.x;
  const float* W; unsigned short* Wt; int K, N, base;
  if      (tile < 144)  { W = s0; Wt = d0; K = 384; N = 384; base = 0; }
  else if (tile < 216)  { W = s1; Wt = d1; K = 384; N = 192; base = 144; }
  else if (tile < 288)  { W = s2; Wt = d2; K = 192; N = 384; base = 216; }
  else if (tile < 576)  { W = s3; Wt = d3; K = 384; N = 768; base = 288; }
  else if (tile < 864)  { W = s4; Wt = d4; K = 768; N = 384; base = 576; }
  else if (tile < 1152) { W = s5; Wt = d5; K = 384; N = 768; base = 864; }
  else if (tile < 1728) { W = s6; Wt = d6; K = 768; N = 768; base = 1152; }
  else if (tile < 2304) { W = s7; Wt = d7; K = 768; N = 768; base = 1728; }
  else if (tile < 2592) { W = s8; Wt = d8; K = 768; N = 384; base = 2304; }
  else                  { W = s9; Wt = d9; K = 384; N = 768; base = 2592; }
  int lt = tile - base;
  int ntx = N >> 5;
  int n0 = (lt % ntx) * 32, k0 = (lt / ntx) * 32;
  int tx = threadIdx.x & 31, ty = threadIdx.x >> 5;
#pragma unroll
  for (int j = 0; j < 4; ++j)
    t[ty + 8 * j][tx] = W[(size_t)(k0 + ty + 8 * j) * N + n0 + tx];
  __syncthreads();
#pragma unroll
  for (int j = 0; j < 4; ++j) {
    int n = ty + 8 * j;
    Wt[(size_t)(n0 + n) * K + k0 + tx] = f2bf(t[tx][n]);
  }
}

__global__ void k_wcat(const float* __restrict__ comp, const float* __restrict__ bases,
                       unsigned short* __restrict__ Wt) {
  int idx = blockIdx.x * 256 + threadIdx.x;
  if (idx >= 12 * Dm * Dm) return;
  int i = idx % Dm;
  int o = (idx / Dm) % Dm;
  int r = idx / (Dm * Dm);
  float s = 0.f;
#pragma unroll
  for (int b = 0; b < 8; ++b)
    s += comp[r * 8 + b] * bases[(size_t)b * Dm * Dm + (size_t)i * Dm + o];
  Wt[idx] = f2bf(s);
}

__global__ void k_gather_b(const int* __restrict__ idx, const uint32_t* __restrict__ x2,
                           uint32_t* __restrict__ out2, int rows, int D2) {
  size_t i = (size_t)blockIdx.x * 256 + threadIdx.x;
  if (i >= (size_t)rows * D2) return;
  int r = (int)(i / D2);
  int c = (int)(i - (size_t)r * D2);
  out2[i] = x2[(size_t)idx[r] * D2 + c];
}

// ent[mte[m]][d] += 0.25*(g1[m][d]+g2[m][d])
__global__ void k_scatter_movie2(const int* __restrict__ mte, const float* __restrict__ g1,
                                 const float* __restrict__ g2, float* __restrict__ ent) {
  size_t i = (size_t)blockIdx.x * 256 + threadIdx.x;
  if (i >= MBF) return;
  int m = (int)(i / Dm);
  int d = (int)(i - (size_t)m * Dm);
  atomicAdd(&ent[(size_t)mte[m] * Dm + d], 0.25f * (g1[i] + g2[i]));
}

// ---------------------------------------------------------------------------
// CSR build
// ---------------------------------------------------------------------------

__global__ void k_hist(const int* __restrict__ dst, int* __restrict__ cnt, int E) {
  int e = blockIdx.x * 256 + threadIdx.x;
  if (e < E) atomicAdd(&cnt[dst[e]], 1);
}

__global__ void k_hist_lt(const int* __restrict__ dst, const int* __restrict__ typ,
                          int* __restrict__ cnt, int E) {
  int e = blockIdx.x * 256 + threadIdx.x;
  if (e < E && typ[e] < 6) atomicAdd(&cnt[dst[e]], 1);
}

__global__ void k_add_i(const int* __restrict__ a, const int* __restrict__ b,
                        int* __restrict__ o, int* __restrict__ o2, int n) {
  int i = blockIdx.x * 256 + threadIdx.x;
  if (i < n) { int v = a[i] + b[i]; o[i] = v; o2[i] = v; }
}

__global__ void k_scan_blk(const int* __restrict__ in, int* __restrict__ out,
                           int* __restrict__ part, int n) {
  __shared__ int s[256];
  int t = threadIdx.x;
  int g = blockIdx.x * 256 + t;
  int v = (g < n) ? in[g] : 0;
  s[t] = v;
  __syncthreads();
  for (int off = 1; off < 256; off <<= 1) {
    int add = (t >= off) ? s[t - off] : 0;
    __syncthreads();
    s[t] += add;
    __syncthreads();
  }
  if (g < n) out[g] = s[t] - v;
  if (t == 255) part[blockIdx.x] = s[255];
}

__global__ void k_scan_top(int* __restrict__ part, int nb) {
  __shared__ int s[256];
  int t = threadIdx.x;
  int v = (t < nb) ? part[t] : 0;
  s[t] = v;
  __syncthreads();
  for (int off = 1; off < 256; off <<= 1) {
    int add = (t >= off) ? s[t - off] : 0;
    __syncthreads();
    s[t] += add;
    __syncthreads();
  }
  if (t < nb) part[t] = s[t] - v;
}

__global__ void k_scan_add(int* __restrict__ out, const int* __restrict__ part,
                           int* __restrict__ cur, int n) {
  int g = blockIdx.x * 256 + threadIdx.x;
  if (g < n) { int v = out[g] + part[blockIdx.x]; out[g] = v; cur[g] = v; }
}

__global__ void k_fill(const int* __restrict__ src, const int* __restrict__ dst,
                       int* __restrict__ cur, int* __restrict__ slots, int E) {
  int e = blockIdx.x * 256 + threadIdx.x;
  if (e >= E) return;
  int d = dst[e];
  int pos = atomicAdd(&cur[d], 1);
  slots[pos] = src[e];
}

__global__ void k_fill_split(const int* __restrict__ src, const int* __restrict__ dst,
                             const int* __restrict__ typ, int* __restrict__ cur_a,
                             int* __restrict__ cur_b, int* __restrict__ slots, int E) {
  int e = blockIdx.x * 256 + threadIdx.x;
  if (e >= E) return;
  int d = dst[e];
  int* c = (typ[e] < 6) ? cur_a : cur_b;
  int pos = atomicAdd(&c[d], 1);
  slots[pos] = src[e] | (typ[e] << 16);
}

__global__ void k_dis_rp(const int* __restrict__ rp, float* __restrict__ dis, int n, int E) {
  int v = blockIdx.x * 256 + threadIdx.x;
  if (v >= n) return;
  int e0 = rp[v], e1 = (v + 1 < n) ? rp[v + 1] : E;
  dis[v] = rsqrtf((float)(e1 - e0) + 1.0f);
}

__global__ void k_count_type(const int* __restrict__ dst, const int* __restrict__ typ,
                             float* __restrict__ cnt, int E) {
  int i = blockIdx.x * 256 + threadIdx.x;
  if (i < E) atomicAdd(&cnt[(size_t)typ[i] * NE + dst[i]], 1.0f);
}

__global__ void k_rcp(float* __restrict__ c, size_t n) {
  size_t i = (size_t)blockIdx.x * 256 + threadIdx.x;
  if (i < n) { float v = c[i]; c[i] = (v > 0.f) ? 1.0f / v : 0.f; }
}

// ---------------------------------------------------------------------------
// GCN gather body: one wave per dst row, 2-edge unrolled.
// OUTM: 0 none, 1 outb=bf16(a), 2 outb=bf16(acc_new).
// ACCM: 1 acc += sc*a; 2 acc = sc*(x[v]+a); 3 acc = sc*a.
// ---------------------------------------------------------------------------
template <int OUTM, int ACCM>
__device__ __forceinline__ void gcn_body(
    const unsigned short* __restrict__ x, const float* __restrict__ dis,
    const int* __restrict__ rp, const int* __restrict__ slots,
    unsigned short* __restrict__ outb, float* __restrict__ acc,
    int n, int E, float sc, int blk) {
  int v = (int)(((size_t)blk * 256 + threadIdx.x) >> 6);
  int lane = threadIdx.x & 63;
  if (v >= n) return;
  float dv = dis[v];
  const uint32_t* xr = (const uint32_t*)(x + (size_t)v * Dm);
  float xv[6];
#pragma unroll
  for (int i = 0; i < 3; ++i) {
    uint32_t u = xr[lane + 64 * i];
    xv[2 * i] = bflo(u); xv[2 * i + 1] = bfhi(u);
  }
  float a[6];
#pragma unroll
  for (int i = 0; i < 6; ++i) a[i] = dv * xv[i];
  int e0 = rp[v], e1 = (v + 1 < n) ? rp[v + 1] : E;
  int e = e0;
  for (; e + 2 <= e1; e += 2) {
    int s0 = slots[e], s1 = slots[e + 1];
    float c0 = dis[s0], c1 = dis[s1];
    const uint32_t* x0 = (const uint32_t*)(x + (size_t)s0 * Dm);
    const uint32_t* x1 = (const uint32_t*)(x + (size_t)s1 * Dm);
    uint32_t u0[3], u1[3];
#pragma unroll
    for (int i = 0; i < 3; ++i) { u0[i] = x0[lane + 64 * i]; u1[i] = x1[lane + 64 * i]; }
#pragma unroll
    for (int i = 0; i < 3; ++i) {
      a[2 * i]     = fmaf(c0, bflo(u0[i]), a[2 * i]);
      a[2 * i + 1] = fmaf(c0, bfhi(u0[i]), a[2 * i + 1]);
      a[2 * i]     = fmaf(c1, bflo(u1[i]), a[2 * i]);
      a[2 * i + 1] = fmaf(c1, bfhi(u1[i]), a[2 * i + 1]);
    }
  }
  if (e < e1) {
    int s0 = slots[e];
    float c0 = dis[s0];
    const uint32_t* x0 = (const uint32_t*)(x + (size_t)s0 * Dm);
#pragma unroll
    for (int i = 0; i < 3; ++i) {
      uint32_t u = x0[lane + 64 * i];
      a[2 * i]     = fmaf(c0, bflo(u), a[2 * i]);
      a[2 * i + 1] = fmaf(c0, bfhi(u), a[2 * i + 1]);
    }
  }
#pragma unroll
  for (int i = 0; i < 6; ++i) a[i] *= dv;
  if (OUTM == 1) {
    uint32_t* ob = (uint32_t*)(outb + (size_t)v * Dm);
#pragma unroll
    for (int i = 0; i < 3; ++i) ob[lane + 64 * i] = pkbf(a[2 * i], a[2 * i + 1]);
  }
  float* ar = acc + (size_t)v * Dm;
  float nw[6];
#pragma unroll
  for (int i = 0; i < 3; ++i) {
    int cidx = 2 * (lane + 64 * i);
    if (ACCM == 1) {
      float2 old = *(const float2*)(ar + cidx);
      nw[2 * i] = old.x + sc * a[2 * i];
      nw[2 * i + 1] = old.y + sc * a[2 * i + 1];
    } else if (ACCM == 2) {
      nw[2 * i] = sc * (xv[2 * i] + a[2 * i]);
      nw[2 * i + 1] = sc * (xv[2 * i + 1] + a[2 * i + 1]);
    } else {
      nw[2 * i] = sc * a[2 * i];
      nw[2 * i + 1] = sc * a[2 * i + 1];
    }
    *(float2*)(ar + cidx) = float2{nw[2 * i], nw[2 * i + 1]};
  }
  if (OUTM == 2) {
    uint32_t* ob = (uint32_t*)(outb + (size_t)v * Dm);
#pragma unroll
    for (int i = 0; i < 3; ++i) ob[lane + 64 * i] = pkbf(nw[2 * i], nw[2 * i + 1]);
  }
}

template <int OUTM, int ACCM>
__global__ void k_gcn_gb(const unsigned short* __restrict__ x, const float* __restrict__ dis,
                         const int* __restrict__ rp, const int* __restrict__ slots,
                         unsigned short* __restrict__ outb, float* __restrict__ acc,
                         int n, int E, float sc) {
  gcn_body<OUTM, ACCM>(x, dis, rp, slots, outb, acc, n, E, sc, blockIdx.x);
}

// fused round 1: c1 (entity) || ts1 || is1
__global__ void k_gcn_r1(const unsigned short* e0b, const float* disc,
                         const int* c_rp, const int* c_sl,
                         unsigned short* c1b, float* accb,
                         const unsigned short* nfb,
                         const float* dist, const int* ts_rp, const int* ts_sl,
                         unsigned short* t1b, float* g1,
                         const float* disi, const int* is_rp, const int* is_sl,
                         unsigned short* t2b, float* g2) {
  int blk = blockIdx.x;
  if (blk < NBLK_E) {
    gcn_body<1, 2>(e0b, disc, c_rp, c_sl, c1b, accb, NE, EC, 0.25f, blk);
  } else if (blk < NBLK_E + NBLK_M) {
    gcn_body<1, 3>(nfb, dist, ts_rp, ts_sl, t1b, g1, NM, ES, 1.0f, blk - NBLK_E);
  } else {
    gcn_body<1, 3>(nfb, disi, is_rp, is_sl, t2b, g2, NM, ES, 1.0f, blk - NBLK_E - NBLK_M);
  }
}

// fused round 2: c2 (entity) || ts2 || is2
__global__ void k_gcn_r2(const unsigned short* c1b, const float* disc,
                         const int* c_rp, const int* c_sl,
                         unsigned short* c2b, float* accb,
                         const unsigned short* t1b,
                         const float* dist, const int* ts_rp, const int* ts_sl, float* g1,
                         const unsigned short* t2b,
                         const float* disi, const int* is_rp, const int* is_sl, float* g2) {
  int blk = blockIdx.x;
  if (blk < NBLK_E) {
    gcn_body<1, 1>(c1b, disc, c_rp, c_sl, c2b, accb, NE, EC, 0.25f, blk);
  } else if (blk < NBLK_E + NBLK_M) {
    gcn_body<0, 1>(t1b, dist, ts_rp, ts_sl, nullptr, g1, NM, ES, 1.0f, blk - NBLK_E);
  } else {
    gcn_body<0, 1>(t2b, disi, is_rp, is_sl, nullptr, g2, NM, ES, 1.0f, blk - NBLK_E - NBLK_M);
  }
}

// ---------------------------------------------------------------------------
// RGCN gather, split-range, 2-edge unrolled. EMITB: emit ent0b bf16 (last).
// ---------------------------------------------------------------------------
template <bool FIRST, bool EMITB>
__global__ void k_rgcn_g(const unsigned short* __restrict__ hh, const float* __restrict__ rcp,
                         const int* __restrict__ rp, const int* __restrict__ bnd,
                         const int* __restrict__ slots, float* __restrict__ ent0,
                         unsigned short* __restrict__ outb, int E) {
  int v = (int)((blockIdx.x * (size_t)blockDim.x + threadIdx.x) >> 6);
  int lane = threadIdx.x & 63;
  if (v >= NE) return;
  const int rbase = FIRST ? 0 : 6;
  int e0, e1;
  if (FIRST) { e0 = rp[v]; e1 = bnd[v]; }
  else       { e0 = bnd[v]; e1 = (v + 1 < NE) ? rp[v + 1] : E; }
  float* er = ent0 + (size_t)v * Dm;
  float2 a[3];
#pragma unroll
  for (int i = 0; i < 3; ++i) a[i] = *(const float2*)(er + 2 * lane + 128 * i);
  int e = e0;
  for (; e + 2 <= e1; e += 2) {
    int p0 = slots[e], p1 = slots[e + 1];
    int r0 = (p0 >> 16) - rbase, s0 = p0 & 0xFFFF;
    int r1 = (p1 >> 16) - rbase, s1 = p1 & 0xFFFF;
    float nm0 = rcp[(size_t)(r0 + rbase) * NE + v];
    float nm1 = rcp[(size_t)(r1 + rbase) * NE + v];
    const uint32_t* h0 = (const uint32_t*)(hh + (size_t)s0 * 2304 + (size_t)r0 * 384);
    const uint32_t* h1 = (const uint32_t*)(hh + (size_t)s1 * 2304 + (size_t)r1 * 384);
    uint32_t u0[3], u1[3];
#pragma unroll
    for (int i = 0; i < 3; ++i) { u0[i] = h0[lane + 64 * i]; u1[i] = h1[lane + 64 * i]; }
#pragma unroll
    for (int i = 0; i < 3; ++i) {
      a[i].x = fmaf(nm0, bflo(u0[i]), a[i].x);
      a[i].y = fmaf(nm0, bfhi(u0[i]), a[i].y);
      a[i].x = fmaf(nm1, bflo(u1[i]), a[i].x);
      a[i].y = fmaf(nm1, bfhi(u1[i]), a[i].y);
    }
  }
  if (e < e1) {
    int p0 = slots[e];
    int r0 = (p0 >> 16) - rbase, s0 = p0 & 0xFFFF;
    float nm0 = rcp[(size_t)(r0 + rbase) * NE + v];
    const uint32_t* h0 = (const uint32_t*)(hh + (size_t)s0 * 2304 + (size_t)r0 * 384);
#pragma unroll
    for (int i = 0; i < 3; ++i) {
      uint32_t u = h0[lane + 64 * i];
      a[i].x = fmaf(nm0, bflo(u), a[i].x);
      a[i].y = fmaf(nm0, bfhi(u), a[i].y);
    }
  }
#pragma unroll
  for (int i = 0; i < 3; ++i) *(float2*)(er + 2 * lane + 128 * i) = a[i];
  if (EMITB) {
    uint32_t* ob = (uint32_t*)(outb + (size_t)v * Dm);
#pragma unroll
    for (int i = 0; i < 3; ++i) ob[lane + 64 * i] = pkbf(a[i].x, a[i].y);
  }
}

// ---------------------------------------------------------------------------
// bf16 MFMA GEMM, 128x128 (m97 structure). A[M][K], Wt[N][K] bf16.
// OUT: 0 = f32 C, 1 = bf16 C, 2 = f32 transposed prompt layout, written via
// an LDS-transpose epilogue (256B-contiguous runs; M,N must be tile-exact).
// ---------------------------------------------------------------------------
template <bool RELU, bool RES, int OUT>
__global__ __launch_bounds__(256) void mgemm_bf(
    const unsigned short* __restrict__ A, const unsigned short* __restrict__ Wt,
    const float* __restrict__ bias, const float* __restrict__ Rp,
    void* __restrict__ Cv, int M, int N, int K) {
  __shared__ __align__(16) unsigned short SMEM[2 * 128 * 64];
  unsigned short* As = SMEM;
  unsigned short* Bs = SMEM + 128 * 64;
  const int tid = threadIdx.x;
  const int lane = tid & 63;
  const int w = tid >> 6;
  const int bm = blockIdx.x * 128, bn = blockIdx.y * 128;
  const int wr = (w >> 1) * 64, wc = (w & 1) * 64;
  const int lrow = lane & 15, lq = lane >> 4;
  f32x4 acc[4][4] = {};
  const int prow_l = lane >> 3;
  const int pslot = lane & 7;

  for (int k0 = 0; k0 < K; k0 += 64) {
    __syncthreads();
#pragma unroll
    for (int j = 0; j < 4; ++j) {
      int seg = j * 4 + w;
      int prow = seg * 8 + prow_l;
      int aslot = pslot ^ (prow & 7);
      int arow = min(bm + prow, M - 1);
      gl16(A + (size_t)arow * K + k0 + aslot * 8, &As[seg * 512 + lane * 8]);
    }
#pragma unroll
    for (int j = 0; j < 4; ++j) {
      int seg = j * 4 + w;
      int prow = seg * 8 + prow_l;
      int bslot = pslot ^ (prow & 7);
      int brow = min(bn + prow, N - 1);
      gl16(Wt + (size_t)brow * K + k0 + bslot * 8, &Bs[seg * 512 + lane * 8]);
    }
    __syncthreads();
#pragma unroll
    for (int ks = 0; ks < 2; ++ks) {
      short8v af[4], bf[4];
      const int slot = ks * 4 + lq;
#pragma unroll
      for (int mr = 0; mr < 4; ++mr) {
        int r = wr + mr * 16 + lrow;
        af[mr] = *(const short8v*)&As[r * 64 + ((slot ^ (r & 7)) << 3)];
      }
#pragma unroll
      for (int nc = 0; nc < 4; ++nc) {
        int r = wc + nc * 16 + lrow;
        bf[nc] = *(const short8v*)&Bs[r * 64 + ((slot ^ (r & 7)) << 3)];
      }
#pragma unroll
      for (int mr = 0; mr < 4; ++mr)
#pragma unroll
        for (int nc = 0; nc < 4; ++nc)
          acc[mr][nc] = __builtin_amdgcn_mfma_f32_16x16x32_bf16(
              af[mr], bf[nc], acc[mr][nc], 0, 0, 0);
    }
  }

  if (OUT == 2) {
    // LDS-transpose epilogue: wave's 64-col range is one 64-aligned dd-block.
    const int c0 = bn + wc;
    int l = c0 / 1536, rem = c0 - l * 1536;
    int blk2 = rem / 768, rem2 = rem - blk2 * 768;
    int h2 = rem2 >> 6;
    const size_t colb0 = (size_t)(l * 2 + blk2) * 3145728 + (size_t)h2 * 16384;
    float bias4[4];
#pragma unroll
    for (int nc = 0; nc < 4; ++nc) bias4[nc] = bias[c0 + nc * 16 + lrow];
    float* wl = (float*)SMEM + w * (16 * 66);   // 4 waves * 4224B = 16.9KB <= 32KB
    const int row16 = lane >> 2;
    const int qq = (lane & 3) * 16;
#pragma unroll
    for (int mr = 0; mr < 4; ++mr) {
      __syncthreads();   // mr=0: drain K-loop LDS reads; else: prev chunk reads done
#pragma unroll
      for (int e = 0; e < 4; ++e)
#pragma unroll
        for (int nc = 0; nc < 4; ++nc)
          wl[(lq * 4 + e) * 66 + nc * 16 + lrow] = acc[mr][nc][e] + bias4[nc];
      __syncthreads();   // writes visible before transpose read
      int r = bm + wr + mr * 16 + row16;
      float* op = (float*)Cv + colb0 + (size_t)r * 64 + (size_t)(r >> 8) * 180224 + qq;
      float4 v0 = *(float4*)&wl[row16 * 66 + qq + 0];
      float4 v1 = *(float4*)&wl[row16 * 66 + qq + 4];
      float4 v2 = *(float4*)&wl[row16 * 66 + qq + 8];
      float4 v3 = *(float4*)&wl[row16 * 66 + qq + 12];
      *(float4*)(op + 0)  = v0;
      *(float4*)(op + 4)  = v1;
      *(float4*)(op + 8)  = v2;
      *(float4*)(op + 12) = v3;
    }
    return;
  }

#pragma unroll
  for (int mr = 0; mr < 4; ++mr) {
#pragma unroll
    for (int e = 0; e < 4; ++e) {
      int r = bm + wr + mr * 16 + lq * 4 + e;
      if (r >= M) continue;
#pragma unroll
      for (int nc = 0; nc < 4; ++nc) {
        int c = bn + wc + nc * 16 + lrow;
        if (c >= N) continue;
        float v = acc[mr][nc][e];
        if (bias) v += bias[c];
        if (RES) v += Rp[(size_t)r * N + c];
        if (RELU) v = fmaxf(v, 0.f);
        if (OUT == 0) ((float*)Cv)[(size_t)r * N + c] = v;
        else ((unsigned short*)Cv)[(size_t)r * N + c] = f2bf(v);
      }
    }
  }
}

// Fallback FINAL GEMM (ws too small): W f32 from d_in, in-kernel conversion.
__global__ __launch_bounds__(256) void mgemm_fin(
    const unsigned short* __restrict__ A, const float* __restrict__ W,
    const float* __restrict__ bias, float* __restrict__ O, int M, int N, int K) {
  __shared__ __align__(16) unsigned short As[128 * 64];
  __shared__ __align__(16) unsigned short Bs[128 * 64];
  const int tid = threadIdx.x;
  const int lane = tid & 63;
  const int w = tid >> 6;
  const int bm = blockIdx.x * 128, bn = blockIdx.y * 128;
  const int wr = (w >> 1) * 64, wc = (w & 1) * 64;
  const int lrow = lane & 15, lq = lane >> 4;
  f32x4 acc[4][4] = {};
  const int prow_l = lane >> 3;
  const int pslot = lane & 7;
  const int n_loc = tid & 127;
  const int kh = (tid >> 7) * 32;

  for (int k0 = 0; k0 < K; k0 += 64) {
    __syncthreads();
#pragma unroll
    for (int j = 0; j < 4; ++j) {
      int seg = j * 4 + w;
      int prow = seg * 8 + prow_l;
      int aslot = pslot ^ (prow & 7);
      gl16(A + (size_t)(bm + prow) * K + k0 + aslot * 8, &As[seg * 512 + lane * 8]);
    }
    float wv[32];
    const float* wp = W + (size_t)(k0 + kh) * N + bn + n_loc;
#pragma unroll
    for (int j = 0; j < 32; ++j) wv[j] = wp[(size_t)j * N];
#pragma unroll
    for (int c = 0; c < 4; ++c) {
      uint32_t u0 = pkbf(wv[8 * c + 0], wv[8 * c + 1]);
      uint32_t u1 = pkbf(wv[8 * c + 2], wv[8 * c + 3]);
      uint32_t u2 = pkbf(wv[8 * c + 4], wv[8 * c + 5]);
      uint32_t u3 = pkbf(wv[8 * c + 6], wv[8 * c + 7]);
      int s = (kh >> 3) + c;
      *(uint4*)&Bs[n_loc * 64 + ((s ^ (n_loc & 7)) << 3)] = uint4{u0, u1, u2, u3};
    }
    __syncthreads();
#pragma unroll
    for (int ks = 0; ks < 2; ++ks) {
      short8v af[4], bf[4];
      const int slot = ks * 4 + lq;
#pragma unroll
      for (int mr = 0; mr < 4; ++mr) {
        int r = wr + mr * 16 + lrow;
        af[mr] = *(const short8v*)&As[r * 64 + ((slot ^ (r & 7)) << 3)];
      }
#pragma unroll
      for (int nc = 0; nc < 4; ++nc) {
        int r = wc + nc * 16 + lrow;
        bf[nc] = *(const short8v*)&Bs[r * 64 + ((slot ^ (r & 7)) << 3)];
      }
#pragma unroll
      for (int mr = 0; mr < 4; ++mr)
#pragma unroll
        for (int nc = 0; nc < 4; ++nc)
          acc[mr][nc] = __builtin_amdgcn_mfma_f32_16x16x32_bf16(
              af[mr], bf[nc], acc[mr][nc], 0, 0, 0);
    }
  }
#pragma unroll
  for (int mr = 0; mr < 4; ++mr) {
#pragma unroll
    for (int e = 0; e < 4; ++e) {
      int r = bm + wr + mr * 16 + lq * 4 + e;
      int b = r >> 8, t = r & 255;
#pragma unroll
      for (int nc = 0; nc < 4; ++nc) {
        int c = bn + wc + nc * 16 + lrow;
        float v = acc[mr][nc][e] + bias[c];
        int l = c / 1536, rem = c - l * 1536;
        int blk = rem / 768, rem2 = rem - blk * 768;
        int hh = rem2 >> 6, dd = rem2 & 63;
        size_t oi = (((((size_t)l * 2 + blk) * 16 + b) * 12 + hh) * 256 + t) * 64 + dd;
        O[oi] = v;
      }
    }
  }
}

// ---------------------------------------------------------------------------
// fused cross-attention (bf16 inputs): one wave per (b,t)
// ---------------------------------------------------------------------------
__global__ __launch_bounds__(256) void k_attn(
    const unsigned short* __restrict__ qb, const unsigned short* __restrict__ eb_all,
    const unsigned short* __restrict__ tokb, float* __restrict__ pr0,
    unsigned short* __restrict__ pr0b) {
  int gw = (int)((blockIdx.x * (size_t)blockDim.x + threadIdx.x) >> 6);
  int lane = threadIdx.x & 63;
  if (gw >= NTOK) return;
  int b = gw >> 8;
  const unsigned short* qr = qb + (size_t)gw * Hm;
  float2 q[6];
#pragma unroll
  for (int i = 0; i < 6; ++i) {
    uint32_t u = *(const uint32_t*)(qr + 2 * lane + 128 * i);
    q[i] = float2{bflo(u), bfhi(u)};
  }
  const unsigned short* eb = eb_all + (size_t)b * LE * Hm;
  float myA = -3.0e38f;
  for (int e = 0; e < LE; ++e) {
    const unsigned short* er = eb + (size_t)e * Hm;
    float s = 0.f;
#pragma unroll
    for (int i = 0; i < 6; ++i) {
      uint32_t u = *(const uint32_t*)(er + 2 * lane + 128 * i);
      s = fmaf(q[i].x, bflo(u), s);
      s = fmaf(q[i].y, bfhi(u), s);
    }
#pragma unroll
    for (int off = 32; off > 0; off >>= 1) s += __shfl_xor(s, off);
    if (lane == e) myA = s * (1.0f / 768.0f);
  }
  float mx = myA;
#pragma unroll
  for (int off = 32; off > 0; off >>= 1) mx = fmaxf(mx, __shfl_xor(mx, off));
  float p = (lane < LE) ? expf(myA - mx) : 0.f;
  float sum = p;
#pragma unroll
  for (int off = 32; off > 0; off >>= 1) sum += __shfl_xor(sum, off);
  float wgt = p / sum;
  const unsigned short* tr = tokb + (size_t)gw * Hm;
  float2 a[6];
#pragma unroll
  for (int i = 0; i < 6; ++i) {
    uint32_t u = *(const uint32_t*)(tr + 2 * lane + 128 * i);
    a[i] = float2{bflo(u), bfhi(u)};
  }
  for (int e = 0; e < LE; ++e) {
    float we = __shfl(wgt, e);
    const unsigned short* er = eb + (size_t)e * Hm;
#pragma unroll
    for (int i = 0; i < 6; ++i) {
      uint32_t u = *(const uint32_t*)(er + 2 * lane + 128 * i);
      a[i].x = fmaf(we, bflo(u), a[i].x);
      a[i].y = fmaf(we, bfhi(u), a[i].y);
    }
  }
  float* orow = pr0 + (size_t)gw * Hm;
  unsigned short* obrow = pr0b + (size_t)gw * Hm;
#pragma unroll
  for (int i = 0; i < 6; ++i) {
    *(float2*)(orow + 2 * lane + 128 * i) = a[i];
    *(uint32_t*)(obrow + 2 * lane + 128 * i) = pkbf(a[i].x, a[i].y);
  }
}

// ---------------------------------------------------------------------------

extern "C" void kernel_launch(void* const* d_in, const int* in_sizes, int n_in,
                              void* d_out, int out_size, void* d_ws, size_t ws_size,
                              hipStream_t stream) {
  (void)in_sizes; (void)n_in; (void)out_size;

  const float* x_node = (const float*)d_in[0];
  const float* bases  = (const float*)d_in[1];
  const float* comp   = (const float*)d_in[2];
  const float* root   = (const float*)d_in[3];
  const float* rbias  = (const float*)d_in[4];
  const float* ep1w1  = (const float*)d_in[5];
  const float* ep1b1  = (const float*)d_in[6];
  const float* ep1w2  = (const float*)d_in[7];
  const float* ep1b2  = (const float*)d_in[8];
  const float* ep2w   = (const float*)d_in[9];
  const float* ep2b   = (const float*)d_in[10];
  const float* tp1w1  = (const float*)d_in[11];
  const float* tp1b1  = (const float*)d_in[12];
  const float* tp1w2  = (const float*)d_in[13];
  const float* tp1b2  = (const float*)d_in[14];
  const float* tp2w   = (const float*)d_in[15];
  const float* tp2b   = (const float*)d_in[16];
  const float* caw    = (const float*)d_in[17];
  const float* pp1w1  = (const float*)d_in[18];
  const float* pp1b1  = (const float*)d_in[19];
  const float* pp1w2  = (const float*)d_in[20];
  const float* pp1b2  = (const float*)d_in[21];
  const float* pp2w   = (const float*)d_in[22];
  const float* pp2b   = (const float*)d_in[23];
  const float* tokens = (const float*)d_in[24];
  const int* ei_kg = (const int*)d_in[25];
  const int* etype = (const int*)d_in[26];
  const int* ei_c  = (const int*)d_in[27];
  const int* ei_ts = (const int*)d_in[28];
  const int* ei_is = (const int*)d_in[29];
  const int* mte   = (const int*)d_in[30];
  const int* eids  = (const int*)d_in[31];

  float* O = (float*)d_out;
  unsigned short* xb    = (unsigned short*)(O + P_XB);
  unsigned short* wct   = (unsigned short*)(O + P_WCT);
  float* rcpc  = O + P_CNT;
  float* ent0  = O + P_ENT0;
  unsigned short* hh    = (unsigned short*)(O + P_HH);
  float* disc  = O + P_DIS;
  float* dist  = O + P_DIS + 30000;
  float* disi  = O + P_DIS + 36000;
  unsigned short* ent0b = (unsigned short*)(O + P_E0B);
  unsigned short* c1b   = (unsigned short*)(O + P_C1B);
  unsigned short* c2b   = (unsigned short*)(O + P_C2B);
  unsigned short* nfb   = (unsigned short*)(O + P_NFB);
  unsigned short* t1b   = (unsigned short*)(O + P_T1B);
  unsigned short* t2b   = (unsigned short*)(O + P_T2B);
  float* g1    = O + P_G1;
  float* g2    = O + P_G2;
  float* accb  = O + P_ACC;
  unsigned short* entb  = (unsigned short*)(O + P_ENTB);
  unsigned short* hidb  = (unsigned short*)(O + P_HIDB);
  unsigned short* ent2b = (unsigned short*)(O + P_ENT2B);
  unsigned short* e768b = (unsigned short*)(O + P_E768B);
  unsigned short* tokb  = (unsigned short*)(O + P_TOKB);
  unsigned short* thidb = (unsigned short*)(O + P_THIDB);
  unsigned short* tok1b = (unsigned short*)(O + P_TOK1B);
  unsigned short* tok2b = (unsigned short*)(O + P_TOK2B);
  unsigned short* qb    = (unsigned short*)(O + P_QB);
  unsigned short* eemb  = (unsigned short*)(O + P_EEMB);
  float* pr0   = O + P_PR0;
  unsigned short* pr0b  = (unsigned short*)(O + P_PR0B);
  unsigned short* phidb = (unsigned short*)(O + P_PHIDB);
  unsigned short* wts   = (unsigned short*)(O + P_WT);

  int* iws = (int*)d_ws;
  unsigned short* p2b = (unsigned short*)d_ws;
  unsigned short* pp2t = (unsigned short*)d_ws + WS_PP2T_BYTE / 2;
  const bool ws_ok = (ws_size >= WS_NEED);
  int* cnt_i  = iws + I_CNT;
  int* part   = iws + I_PART;
  int* kg_rp  = iws + I_KG_RP;  int* kg_ca = iws + I_KG_CA;  int* kg_sl = iws + I_KG_SL;
  int* kg_bnd = iws + I_KG_BND; int* kg_cb = iws + I_KG_CB;
  int* c_rp   = iws + I_C_RP;   int* c_cur  = iws + I_C_CUR;   int* c_sl  = iws + I_C_SL;
  int* ts_rp  = iws + I_TS_RP;  int* ts_cur = iws + I_TS_CUR;  int* ts_sl = iws + I_TS_SL;
  int* is_rp  = iws + I_IS_RP;  int* is_cur = iws + I_IS_CUR;  int* is_sl = iws + I_IS_SL;

  const int EW = 256;

  // ---------------- phase A: conversions ----------------
  k_cvt<<<cdiv(NBf / 2, EW), EW, 0, stream>>>(x_node, xb, NBf / 2);
  k_wcat<<<cdiv(12 * Dm * Dm, EW), EW, 0, stream>>>(comp, bases, wct);
  k_cvt_t_all<<<2880, 256, 0, stream>>>(
      root, wts + S_ROOT, ep1w1, wts + S_EP1A, ep1w2, wts + S_EP1B,
      ep2w, wts + S_EP2, tp1w1, wts + S_TP1A, tp1w2, wts + S_TP1B,
      tp2w, wts + S_TP2, caw, wts + S_CAW, pp1w1, wts + S_PP1A,
      pp1w2, wts + S_PP1B);

  // ---------------- CSR builds ----------------
  hipMemsetAsync(cnt_i, 0, (size_t)NE * 4, stream);
  k_hist<<<cdiv(EKG, EW), EW, 0, stream>>>(ei_kg + EKG, cnt_i, EKG);
  {
    int nb = cdiv(NE, 256);
    k_scan_blk<<<nb, 256, 0, stream>>>(cnt_i, kg_rp, part, NE);
    k_scan_top<<<1, 256, 0, stream>>>(part, nb);
    k_scan_add<<<nb, 256, 0, stream>>>(kg_rp, part, kg_ca, NE);
  }
  hipMemsetAsync(cnt_i, 0, (size_t)NE * 4, stream);
  k_hist_lt<<<cdiv(EKG, EW), EW, 0, stream>>>(ei_kg + EKG, etype, cnt_i, EKG);
  k_add_i<<<cdiv(NE, EW), EW, 0, stream>>>(kg_rp, cnt_i, kg_bnd, kg_cb, NE);
  k_fill_split<<<cdiv(EKG, EW), EW, 0, stream>>>(
      ei_kg, ei_kg + EKG, etype, kg_ca, kg_cb, kg_sl, EKG);

  auto build_csr = [&](const int* ei, int n, int E, int* rp, int* cur, int* sl) {
    hipMemsetAsync(cnt_i, 0, (size_t)n * 4, stream);
    k_hist<<<cdiv(E, EW), EW, 0, stream>>>(ei + E, cnt_i, E);
    int nb = cdiv(n, 256);
    k_scan_blk<<<nb, 256, 0, stream>>>(cnt_i, rp, part, n);
    k_scan_top<<<1, 256, 0, stream>>>(part, nb);
    k_scan_add<<<nb, 256, 0, stream>>>(rp, part, cur, n);
    k_fill<<<cdiv(E, EW), EW, 0, stream>>>(ei, ei + E, cur, sl, E);
  };
  build_csr(ei_c, NE, EC, c_rp, c_cur, c_sl);
  build_csr(ei_ts, NM, ES, ts_rp, ts_cur, ts_sl);
  build_csr(ei_is, NM, ES, is_rp, is_cur, is_sl);

  k_dis_rp<<<cdiv(NE, EW), EW, 0, stream>>>(c_rp, disc, NE, EC);
  k_dis_rp<<<cdiv(NM, EW), EW, 0, stream>>>(ts_rp, dist, NM, ES);
  k_dis_rp<<<cdiv(NM, EW), EW, 0, stream>>>(is_rp, disi, NM, ES);

  hipMemsetAsync(rcpc, 0, (size_t)12 * NE * 4, stream);
  k_count_type<<<cdiv(EKG, EW), EW, 0, stream>>>(ei_kg + EKG, etype, rcpc, EKG);
  k_rcp<<<cdiv((long)12 * NE, EW), EW, 0, stream>>>(rcpc, (size_t)12 * NE);

  // ---------------- RGCN ----------------
  mgemm_bf<false, true, 0><<<dim3(cdiv(NE, 128), cdiv(Dm, 128)), 256, 0, stream>>>(
      xb, wts + S_ROOT, rbias, x_node, ent0, NE, Dm, Dm);
  mgemm_bf<false, false, 1><<<dim3(cdiv(NE, 128), cdiv(6 * Dm, 128)), 256, 0, stream>>>(
      xb, wct, nullptr, nullptr, hh, NE, 6 * Dm, Dm);
  k_rgcn_g<true, false><<<cdiv((long)NE * 64, EW), EW, 0, stream>>>(
      hh, rcpc, kg_rp, kg_bnd, kg_sl, ent0, nullptr, EKG);
  mgemm_bf<false, false, 1><<<dim3(cdiv(NE, 128), cdiv(6 * Dm, 128)), 256, 0, stream>>>(
      xb, wct + (size_t)6 * Dm * Dm, nullptr, nullptr, hh, NE, 6 * Dm, Dm);
  k_rgcn_g<false, true><<<cdiv((long)NE * 64, EW), EW, 0, stream>>>(
      hh, rcpc, kg_rp, kg_bnd, kg_sl, ent0, ent0b, EKG);

  // ---------------- phase B: fused graph chains (disjoint buffers) --------
  k_gather_b<<<cdiv((long)NM * 192, EW), EW, 0, stream>>>(
      mte, (const uint32_t*)ent0b, (uint32_t*)nfb, NM, 192);
  k_gcn_r1<<<NBLK_E + 2 * NBLK_M, 256, 0, stream>>>(
      ent0b, disc, c_rp, c_sl, c1b, accb,
      nfb, dist, ts_rp, ts_sl, t1b, g1,
      disi, is_rp, is_sl, t2b, g2);
  k_gcn_r2<<<NBLK_E + 2 * NBLK_M, 256, 0, stream>>>(
      c1b, disc, c_rp, c_sl, c2b, accb,
      t1b, dist, ts_rp, ts_sl, g1,
      t2b, disi, is_rp, is_sl, g2);
  k_scatter_movie2<<<cdiv(MBF, EW), EW, 0, stream>>>(mte, g1, g2, accb);
  k_gcn_gb<2, 1><<<NBLK_E, 256, 0, stream>>>(
      c2b, disc, c_rp, c_sl, entb, accb, NE, EC, 0.25f);

  // pp2t conversion (CSR arrays now dead)
  if (ws_ok) {
    k_cvt_t<<<dim3(NO / 32, Hm / 32), 256, 0, stream>>>(pp2w, pp2t, Hm, NO);
  }

  // ---------------- entity MLP ----------------
  mgemm_bf<true, false, 1><<<dim3(cdiv(NE, 128), cdiv(192, 128)), 256, 0, stream>>>(
      entb, wts + S_EP1A, ep1b1, nullptr, hidb, NE, 192, Dm);
  mgemm_bf<false, true, 1><<<dim3(cdiv(NE, 128), cdiv(Dm, 128)), 256, 0, stream>>>(
      hidb, wts + S_EP1B, ep1b2, accb, ent2b, NE, Dm, 192);
  mgemm_bf<false, false, 1><<<dim3(cdiv(NE, 128), cdiv(Hm, 128)), 256, 0, stream>>>(
      ent2b, wts + S_EP2, ep2b, nullptr, e768b, NE, Hm, Dm);

  // ---------------- token path ----------------
  k_cvt<<<cdiv((long)NTOK * Hm / 2, EW), EW, 0, stream>>>(tokens, tokb, (size_t)NTOK * Hm / 2);
  mgemm_bf<true, false, 1><<<dim3(cdiv(NTOK, 128), cdiv(Dm, 128)), 256, 0, stream>>>(
      tokb, wts + S_TP1A, tp1b1, nullptr, thidb, NTOK, Dm, Hm);
  mgemm_bf<false, true, 1><<<dim3(cdiv(NTOK, 128), cdiv(Hm, 128)), 256, 0, stream>>>(
      thidb, wts + S_TP1B, tp1b2, tokens, tok1b, NTOK, Hm, Dm);
  mgemm_bf<false, false, 1><<<dim3(cdiv(NTOK, 128), cdiv(Hm, 128)), 256, 0, stream>>>(
      tok1b, wts + S_TP2, tp2b, nullptr, tok2b, NTOK, Hm, Hm);
  mgemm_bf<false, false, 1><<<dim3(cdiv(NTOK, 128), cdiv(Hm, 128)), 256, 0, stream>>>(
      tok2b, wts + S_CAW, nullptr, nullptr, qb, NTOK, Hm, Hm);

  k_gather_b<<<cdiv((long)Bc * LE * (Hm / 2), EW), EW, 0, stream>>>(
      eids, (const uint32_t*)e768b, (uint32_t*)eemb, Bc * LE, Hm / 2);
  k_attn<<<cdiv((long)NTOK * 64, 256), 256, 0, stream>>>(qb, eemb, tok2b, pr0, pr0b);

  mgemm_bf<true, false, 1><<<dim3(cdiv(NTOK, 128), cdiv(Dm, 128)), 256, 0, stream>>>(
      pr0b, wts + S_PP1A, pp1b1, nullptr, phidb, NTOK, Dm, Hm);
  mgemm_bf<false, true, 1><<<dim3(cdiv(NTOK, 128), cdiv(Hm, 128)), 256, 0, stream>>>(
      phidb, wts + S_PP1B, pp1b2, pr0, p2b, NTOK, Hm, Dm);

  // ---------------- final GEMM + transpose (LDS-transpose epilogue) -------
  if (ws_ok) {
    mgemm_bf<false, false, 2><<<dim3(NTOK / 128, NO / 128), 256, 0, stream>>>(
        p2b, pp2t, pp2b, nullptr, O, NTOK, NO, Hm);
  } else {
    mgemm_fin<<<dim3(NTOK / 128, NO / 128), 256, 0, stream>>>(
        p2b, pp2w, pp2b, O, NTOK, NO, Hm);
  }
}